// Round 7
// baseline (2028.081 us; speedup 1.0000x reference)
//
#include <hip/hip_runtime.h>

// Problem constants (from reference)
#define NN 100000      // nodes
#define NE 1600000     // edges
#define NBATCH 100     // graphs
constexpr float EPS = 1e-5f;

__device__ __forceinline__ float lrelu(float x) { return x > 0.f ? x : 0.01f * x; }

// ---------------- CSR build ----------------

__global__ void k_hist(const int* __restrict__ dst, int* __restrict__ deg) {
    for (int e = blockIdx.x * blockDim.x + threadIdx.x; e < NE; e += gridDim.x * blockDim.x)
        atomicAdd(&deg[dst[e]], 1);
}

__global__ __launch_bounds__(1024) void k_scan(const int* __restrict__ deg,
                                               int* __restrict__ rowstart,
                                               int* __restrict__ cursor) {
    __shared__ int part[1024];
    const int t = threadIdx.x;
    const int chunk = (NN + 1023) / 1024;
    const int beg = t * chunk;
    const int end = (beg + chunk < NN) ? beg + chunk : NN;
    int s = 0;
    for (int i = beg; i < end; ++i) s += deg[i];
    part[t] = s;
    __syncthreads();
    for (int off = 1; off < 1024; off <<= 1) {
        int other = (t >= off) ? part[t - off] : 0;
        __syncthreads();
        part[t] += other;
        __syncthreads();
    }
    int run = part[t] - s;
    for (int i = beg; i < end; ++i) {
        rowstart[i] = run;
        cursor[i] = run;
        run += deg[i];
    }
    if (t == 0) rowstart[NN] = NE;
}

__global__ void k_fill(const int* __restrict__ dst, int* __restrict__ cursor,
                       int* __restrict__ csr_e) {
    for (int e = blockIdx.x * blockDim.x + threadIdx.x; e < NE; e += gridDim.x * blockDim.x) {
        int pos = atomicAdd(&cursor[dst[e]], 1);
        csr_e[pos] = e;
    }
}

// ---------------- batch boundaries (batch is sorted) ----------------

__global__ void k_bounds(const int* __restrict__ batch, int* __restrict__ bstart) {
    int b = blockIdx.x * blockDim.x + threadIdx.x;
    if (b > NBATCH) return;
    int lo = 0, hi = NN;
    while (lo < hi) {
        int mid = (lo + hi) >> 1;
        if (batch[mid] < b) lo = mid + 1; else hi = mid;
    }
    bstart[b] = lo;
}

// ---------------- kernels ----------------

__global__ void k_gather(const int* __restrict__ xi, const float* __restrict__ emb,
                         float* __restrict__ x0) {
    int total = NN * 16;
    for (int idx = blockIdx.x * blockDim.x + threadIdx.x; idx < total; idx += gridDim.x * blockDim.x) {
        int n = idx >> 4, d = idx & 15;
        x0[idx] = emb[(xi[n] << 4) + d];
    }
}

// agg[n,:] = sum_{e: dst[e]==n} x[src[e],:] * ew[e]
// One wave per node; EP edge-groups in parallel, shfl_xor reduction.
template <int D>
__global__ void k_aggregate(const float* __restrict__ x, const int* __restrict__ csr_e,
                            const int* __restrict__ rowstart, const int* __restrict__ src,
                            const float* __restrict__ ew, float* __restrict__ agg) {
    constexpr int LPN = (D >= 64) ? 16 : (D / 4);   // float4 lanes per segment group
    constexpr int SEG = D / (4 * LPN);              // float4 segments per lane (128->2, else 1)
    constexpr int EP  = 64 / LPN;                   // edge-parallel groups per wave
    const int wid  = blockIdx.x * (blockDim.x >> 6) + (threadIdx.x >> 6);
    const int lane = threadIdx.x & 63;
    const int sl   = lane % LPN;                    // segment lane
    const int eg   = lane / LPN;                    // edge group
    const int n = wid;
    if (n >= NN) return;
    const int beg = rowstart[n], end = rowstart[n + 1];
    float4 acc[SEG];
#pragma unroll
    for (int t = 0; t < SEG; ++t) acc[t] = {0.f, 0.f, 0.f, 0.f};
    for (int i = beg + eg; i < end; i += EP) {
        const int e = csr_e[i];
        const int s = src[e];
        const float w = ew[e];
#pragma unroll
        for (int t = 0; t < SEG; ++t) {
            const float4 v = *(const float4*)&x[(size_t)s * D + (sl + t * LPN) * 4];
            acc[t].x += v.x * w; acc[t].y += v.y * w; acc[t].z += v.z * w; acc[t].w += v.w * w;
        }
    }
#pragma unroll
    for (int m = LPN; m < 64; m <<= 1) {
#pragma unroll
        for (int t = 0; t < SEG; ++t) {
            acc[t].x += __shfl_xor(acc[t].x, m);
            acc[t].y += __shfl_xor(acc[t].y, m);
            acc[t].z += __shfl_xor(acc[t].z, m);
            acc[t].w += __shfl_xor(acc[t].w, m);
        }
    }
    if (eg == 0) {
#pragma unroll
        for (int t = 0; t < SEG; ++t)
            *(float4*)&agg[(size_t)n * D + (sl + t * LPN) * 4] = acc[t];
    }
}

// out[N,DOUT] = agg @ wrel + xin @ wroot + brel
// 128x64 tile, BK=16, 8x4 micro-tile (acc=32 regs). 64 FMAs per 6 LDS b128 reads.
template <int DIN, int DOUT>
__global__ __launch_bounds__(256) void k_conv_gemm(
        const float* __restrict__ agg, const float* __restrict__ xin,
        const float* __restrict__ wrel, const float* __restrict__ brel,
        const float* __restrict__ wroot, float* __restrict__ out) {
    constexpr int BK = 16;
    constexpr int AS = 132;                // padded A stride (128+4), 16B-aligned rows
    __shared__ float sAa[BK][AS];
    __shared__ float sAx[BK][AS];
    __shared__ float sWr[BK][64];
    __shared__ float sWo[BK][64];

    const int tid = threadIdx.x;
    const int c0 = blockIdx.x * 64;        // column tile
    const int n0 = blockIdx.y * 128;       // row tile
    const int tr = tid >> 4;               // 0..15 -> rows tr*8..tr*8+7
    const int tc = tid & 15;               // 0..15 -> cols tc*4..tc*4+3

    // staging: A rows 128 x BK cols; 8 floats per thread (2 x float4)
    const int ar = tid >> 1;               // 0..127 node row
    const int ac = (tid & 1) * 8;          // k sub-col {0, 8}
    const int wkr = tid >> 4;              // 0..15 k row
    const int wc = (tid & 15) * 4;         // col {0..60}
    int an = n0 + ar; if (an >= NN) an = NN - 1;

    float acc[8][4] = {};

    for (int kk = 0; kk < DIN; kk += BK) {
        const float4 a4a = *(const float4*)&agg[(size_t)an * DIN + kk + ac];
        const float4 a4b = *(const float4*)&agg[(size_t)an * DIN + kk + ac + 4];
        const float4 x4a = *(const float4*)&xin[(size_t)an * DIN + kk + ac];
        const float4 x4b = *(const float4*)&xin[(size_t)an * DIN + kk + ac + 4];
        const float4 wr4 = *(const float4*)&wrel[(size_t)(kk + wkr) * DOUT + c0 + wc];
        const float4 wo4 = *(const float4*)&wroot[(size_t)(kk + wkr) * DOUT + c0 + wc];
        __syncthreads();
        sAa[ac + 0][ar] = a4a.x; sAa[ac + 1][ar] = a4a.y; sAa[ac + 2][ar] = a4a.z; sAa[ac + 3][ar] = a4a.w;
        sAa[ac + 4][ar] = a4b.x; sAa[ac + 5][ar] = a4b.y; sAa[ac + 6][ar] = a4b.z; sAa[ac + 7][ar] = a4b.w;
        sAx[ac + 0][ar] = x4a.x; sAx[ac + 1][ar] = x4a.y; sAx[ac + 2][ar] = x4a.z; sAx[ac + 3][ar] = x4a.w;
        sAx[ac + 4][ar] = x4b.x; sAx[ac + 5][ar] = x4b.y; sAx[ac + 6][ar] = x4b.z; sAx[ac + 7][ar] = x4b.w;
        *(float4*)&sWr[wkr][wc] = wr4;
        *(float4*)&sWo[wkr][wc] = wo4;
        __syncthreads();
#pragma unroll
        for (int k = 0; k < BK; ++k) {
            const float4 aA0 = *(const float4*)&sAa[k][tr * 8];
            const float4 aA1 = *(const float4*)&sAa[k][tr * 8 + 4];
            const float4 aX0 = *(const float4*)&sAx[k][tr * 8];
            const float4 aX1 = *(const float4*)&sAx[k][tr * 8 + 4];
            const float4 br = *(const float4*)&sWr[k][tc * 4];
            const float4 bo = *(const float4*)&sWo[k][tc * 4];
            const float a_[8] = {aA0.x, aA0.y, aA0.z, aA0.w, aA1.x, aA1.y, aA1.z, aA1.w};
            const float x_[8] = {aX0.x, aX0.y, aX0.z, aX0.w, aX1.x, aX1.y, aX1.z, aX1.w};
            const float r_[4] = {br.x, br.y, br.z, br.w};
            const float o_[4] = {bo.x, bo.y, bo.z, bo.w};
#pragma unroll
            for (int i = 0; i < 8; ++i)
#pragma unroll
                for (int j = 0; j < 4; ++j)
                    acc[i][j] += a_[i] * r_[j] + x_[i] * o_[j];
        }
    }

    const float4 b4 = *(const float4*)&brel[c0 + tc * 4];
    const float bb[4] = {b4.x, b4.y, b4.z, b4.w};
#pragma unroll
    for (int i = 0; i < 8; ++i) {
        const int n = n0 + tr * 8 + i;
        if (n < NN) {
            float4 o;
            o.x = acc[i][0] + bb[0];
            o.y = acc[i][1] + bb[1];
            o.z = acc[i][2] + bb[2];
            o.w = acc[i][3] + bb[3];
            *(float4*)&out[(size_t)n * DOUT + c0 + tc * 4] = o;
        }
    }
}

// graph-norm + lrelu, batch-contiguous, no atomics.
template <int D>
__global__ __launch_bounds__(256) void k_graphnorm(
        float* __restrict__ x, const int* __restrict__ bstart,
        const float* __restrict__ a, const float* __restrict__ g,
        const float* __restrict__ bb) {
    __shared__ float red[256];
    const int b = blockIdx.x;
    const int col = blockIdx.y * 64 + (threadIdx.x & 63);
    const int rg = threadIdx.x >> 6;
    const int beg = bstart[b], end = bstart[b + 1];
    const float cntf = fmaxf((float)(end - beg), 1.f);

    float s = 0.f;
    for (int r = beg + rg; r < end; r += 4) s += x[(size_t)r * D + col];
    red[threadIdx.x] = s;
    __syncthreads();
    if (rg == 0) {
        s += red[threadIdx.x + 64] + red[threadIdx.x + 128] + red[threadIdx.x + 192];
        red[threadIdx.x] = s / cntf;
    }
    __syncthreads();
    const float mean = red[threadIdx.x & 63];
    const float alpha = a[col];
    __syncthreads();

    float v = 0.f;
    for (int r = beg + rg; r < end; r += 4) {
        float xc = x[(size_t)r * D + col] - alpha * mean;
        v += xc * xc;
    }
    red[threadIdx.x] = v;
    __syncthreads();
    if (rg == 0) {
        v += red[threadIdx.x + 64] + red[threadIdx.x + 128] + red[threadIdx.x + 192];
        red[threadIdx.x] = 1.f / sqrtf(v / cntf + EPS);
    }
    __syncthreads();
    const float inv = red[threadIdx.x & 63];
    const float gg = g[col], bbv = bb[col];

    for (int r = beg + rg; r < end; r += 4) {
        float xc = x[(size_t)r * D + col] - alpha * mean;
        float y = gg * xc * inv + bbv;
        x[(size_t)r * D + col] = lrelu(y);
    }
}

// graph-feature mean into h0 (stride 272, cols 0..255)
__global__ __launch_bounds__(256) void k_gf2(const float* __restrict__ x3,
                                             const int* __restrict__ bstart,
                                             float* __restrict__ h0) {
    __shared__ float red[256];
    const int b = blockIdx.x;
    const int col = blockIdx.y * 64 + (threadIdx.x & 63);
    const int rg = threadIdx.x >> 6;
    const int beg = bstart[b], end = bstart[b + 1];
    const float cntf = fmaxf((float)(end - beg), 1.f);
    float s = 0.f;
    for (int r = beg + rg; r < end; r += 4) s += x3[(size_t)r * 256 + col];
    red[threadIdx.x] = s;
    __syncthreads();
    if (rg == 0) {
        s += red[threadIdx.x + 64] + red[threadIdx.x + 128] + red[threadIdx.x + 192];
        h0[b * 272 + col] = s / cntf;
    }
}

__global__ void k_demo(const float* __restrict__ dg, const float* __restrict__ w,
                       const float* __restrict__ b, float* __restrict__ h0) {
    int idx = blockIdx.x * blockDim.x + threadIdx.x;
    if (idx < NBATCH * 16) {
        int i = idx >> 4, j = idx & 15;
        float acc = b[j];
        for (int k = 0; k < 4; ++k) acc += dg[i * 4 + k] * w[k * 16 + j];
        h0[i * 272 + 256 + j] = acc;
    }
}

__global__ void k_linear(const float* __restrict__ in, const float* __restrict__ w,
                         const float* __restrict__ b, float* __restrict__ out,
                         int rows, int K, int D) {
    int total = rows * D;
    for (int idx = blockIdx.x * blockDim.x + threadIdx.x; idx < total; idx += gridDim.x * blockDim.x) {
        int i = idx / D, j = idx - i * D;
        float acc = b[j];
        for (int k = 0; k < K; ++k) acc += in[i * K + k] * w[k * D + j];
        out[idx] = acc;
    }
}

__global__ void k_bn_lrelu(float* __restrict__ h, const float* __restrict__ g,
                           const float* __restrict__ b, int rows, int C) {
    int j = threadIdx.x;
    if (j >= C) return;
    float s = 0.f;
    for (int i = 0; i < rows; ++i) s += h[i * C + j];
    float m = s / rows;
    float v = 0.f;
    for (int i = 0; i < rows; ++i) { float d = h[i * C + j] - m; v += d * d; }
    v /= rows;
    float inv = 1.f / sqrtf(v + EPS);
    float gg = g[j], bb = b[j];
    for (int i = 0; i < rows; ++i) {
        float y = gg * (h[i * C + j] - m) * inv + bb;
        h[i * C + j] = lrelu(y);
    }
}

// ---------------- launcher ----------------

extern "C" void kernel_launch(void* const* d_in, const int* in_sizes, int n_in,
                              void* d_out, int out_size, void* d_ws, size_t ws_size,
                              hipStream_t stream) {
    const int*   x_idx  = (const int*)d_in[0];
    const int*   ei     = (const int*)d_in[1];
    const float* eattr  = (const float*)d_in[2];
    const int*   batch  = (const int*)d_in[3];
    const float* demog  = (const float*)d_in[4];
    const float* emb    = (const float*)d_in[5];
    const float* wrel1  = (const float*)d_in[6];
    const float* brel1  = (const float*)d_in[7];
    const float* wroot1 = (const float*)d_in[8];
    const float* wrel2  = (const float*)d_in[9];
    const float* brel2  = (const float*)d_in[10];
    const float* wroot2 = (const float*)d_in[11];
    const float* wrel3  = (const float*)d_in[12];
    const float* brel3  = (const float*)d_in[13];
    const float* wroot3 = (const float*)d_in[14];
    const float* gn1g = (const float*)d_in[15];
    const float* gn1b = (const float*)d_in[16];
    const float* gn1a = (const float*)d_in[17];
    const float* gn2g = (const float*)d_in[18];
    const float* gn2b = (const float*)d_in[19];
    const float* gn2a = (const float*)d_in[20];
    const float* dw   = (const float*)d_in[21];
    const float* db   = (const float*)d_in[22];
    const float* l1w  = (const float*)d_in[23];
    const float* l1b  = (const float*)d_in[24];
    const float* bn1g = (const float*)d_in[25];
    const float* bn1b = (const float*)d_in[26];
    const float* l2w  = (const float*)d_in[27];
    const float* l2b  = (const float*)d_in[28];
    const float* bn2g = (const float*)d_in[29];
    const float* bn2b = (const float*)d_in[30];
    const float* l3w  = (const float*)d_in[31];
    const float* l3b  = (const float*)d_in[32];
    float* out = (float*)d_out;

    float* W    = (float*)d_ws;
    float* x2   = W;
    float* agg2 = W + 12800000;
    float* x3   = W + 25600000;
    float* x1   = W + 25600000;
    float* agg1 = W + 32000000;
    float* x0   = W + 38400000;
    float* agg0 = W + 40000000;
    int*   csr_e    = (int*)(W + 51200000);      // NE
    int*   rowstart = (int*)(W + 52800000);      // NN+1
    int*   cursor   = (int*)(W + 52920000);      // NN
    int*   deg      = (int*)(W + 53040000);      // NN
    int*   bstart   = (int*)(W + 53160000);      // NBATCH+1
    float* h0   = W + 53161000;                  // 100*272
    float* h1   = h0 + 27200;                    // 100*128
    float* h2   = h1 + 12800;                    // 100*64

    const int* src = ei;
    const int* dst = ei + NE;

    auto gsz = [](long long t) {
        long long b = (t + 255) / 256;
        return (int)(b > 524288 ? 524288 : b);
    };
    const int nrow_blk = (NN + 127) / 128;   // 782
    const int nagg_blk = (NN + 3) / 4;       // 25000 (4 waves/block, 1 node/wave)

    // ---- CSR build (by dst) ----
    hipMemsetAsync(deg, 0, NN * sizeof(int), stream);
    k_hist<<<gsz(NE), 256, 0, stream>>>(dst, deg);
    k_scan<<<1, 1024, 0, stream>>>(deg, rowstart, cursor);
    k_fill<<<gsz(NE), 256, 0, stream>>>(dst, cursor, csr_e);

    // batch boundaries (batch sorted)
    k_bounds<<<1, 128, 0, stream>>>(batch, bstart);

    // x0 = emb[x_idx]
    k_gather<<<gsz((long long)NN * 16), 256, 0, stream>>>(x_idx, emb, x0);

    // conv1: 16 -> 64
    k_aggregate<16><<<nagg_blk, 256, 0, stream>>>(x0, csr_e, rowstart, src, eattr, agg0);
    k_conv_gemm<16, 64><<<dim3(1, nrow_blk), 256, 0, stream>>>(agg0, x0, wrel1, brel1, wroot1, x1);
    k_graphnorm<64><<<dim3(NBATCH, 1), 256, 0, stream>>>(x1, bstart, gn1a, gn1g, gn1b);

    // conv2: 64 -> 128
    k_aggregate<64><<<nagg_blk, 256, 0, stream>>>(x1, csr_e, rowstart, src, eattr, agg1);
    k_conv_gemm<64, 128><<<dim3(2, nrow_blk), 256, 0, stream>>>(agg1, x1, wrel2, brel2, wroot2, x2);
    k_graphnorm<128><<<dim3(NBATCH, 2), 256, 0, stream>>>(x2, bstart, gn2a, gn2g, gn2b);

    // conv3: 128 -> 256
    k_aggregate<128><<<nagg_blk, 256, 0, stream>>>(x2, csr_e, rowstart, src, eattr, agg2);
    k_conv_gemm<128, 256><<<dim3(4, nrow_blk), 256, 0, stream>>>(agg2, x2, wrel3, brel3, wroot3, x3);

    // head
    k_gf2<<<dim3(NBATCH, 4), 256, 0, stream>>>(x3, bstart, h0);
    k_demo<<<(NBATCH * 16 + 255) / 256, 256, 0, stream>>>(demog, dw, db, h0);

    k_linear<<<gsz(NBATCH * 128), 256, 0, stream>>>(h0, l1w, l1b, h1, NBATCH, 272, 128);
    k_bn_lrelu<<<1, 128, 0, stream>>>(h1, bn1g, bn1b, NBATCH, 128);
    k_linear<<<gsz(NBATCH * 64), 256, 0, stream>>>(h1, l2w, l2b, h2, NBATCH, 128, 64);
    k_bn_lrelu<<<1, 64, 0, stream>>>(h2, bn2g, bn2b, NBATCH, 64);
    k_linear<<<gsz(NBATCH * 3), 256, 0, stream>>>(h2, l3w, l3b, out, NBATCH, 64, 3);
}

// Round 8
// 1565.886 us; speedup vs baseline: 1.2952x; 1.2952x over previous
//
#include <hip/hip_runtime.h>

// Problem constants (from reference)
#define NN 100000      // nodes
#define NE 1600000     // edges
#define NBATCH 100     // graphs
constexpr float EPS = 1e-5f;

__device__ __forceinline__ float lrelu(float x) { return x > 0.f ? x : 0.01f * x; }

// ---------------- CSR build ----------------

__global__ void k_hist(const int* __restrict__ dst, int* __restrict__ deg) {
    for (int e = blockIdx.x * blockDim.x + threadIdx.x; e < NE; e += gridDim.x * blockDim.x)
        atomicAdd(&deg[dst[e]], 1);
}

// single block: exclusive scan of deg -> rowstart; cursor (may alias deg)
__global__ __launch_bounds__(1024) void k_scan(const int* __restrict__ deg,
                                               int* __restrict__ rowstart,
                                               int* __restrict__ cursor) {
    __shared__ int part[1024];
    const int t = threadIdx.x;
    const int chunk = (NN + 1023) / 1024;
    const int beg = t * chunk;
    const int end = (beg + chunk < NN) ? beg + chunk : NN;
    int s = 0;
    for (int i = beg; i < end; ++i) s += deg[i];
    part[t] = s;
    __syncthreads();
    for (int off = 1; off < 1024; off <<= 1) {
        int other = (t >= off) ? part[t - off] : 0;
        __syncthreads();
        part[t] += other;
        __syncthreads();
    }
    int run = part[t] - s;
    for (int i = beg; i < end; ++i) {
        const int d = deg[i];          // read BEFORE cursor write (cursor may alias deg)
        rowstart[i] = run;
        cursor[i] = run;
        run += d;
    }
    if (t == 0) rowstart[NN] = NE;
}

// scatter src/ew into dst-sorted order (removes csr_e indirection from aggregates)
__global__ void k_fill(const int* __restrict__ dst, const int* __restrict__ srcv,
                       const float* __restrict__ ew, int* __restrict__ cursor,
                       int* __restrict__ csr_src, float* __restrict__ csr_w) {
    for (int e = blockIdx.x * blockDim.x + threadIdx.x; e < NE; e += gridDim.x * blockDim.x) {
        int pos = atomicAdd(&cursor[dst[e]], 1);
        csr_src[pos] = srcv[e];
        csr_w[pos] = ew[e];
    }
}

// ---------------- batch boundaries (batch is sorted) ----------------

__global__ void k_bounds(const int* __restrict__ batch, int* __restrict__ bstart) {
    int b = blockIdx.x * blockDim.x + threadIdx.x;
    if (b > NBATCH) return;
    int lo = 0, hi = NN;
    while (lo < hi) {
        int mid = (lo + hi) >> 1;
        if (batch[mid] < b) lo = mid + 1; else hi = mid;
    }
    bstart[b] = lo;
}

// ---------------- kernels ----------------

__global__ void k_gather(const int* __restrict__ xi, const float* __restrict__ emb,
                         float* __restrict__ x0) {
    int total = NN * 16;
    for (int idx = blockIdx.x * blockDim.x + threadIdx.x; idx < total; idx += gridDim.x * blockDim.x) {
        int n = idx >> 4, d = idx & 15;
        x0[idx] = emb[(xi[n] << 4) + d];
    }
}

// agg[n,:] = sum over dst-sorted edge range of x[csr_src[i],:] * csr_w[i]
// One wave per node; EP edge-groups in parallel, shfl_xor reduction.
template <int D>
__global__ void k_aggregate(const float* __restrict__ x, const int* __restrict__ csr_src,
                            const float* __restrict__ csr_w, const int* __restrict__ rowstart,
                            float* __restrict__ agg) {
    constexpr int LPN = (D >= 64) ? 16 : (D / 4);   // float4 lanes per segment group
    constexpr int SEG = D / (4 * LPN);              // float4 segments per lane
    constexpr int EP  = 64 / LPN;                   // edge-parallel groups per wave
    const int n  = blockIdx.x * (blockDim.x >> 6) + (threadIdx.x >> 6);
    const int lane = threadIdx.x & 63;
    const int sl   = lane % LPN;
    const int eg   = lane / LPN;
    if (n >= NN) return;
    const int beg = rowstart[n], end = rowstart[n + 1];
    float4 acc[SEG];
#pragma unroll
    for (int t = 0; t < SEG; ++t) acc[t] = {0.f, 0.f, 0.f, 0.f};
    for (int i = beg + eg; i < end; i += EP) {
        const int s = csr_src[i];
        const float w = csr_w[i];
#pragma unroll
        for (int t = 0; t < SEG; ++t) {
            const float4 v = *(const float4*)&x[(size_t)s * D + (sl + t * LPN) * 4];
            acc[t].x += v.x * w; acc[t].y += v.y * w; acc[t].z += v.z * w; acc[t].w += v.w * w;
        }
    }
#pragma unroll
    for (int m = LPN; m < 64; m <<= 1) {
#pragma unroll
        for (int t = 0; t < SEG; ++t) {
            acc[t].x += __shfl_xor(acc[t].x, m);
            acc[t].y += __shfl_xor(acc[t].y, m);
            acc[t].z += __shfl_xor(acc[t].z, m);
            acc[t].w += __shfl_xor(acc[t].w, m);
        }
    }
    if (eg == 0) {
#pragma unroll
        for (int t = 0; t < SEG; ++t)
            *(float4*)&agg[(size_t)n * D + (sl + t * LPN) * 4] = acc[t];
    }
}

// out[N,DOUT] = agg @ wrel + xin @ wroot + brel
// 64x64 tile, BK=16, 4x4 micro-tile. VGPR ~112 — the measured local optimum;
// larger micro-tiles (8x4, 4x16) hit the register/occupancy cliff (r5, r7).
template <int DIN, int DOUT>
__global__ __launch_bounds__(256) void k_conv_gemm(
        const float* __restrict__ agg, const float* __restrict__ xin,
        const float* __restrict__ wrel, const float* __restrict__ brel,
        const float* __restrict__ wroot, float* __restrict__ out) {
    constexpr int BK = 16;
    constexpr int AS = 68;
    __shared__ float sAa[BK][AS];
    __shared__ float sAx[BK][AS];
    __shared__ float sWr[BK][64];
    __shared__ float sWo[BK][64];

    const int tid = threadIdx.x;
    const int c0 = blockIdx.x * 64;
    const int n0 = blockIdx.y * 64;
    const int tr = tid >> 4;
    const int tc = tid & 15;

    const int ar = tid >> 2;
    const int ac = (tid & 3) * 4;
    const int wkr = tid >> 4;
    const int wc = (tid & 15) * 4;
    int an = n0 + ar; if (an >= NN) an = NN - 1;

    float acc[4][4] = {};

    for (int kk = 0; kk < DIN; kk += BK) {
        const float4 a4 = *(const float4*)&agg[(size_t)an * DIN + kk + ac];
        const float4 x4 = *(const float4*)&xin[(size_t)an * DIN + kk + ac];
        const float4 wr4 = *(const float4*)&wrel[(size_t)(kk + wkr) * DOUT + c0 + wc];
        const float4 wo4 = *(const float4*)&wroot[(size_t)(kk + wkr) * DOUT + c0 + wc];
        __syncthreads();
        sAa[ac + 0][ar] = a4.x; sAa[ac + 1][ar] = a4.y; sAa[ac + 2][ar] = a4.z; sAa[ac + 3][ar] = a4.w;
        sAx[ac + 0][ar] = x4.x; sAx[ac + 1][ar] = x4.y; sAx[ac + 2][ar] = x4.z; sAx[ac + 3][ar] = x4.w;
        *(float4*)&sWr[wkr][wc] = wr4;
        *(float4*)&sWo[wkr][wc] = wo4;
        __syncthreads();
#pragma unroll
        for (int k = 0; k < BK; ++k) {
            const float4 aA = *(const float4*)&sAa[k][tr * 4];
            const float4 aX = *(const float4*)&sAx[k][tr * 4];
            const float4 br = *(const float4*)&sWr[k][tc * 4];
            const float4 bo = *(const float4*)&sWo[k][tc * 4];
            const float a_[4] = {aA.x, aA.y, aA.z, aA.w};
            const float x_[4] = {aX.x, aX.y, aX.z, aX.w};
            const float r_[4] = {br.x, br.y, br.z, br.w};
            const float o_[4] = {bo.x, bo.y, bo.z, bo.w};
#pragma unroll
            for (int i = 0; i < 4; ++i)
#pragma unroll
                for (int j = 0; j < 4; ++j)
                    acc[i][j] += a_[i] * r_[j] + x_[i] * o_[j];
        }
    }

    const float4 b4 = *(const float4*)&brel[c0 + tc * 4];
    const float bb[4] = {b4.x, b4.y, b4.z, b4.w};
#pragma unroll
    for (int i = 0; i < 4; ++i) {
        const int n = n0 + tr * 4 + i;
        if (n < NN) {
            float4 o;
            o.x = acc[i][0] + bb[0];
            o.y = acc[i][1] + bb[1];
            o.z = acc[i][2] + bb[2];
            o.w = acc[i][3] + bb[3];
            *(float4*)&out[(size_t)n * DOUT + c0 + tc * 4] = o;
        }
    }
}

// graph-norm + lrelu, batch-contiguous, no atomics, 2 global passes.
// var(xc) = E[x^2] - m^2 (2a - a^2)  with m = E[x], xc = x - a*m.
template <int D>
__global__ __launch_bounds__(256) void k_graphnorm(
        float* __restrict__ x, const int* __restrict__ bstart,
        const float* __restrict__ a, const float* __restrict__ g,
        const float* __restrict__ bb) {
    __shared__ float redس[256];
    __shared__ float redq[256];
    const int b = blockIdx.x;
    const int col = blockIdx.y * 64 + (threadIdx.x & 63);
    const int rg = threadIdx.x >> 6;
    const int beg = bstart[b], end = bstart[b + 1];
    const float cntf = fmaxf((float)(end - beg), 1.f);

    float s = 0.f, q = 0.f;
    for (int r = beg + rg; r < end; r += 4) {
        float v = x[(size_t)r * D + col];
        s += v;
        q += v * v;
    }
    redس[threadIdx.x] = s;
    redq[threadIdx.x] = q;
    __syncthreads();
    const float alpha = a[col];
    if (rg == 0) {
        s += redس[threadIdx.x + 64] + redس[threadIdx.x + 128] + redس[threadIdx.x + 192];
        q += redq[threadIdx.x + 64] + redq[threadIdx.x + 128] + redq[threadIdx.x + 192];
        const float m = s / cntf;
        const float ex2 = q / cntf;
        const float v = fmaxf(ex2 - m * m * (2.f * alpha - alpha * alpha), 0.f);
        redس[threadIdx.x] = m;
        redq[threadIdx.x] = 1.f / sqrtf(v + EPS);
    }
    __syncthreads();
    const float mean = redس[threadIdx.x & 63];
    const float inv = redq[threadIdx.x & 63];
    const float gg = g[col], bbv = bb[col];

    for (int r = beg + rg; r < end; r += 4) {
        float xc = x[(size_t)r * D + col] - alpha * mean;
        float y = gg * xc * inv + bbv;
        x[(size_t)r * D + col] = lrelu(y);
    }
}

// graph-feature mean into h0 (stride 272, cols 0..255)
__global__ __launch_bounds__(256) void k_gf2(const float* __restrict__ x3,
                                             const int* __restrict__ bstart,
                                             float* __restrict__ h0) {
    __shared__ float red[256];
    const int b = blockIdx.x;
    const int col = blockIdx.y * 64 + (threadIdx.x & 63);
    const int rg = threadIdx.x >> 6;
    const int beg = bstart[b], end = bstart[b + 1];
    const float cntf = fmaxf((float)(end - beg), 1.f);
    float s = 0.f;
    for (int r = beg + rg; r < end; r += 4) s += x3[(size_t)r * 256 + col];
    red[threadIdx.x] = s;
    __syncthreads();
    if (rg == 0) {
        s += red[threadIdx.x + 64] + red[threadIdx.x + 128] + red[threadIdx.x + 192];
        h0[b * 272 + col] = s / cntf;
    }
}

__global__ void k_demo(const float* __restrict__ dg, const float* __restrict__ w,
                       const float* __restrict__ b, float* __restrict__ h0) {
    int idx = blockIdx.x * blockDim.x + threadIdx.x;
    if (idx < NBATCH * 16) {
        int i = idx >> 4, j = idx & 15;
        float acc = b[j];
        for (int k = 0; k < 4; ++k) acc += dg[i * 4 + k] * w[k * 16 + j];
        h0[i * 272 + 256 + j] = acc;
    }
}

__global__ void k_linear(const float* __restrict__ in, const float* __restrict__ w,
                         const float* __restrict__ b, float* __restrict__ out,
                         int rows, int K, int D) {
    int total = rows * D;
    for (int idx = blockIdx.x * blockDim.x + threadIdx.x; idx < total; idx += gridDim.x * blockDim.x) {
        int i = idx / D, j = idx - i * D;
        float acc = b[j];
        for (int k = 0; k < K; ++k) acc += in[i * K + k] * w[k * D + j];
        out[idx] = acc;
    }
}

__global__ void k_bn_lrelu(float* __restrict__ h, const float* __restrict__ g,
                           const float* __restrict__ b, int rows, int C) {
    int j = threadIdx.x;
    if (j >= C) return;
    float s = 0.f;
    for (int i = 0; i < rows; ++i) s += h[i * C + j];
    float m = s / rows;
    float v = 0.f;
    for (int i = 0; i < rows; ++i) { float d = h[i * C + j] - m; v += d * d; }
    v /= rows;
    float inv = 1.f / sqrtf(v + EPS);
    float gg = g[j], bb = b[j];
    for (int i = 0; i < rows; ++i) {
        float y = gg * (h[i * C + j] - m) * inv + bb;
        h[i * C + j] = lrelu(y);
    }
}

// ---------------- launcher ----------------

extern "C" void kernel_launch(void* const* d_in, const int* in_sizes, int n_in,
                              void* d_out, int out_size, void* d_ws, size_t ws_size,
                              hipStream_t stream) {
    const int*   x_idx  = (const int*)d_in[0];
    const int*   ei     = (const int*)d_in[1];
    const float* eattr  = (const float*)d_in[2];
    const int*   batch  = (const int*)d_in[3];
    const float* demog  = (const float*)d_in[4];
    const float* emb    = (const float*)d_in[5];
    const float* wrel1  = (const float*)d_in[6];
    const float* brel1  = (const float*)d_in[7];
    const float* wroot1 = (const float*)d_in[8];
    const float* wrel2  = (const float*)d_in[9];
    const float* brel2  = (const float*)d_in[10];
    const float* wroot2 = (const float*)d_in[11];
    const float* wrel3  = (const float*)d_in[12];
    const float* brel3  = (const float*)d_in[13];
    const float* wroot3 = (const float*)d_in[14];
    const float* gn1g = (const float*)d_in[15];
    const float* gn1b = (const float*)d_in[16];
    const float* gn1a = (const float*)d_in[17];
    const float* gn2g = (const float*)d_in[18];
    const float* gn2b = (const float*)d_in[19];
    const float* gn2a = (const float*)d_in[20];
    const float* dw   = (const float*)d_in[21];
    const float* db   = (const float*)d_in[22];
    const float* l1w  = (const float*)d_in[23];
    const float* l1b  = (const float*)d_in[24];
    const float* bn1g = (const float*)d_in[25];
    const float* bn1b = (const float*)d_in[26];
    const float* l2w  = (const float*)d_in[27];
    const float* l2b  = (const float*)d_in[28];
    const float* bn2g = (const float*)d_in[29];
    const float* bn2b = (const float*)d_in[30];
    const float* l3w  = (const float*)d_in[31];
    const float* l3b  = (const float*)d_in[32];
    float* out = (float*)d_out;

    float* W    = (float*)d_ws;
    float* x2   = W;
    float* agg2 = W + 12800000;
    float* x3   = W + 25600000;
    float* x1   = W + 25600000;
    float* agg1 = W + 32000000;
    float* x0   = W + 38400000;
    float* agg0 = W + 40000000;
    int*   csr_src  = (int*)(W + 51200000);      // NE
    float* csr_w    = W + 52800000;              // NE
    int*   rowstart = (int*)(W + 54400000);      // NN+1
    int*   deg      = (int*)(W + 54520000);      // NN (aliased as cursor)
    int*   bstart   = (int*)(W + 54640000);      // NBATCH+1
    float* h0   = W + 54641000;                  // 100*272
    float* h1   = h0 + 27200;                    // 100*128
    float* h2   = h1 + 12800;                    // 100*64

    const int* src = ei;
    const int* dst = ei + NE;

    auto gsz = [](long long t) {
        long long b = (t + 255) / 256;
        return (int)(b > 524288 ? 524288 : b);
    };
    const int nrow_blk = (NN + 63) / 64;     // 1563
    const int nagg_blk = (NN + 3) / 4;       // 4 waves/block, 1 node/wave

    // ---- CSR build (by dst); cursor aliases deg ----
    hipMemsetAsync(deg, 0, NN * sizeof(int), stream);
    k_hist<<<gsz(NE), 256, 0, stream>>>(dst, deg);
    k_scan<<<1, 1024, 0, stream>>>(deg, rowstart, deg);
    k_fill<<<gsz(NE), 256, 0, stream>>>(dst, src, eattr, deg, csr_src, csr_w);

    // batch boundaries (batch sorted)
    k_bounds<<<1, 128, 0, stream>>>(batch, bstart);

    // x0 = emb[x_idx]
    k_gather<<<gsz((long long)NN * 16), 256, 0, stream>>>(x_idx, emb, x0);

    // conv1: 16 -> 64
    k_aggregate<16><<<nagg_blk, 256, 0, stream>>>(x0, csr_src, csr_w, rowstart, agg0);
    k_conv_gemm<16, 64><<<dim3(1, nrow_blk), 256, 0, stream>>>(agg0, x0, wrel1, brel1, wroot1, x1);
    k_graphnorm<64><<<dim3(NBATCH, 1), 256, 0, stream>>>(x1, bstart, gn1a, gn1g, gn1b);

    // conv2: 64 -> 128
    k_aggregate<64><<<nagg_blk, 256, 0, stream>>>(x1, csr_src, csr_w, rowstart, agg1);
    k_conv_gemm<64, 128><<<dim3(2, nrow_blk), 256, 0, stream>>>(agg1, x1, wrel2, brel2, wroot2, x2);
    k_graphnorm<128><<<dim3(NBATCH, 2), 256, 0, stream>>>(x2, bstart, gn2a, gn2g, gn2b);

    // conv3: 128 -> 256
    k_aggregate<128><<<nagg_blk, 256, 0, stream>>>(x2, csr_src, csr_w, rowstart, agg2);
    k_conv_gemm<128, 256><<<dim3(4, nrow_blk), 256, 0, stream>>>(agg2, x2, wrel3, brel3, wroot3, x3);

    // head
    k_gf2<<<dim3(NBATCH, 4), 256, 0, stream>>>(x3, bstart, h0);
    k_demo<<<(NBATCH * 16 + 255) / 256, 256, 0, stream>>>(demog, dw, db, h0);

    k_linear<<<gsz(NBATCH * 128), 256, 0, stream>>>(h0, l1w, l1b, h1, NBATCH, 272, 128);
    k_bn_lrelu<<<1, 128, 0, stream>>>(h1, bn1g, bn1b, NBATCH, 128);
    k_linear<<<gsz(NBATCH * 64), 256, 0, stream>>>(h1, l2w, l2b, h2, NBATCH, 128, 64);
    k_bn_lrelu<<<1, 64, 0, stream>>>(h2, bn2g, bn2b, NBATCH, 64);
    k_linear<<<gsz(NBATCH * 3), 256, 0, stream>>>(h2, l3w, l3b, out, NBATCH, 64, 3);
}

// Round 9
// 1336.467 us; speedup vs baseline: 1.5175x; 1.1717x over previous
//
#include <hip/hip_runtime.h>

// Problem constants (from reference)
#define NN 100000      // nodes
#define NE 1600000     // edges
#define NBATCH 100     // graphs
constexpr float EPS = 1e-5f;

__device__ __forceinline__ float lrelu(float x) { return x > 0.f ? x : 0.01f * x; }

// ---------------- CSR build ----------------

__global__ void k_hist(const int* __restrict__ dst, int* __restrict__ deg) {
    for (int e = blockIdx.x * blockDim.x + threadIdx.x; e < NE; e += gridDim.x * blockDim.x)
        atomicAdd(&deg[dst[e]], 1);
}

// single block: exclusive scan of deg -> rowstart; cursor (may alias deg).
// int4-vectorized both passes (chunk=100, NN%4==0, chunks 16B-aligned).
__global__ __launch_bounds__(1024) void k_scan(const int* __restrict__ deg,
                                               int* __restrict__ rowstart,
                                               int* __restrict__ cursor) {
    __shared__ int part[1024];
    const int t = threadIdx.x;
    const int chunk = 100;                        // 1024*100 >= NN, multiple of 4
    const int beg = t * chunk;
    const int end = (beg + chunk < NN) ? beg + chunk : NN;
    int s = 0;
    for (int i = beg; i < end; i += 4) {
        const int4 d4 = *(const int4*)&deg[i];
        s += d4.x + d4.y + d4.z + d4.w;
    }
    part[t] = s;
    __syncthreads();
    for (int off = 1; off < 1024; off <<= 1) {
        int other = (t >= off) ? part[t - off] : 0;
        __syncthreads();
        part[t] += other;
        __syncthreads();
    }
    int run = part[t] - s;                        // exclusive prefix at chunk start
    for (int i = beg; i < end; i += 4) {
        const int4 d4 = *(const int4*)&deg[i];    // read BEFORE cursor write (alias)
        int4 r;
        r.x = run;
        r.y = r.x + d4.x;
        r.z = r.y + d4.y;
        r.w = r.z + d4.z;
        run = r.w + d4.w;
        *(int4*)&rowstart[i] = r;
        *(int4*)&cursor[i] = r;
    }
    if (t == 0) rowstart[NN] = NE;
}

// scatter src/ew into dst-sorted order
__global__ void k_fill(const int* __restrict__ dst, const int* __restrict__ srcv,
                       const float* __restrict__ ew, int* __restrict__ cursor,
                       int* __restrict__ csr_src, float* __restrict__ csr_w) {
    for (int e = blockIdx.x * blockDim.x + threadIdx.x; e < NE; e += gridDim.x * blockDim.x) {
        int pos = atomicAdd(&cursor[dst[e]], 1);
        csr_src[pos] = srcv[e];
        csr_w[pos] = ew[e];
    }
}

// ---------------- batch boundaries (batch is sorted) ----------------

__global__ void k_bounds(const int* __restrict__ batch, int* __restrict__ bstart) {
    int b = blockIdx.x * blockDim.x + threadIdx.x;
    if (b > NBATCH) return;
    int lo = 0, hi = NN;
    while (lo < hi) {
        int mid = (lo + hi) >> 1;
        if (batch[mid] < b) lo = mid + 1; else hi = mid;
    }
    bstart[b] = lo;
}

// ---------------- kernels ----------------

__global__ void k_gather(const int* __restrict__ xi, const float* __restrict__ emb,
                         float* __restrict__ x0) {
    int total = NN * 4;
    for (int idx = blockIdx.x * blockDim.x + threadIdx.x; idx < total; idx += gridDim.x * blockDim.x) {
        int n = idx >> 2, seg = idx & 3;
        *(float4*)&x0[(size_t)n * 16 + seg * 4] =
            *(const float4*)&emb[((size_t)xi[n] << 4) + seg * 4];
    }
}

// agg[n,:] = sum over dst-sorted edge range of x[csr_src[i],:] * csr_w[i]
// One wave per node; EP edge-groups in parallel, 2x unrolled (dual accumulators
// for memory-level parallelism), shfl_xor reduction.
template <int D>
__global__ void k_aggregate(const float* __restrict__ x, const int* __restrict__ csr_src,
                            const float* __restrict__ csr_w, const int* __restrict__ rowstart,
                            float* __restrict__ agg) {
    constexpr int LPN = (D >= 64) ? 16 : (D / 4);   // float4 lanes per edge group
    constexpr int SEG = D / (4 * LPN);              // float4 segments per lane
    constexpr int EP  = 64 / LPN;                   // edge-parallel groups per wave
    const int n  = blockIdx.x * (blockDim.x >> 6) + (threadIdx.x >> 6);
    const int lane = threadIdx.x & 63;
    const int sl   = lane % LPN;
    const int eg   = lane / LPN;
    if (n >= NN) return;
    const int beg = rowstart[n], end = rowstart[n + 1];
    float4 acc[SEG], acc2[SEG];
#pragma unroll
    for (int t = 0; t < SEG; ++t) { acc[t] = {0.f, 0.f, 0.f, 0.f}; acc2[t] = {0.f, 0.f, 0.f, 0.f}; }
    int i = beg + eg;
    for (; i + EP < end; i += 2 * EP) {
        const int   s0 = csr_src[i];
        const float w0 = csr_w[i];
        const int   s1 = csr_src[i + EP];
        const float w1 = csr_w[i + EP];
#pragma unroll
        for (int t = 0; t < SEG; ++t) {
            const float4 v0 = *(const float4*)&x[(size_t)s0 * D + (sl + t * LPN) * 4];
            const float4 v1 = *(const float4*)&x[(size_t)s1 * D + (sl + t * LPN) * 4];
            acc[t].x += v0.x * w0; acc[t].y += v0.y * w0; acc[t].z += v0.z * w0; acc[t].w += v0.w * w0;
            acc2[t].x += v1.x * w1; acc2[t].y += v1.y * w1; acc2[t].z += v1.z * w1; acc2[t].w += v1.w * w1;
        }
    }
    if (i < end) {
        const int   s0 = csr_src[i];
        const float w0 = csr_w[i];
#pragma unroll
        for (int t = 0; t < SEG; ++t) {
            const float4 v0 = *(const float4*)&x[(size_t)s0 * D + (sl + t * LPN) * 4];
            acc[t].x += v0.x * w0; acc[t].y += v0.y * w0; acc[t].z += v0.z * w0; acc[t].w += v0.w * w0;
        }
    }
#pragma unroll
    for (int t = 0; t < SEG; ++t) {
        acc[t].x += acc2[t].x; acc[t].y += acc2[t].y; acc[t].z += acc2[t].z; acc[t].w += acc2[t].w;
    }
#pragma unroll
    for (int m = LPN; m < 64; m <<= 1) {
#pragma unroll
        for (int t = 0; t < SEG; ++t) {
            acc[t].x += __shfl_xor(acc[t].x, m);
            acc[t].y += __shfl_xor(acc[t].y, m);
            acc[t].z += __shfl_xor(acc[t].z, m);
            acc[t].w += __shfl_xor(acc[t].w, m);
        }
    }
    if (eg == 0) {
#pragma unroll
        for (int t = 0; t < SEG; ++t)
            *(float4*)&agg[(size_t)n * D + (sl + t * LPN) * 4] = acc[t];
    }
}

// out[N,DOUT] = agg @ wrel + xin @ wroot + brel
// 64x64 tile, BK=16, 4x4 micro-tile. VGPR 112 — measured local optimum (frozen);
// larger micro-tiles (8x4, 4x16) hit the register/occupancy cliff (r5, r7).
template <int DIN, int DOUT>
__global__ __launch_bounds__(256) void k_conv_gemm(
        const float* __restrict__ agg, const float* __restrict__ xin,
        const float* __restrict__ wrel, const float* __restrict__ brel,
        const float* __restrict__ wroot, float* __restrict__ out) {
    constexpr int BK = 16;
    constexpr int AS = 68;
    __shared__ float sAa[BK][AS];
    __shared__ float sAx[BK][AS];
    __shared__ float sWr[BK][64];
    __shared__ float sWo[BK][64];

    const int tid = threadIdx.x;
    const int c0 = blockIdx.x * 64;
    const int n0 = blockIdx.y * 64;
    const int tr = tid >> 4;
    const int tc = tid & 15;

    const int ar = tid >> 2;
    const int ac = (tid & 3) * 4;
    const int wkr = tid >> 4;
    const int wc = (tid & 15) * 4;
    int an = n0 + ar; if (an >= NN) an = NN - 1;

    float acc[4][4] = {};

    for (int kk = 0; kk < DIN; kk += BK) {
        const float4 a4 = *(const float4*)&agg[(size_t)an * DIN + kk + ac];
        const float4 x4 = *(const float4*)&xin[(size_t)an * DIN + kk + ac];
        const float4 wr4 = *(const float4*)&wrel[(size_t)(kk + wkr) * DOUT + c0 + wc];
        const float4 wo4 = *(const float4*)&wroot[(size_t)(kk + wkr) * DOUT + c0 + wc];
        __syncthreads();
        sAa[ac + 0][ar] = a4.x; sAa[ac + 1][ar] = a4.y; sAa[ac + 2][ar] = a4.z; sAa[ac + 3][ar] = a4.w;
        sAx[ac + 0][ar] = x4.x; sAx[ac + 1][ar] = x4.y; sAx[ac + 2][ar] = x4.z; sAx[ac + 3][ar] = x4.w;
        *(float4*)&sWr[wkr][wc] = wr4;
        *(float4*)&sWo[wkr][wc] = wo4;
        __syncthreads();
#pragma unroll
        for (int k = 0; k < BK; ++k) {
            const float4 aA = *(const float4*)&sAa[k][tr * 4];
            const float4 aX = *(const float4*)&sAx[k][tr * 4];
            const float4 br = *(const float4*)&sWr[k][tc * 4];
            const float4 bo = *(const float4*)&sWo[k][tc * 4];
            const float a_[4] = {aA.x, aA.y, aA.z, aA.w};
            const float x_[4] = {aX.x, aX.y, aX.z, aX.w};
            const float r_[4] = {br.x, br.y, br.z, br.w};
            const float o_[4] = {bo.x, bo.y, bo.z, bo.w};
#pragma unroll
            for (int i = 0; i < 4; ++i)
#pragma unroll
                for (int j = 0; j < 4; ++j)
                    acc[i][j] += a_[i] * r_[j] + x_[i] * o_[j];
        }
    }

    const float4 b4 = *(const float4*)&brel[c0 + tc * 4];
    const float bb[4] = {b4.x, b4.y, b4.z, b4.w};
#pragma unroll
    for (int i = 0; i < 4; ++i) {
        const int n = n0 + tr * 4 + i;
        if (n < NN) {
            float4 o;
            o.x = acc[i][0] + bb[0];
            o.y = acc[i][1] + bb[1];
            o.z = acc[i][2] + bb[2];
            o.w = acc[i][3] + bb[3];
            *(float4*)&out[(size_t)n * DOUT + c0 + tc * 4] = o;
        }
    }
}

// graph-norm + lrelu, batch-contiguous, no atomics, 2 global passes.
// var(xc) = E[x^2] - m^2 (2a - a^2)  with m = E[x], xc = x - a*m.
template <int D>
__global__ __launch_bounds__(256) void k_graphnorm(
        float* __restrict__ x, const int* __restrict__ bstart,
        const float* __restrict__ a, const float* __restrict__ g,
        const float* __restrict__ bb) {
    __shared__ float reds[256];
    __shared__ float redq[256];
    const int b = blockIdx.x;
    const int col = blockIdx.y * 64 + (threadIdx.x & 63);
    const int rg = threadIdx.x >> 6;
    const int beg = bstart[b], end = bstart[b + 1];
    const float cntf = fmaxf((float)(end - beg), 1.f);

    float s = 0.f, q = 0.f;
    for (int r = beg + rg; r < end; r += 4) {
        float v = x[(size_t)r * D + col];
        s += v;
        q += v * v;
    }
    reds[threadIdx.x] = s;
    redq[threadIdx.x] = q;
    __syncthreads();
    const float alpha = a[col];
    if (rg == 0) {
        s += reds[threadIdx.x + 64] + reds[threadIdx.x + 128] + reds[threadIdx.x + 192];
        q += redq[threadIdx.x + 64] + redq[threadIdx.x + 128] + redq[threadIdx.x + 192];
        const float m = s / cntf;
        const float ex2 = q / cntf;
        const float v = fmaxf(ex2 - m * m * (2.f * alpha - alpha * alpha), 0.f);
        reds[threadIdx.x] = m;
        redq[threadIdx.x] = 1.f / sqrtf(v + EPS);
    }
    __syncthreads();
    const float mean = reds[threadIdx.x & 63];
    const float inv = redq[threadIdx.x & 63];
    const float gg = g[col], bbv = bb[col];

    for (int r = beg + rg; r < end; r += 4) {
        float xc = x[(size_t)r * D + col] - alpha * mean;
        float y = gg * xc * inv + bbv;
        x[(size_t)r * D + col] = lrelu(y);
    }
}

// graph-feature mean into h0 (stride 272, cols 0..255)
__global__ __launch_bounds__(256) void k_gf2(const float* __restrict__ x3,
                                             const int* __restrict__ bstart,
                                             float* __restrict__ h0) {
    __shared__ float red[256];
    const int b = blockIdx.x;
    const int col = blockIdx.y * 64 + (threadIdx.x & 63);
    const int rg = threadIdx.x >> 6;
    const int beg = bstart[b], end = bstart[b + 1];
    const float cntf = fmaxf((float)(end - beg), 1.f);
    float s = 0.f;
    for (int r = beg + rg; r < end; r += 4) s += x3[(size_t)r * 256 + col];
    red[threadIdx.x] = s;
    __syncthreads();
    if (rg == 0) {
        s += red[threadIdx.x + 64] + red[threadIdx.x + 128] + red[threadIdx.x + 192];
        h0[b * 272 + col] = s / cntf;
    }
}

__global__ void k_demo(const float* __restrict__ dg, const float* __restrict__ w,
                       const float* __restrict__ b, float* __restrict__ h0) {
    int idx = blockIdx.x * blockDim.x + threadIdx.x;
    if (idx < NBATCH * 16) {
        int i = idx >> 4, j = idx & 15;
        float acc = b[j];
        for (int k = 0; k < 4; ++k) acc += dg[i * 4 + k] * w[k * 16 + j];
        h0[i * 272 + 256 + j] = acc;
    }
}

// fused linear + batch-norm + lrelu: one block per output column.
// block 128 threads; thread t (< rows) computes out[t, j], then LDS mean/var.
__global__ __launch_bounds__(128) void k_lin_bn(const float* __restrict__ in,
                                                const float* __restrict__ w,
                                                const float* __restrict__ bias,
                                                const float* __restrict__ g,
                                                const float* __restrict__ bb,
                                                float* __restrict__ out,
                                                int rows, int K, int C) {
    __shared__ float s1[128], s2[128];
    const int j = blockIdx.x;
    const int t = threadIdx.x;
    float v = 0.f;
    if (t < rows) {
        v = bias[j];
        for (int k = 0; k < K; ++k) v += in[t * K + k] * w[k * C + j];
    }
    s1[t] = (t < rows) ? v : 0.f;
    s2[t] = (t < rows) ? v * v : 0.f;
    __syncthreads();
    for (int off = 64; off > 0; off >>= 1) {
        if (t < off) { s1[t] += s1[t + off]; s2[t] += s2[t + off]; }
        __syncthreads();
    }
    const float m = s1[0] / rows;
    const float var = fmaxf(s2[0] / rows - m * m, 0.f);
    const float inv = 1.f / sqrtf(var + EPS);
    if (t < rows) out[t * C + j] = lrelu(g[j] * (v - m) * inv + bb[j]);
}

__global__ void k_linear(const float* __restrict__ in, const float* __restrict__ w,
                         const float* __restrict__ b, float* __restrict__ out,
                         int rows, int K, int D) {
    int total = rows * D;
    for (int idx = blockIdx.x * blockDim.x + threadIdx.x; idx < total; idx += gridDim.x * blockDim.x) {
        int i = idx / D, j = idx - i * D;
        float acc = b[j];
        for (int k = 0; k < K; ++k) acc += in[i * K + k] * w[k * D + j];
        out[idx] = acc;
    }
}

// ---------------- launcher ----------------

extern "C" void kernel_launch(void* const* d_in, const int* in_sizes, int n_in,
                              void* d_out, int out_size, void* d_ws, size_t ws_size,
                              hipStream_t stream) {
    const int*   x_idx  = (const int*)d_in[0];
    const int*   ei     = (const int*)d_in[1];
    const float* eattr  = (const float*)d_in[2];
    const int*   batch  = (const int*)d_in[3];
    const float* demog  = (const float*)d_in[4];
    const float* emb    = (const float*)d_in[5];
    const float* wrel1  = (const float*)d_in[6];
    const float* brel1  = (const float*)d_in[7];
    const float* wroot1 = (const float*)d_in[8];
    const float* wrel2  = (const float*)d_in[9];
    const float* brel2  = (const float*)d_in[10];
    const float* wroot2 = (const float*)d_in[11];
    const float* wrel3  = (const float*)d_in[12];
    const float* brel3  = (const float*)d_in[13];
    const float* wroot3 = (const float*)d_in[14];
    const float* gn1g = (const float*)d_in[15];
    const float* gn1b = (const float*)d_in[16];
    const float* gn1a = (const float*)d_in[17];
    const float* gn2g = (const float*)d_in[18];
    const float* gn2b = (const float*)d_in[19];
    const float* gn2a = (const float*)d_in[20];
    const float* dw   = (const float*)d_in[21];
    const float* db   = (const float*)d_in[22];
    const float* l1w  = (const float*)d_in[23];
    const float* l1b  = (const float*)d_in[24];
    const float* bn1g = (const float*)d_in[25];
    const float* bn1b = (const float*)d_in[26];
    const float* l2w  = (const float*)d_in[27];
    const float* l2b  = (const float*)d_in[28];
    const float* bn2g = (const float*)d_in[29];
    const float* bn2b = (const float*)d_in[30];
    const float* l3w  = (const float*)d_in[31];
    const float* l3b  = (const float*)d_in[32];
    float* out = (float*)d_out;

    float* W    = (float*)d_ws;
    float* x2   = W;
    float* agg2 = W + 12800000;
    float* x3   = W + 25600000;
    float* x1   = W + 25600000;
    float* agg1 = W + 32000000;
    float* x0   = W + 38400000;
    float* agg0 = W + 40000000;
    int*   csr_src  = (int*)(W + 51200000);      // NE
    float* csr_w    = W + 52800000;              // NE
    int*   rowstart = (int*)(W + 54400000);      // NN+1
    int*   deg      = (int*)(W + 54520000);      // NN (aliased as cursor)
    int*   bstart   = (int*)(W + 54640000);      // NBATCH+1
    float* h0   = W + 54641000;                  // 100*272
    float* h1   = h0 + 27200;                    // 100*128
    float* h2   = h1 + 12800;                    // 100*64

    const int* src = ei;
    const int* dst = ei + NE;

    auto gsz = [](long long t) {
        long long b = (t + 255) / 256;
        return (int)(b > 524288 ? 524288 : b);
    };
    const int nrow_blk = (NN + 63) / 64;     // 1563
    const int nagg_blk = (NN + 3) / 4;       // 4 waves/block, 1 node/wave

    // ---- CSR build (by dst); cursor aliases deg ----
    hipMemsetAsync(deg, 0, NN * sizeof(int), stream);
    k_hist<<<gsz(NE), 256, 0, stream>>>(dst, deg);
    k_scan<<<1, 1024, 0, stream>>>(deg, rowstart, deg);
    k_fill<<<gsz(NE), 256, 0, stream>>>(dst, src, eattr, deg, csr_src, csr_w);

    // batch boundaries (batch sorted)
    k_bounds<<<1, 128, 0, stream>>>(batch, bstart);

    // x0 = emb[x_idx]
    k_gather<<<gsz((long long)NN * 4), 256, 0, stream>>>(x_idx, emb, x0);

    // conv1: 16 -> 64
    k_aggregate<16><<<nagg_blk, 256, 0, stream>>>(x0, csr_src, csr_w, rowstart, agg0);
    k_conv_gemm<16, 64><<<dim3(1, nrow_blk), 256, 0, stream>>>(agg0, x0, wrel1, brel1, wroot1, x1);
    k_graphnorm<64><<<dim3(NBATCH, 1), 256, 0, stream>>>(x1, bstart, gn1a, gn1g, gn1b);

    // conv2: 64 -> 128
    k_aggregate<64><<<nagg_blk, 256, 0, stream>>>(x1, csr_src, csr_w, rowstart, agg1);
    k_conv_gemm<64, 128><<<dim3(2, nrow_blk), 256, 0, stream>>>(agg1, x1, wrel2, brel2, wroot2, x2);
    k_graphnorm<128><<<dim3(NBATCH, 2), 256, 0, stream>>>(x2, bstart, gn2a, gn2g, gn2b);

    // conv3: 128 -> 256
    k_aggregate<128><<<nagg_blk, 256, 0, stream>>>(x2, csr_src, csr_w, rowstart, agg2);
    k_conv_gemm<128, 256><<<dim3(4, nrow_blk), 256, 0, stream>>>(agg2, x2, wrel3, brel3, wroot3, x3);

    // head
    k_gf2<<<dim3(NBATCH, 4), 256, 0, stream>>>(x3, bstart, h0);
    k_demo<<<(NBATCH * 16 + 255) / 256, 256, 0, stream>>>(demog, dw, db, h0);

    k_lin_bn<<<128, 128, 0, stream>>>(h0, l1w, l1b, bn1g, bn1b, h1, NBATCH, 272, 128);
    k_lin_bn<<<64, 128, 0, stream>>>(h1, l2w, l2b, bn2g, bn2b, h2, NBATCH, 128, 64);
    k_linear<<<gsz(NBATCH * 3), 256, 0, stream>>>(h2, l3w, l3b, out, NBATCH, 64, 3);
}

// Round 10
// 1166.283 us; speedup vs baseline: 1.7389x; 1.1459x over previous
//
#include <hip/hip_runtime.h>

// Problem constants (from reference)
#define NN 100000      // nodes
#define NE 1600000     // edges
#define NBATCH 100     // graphs
constexpr float EPS = 1e-5f;

__device__ __forceinline__ float lrelu(float x) { return x > 0.f ? x : 0.01f * x; }

// ---------------- CSR build ----------------

__global__ void k_hist(const int* __restrict__ dst, int* __restrict__ deg) {
    for (int e = blockIdx.x * blockDim.x + threadIdx.x; e < NE; e += gridDim.x * blockDim.x)
        atomicAdd(&deg[dst[e]], 1);
}

// single block: exclusive scan of deg -> rowstart; cursor (may alias deg).
__global__ __launch_bounds__(1024) void k_scan(const int* __restrict__ deg,
                                               int* __restrict__ rowstart,
                                               int* __restrict__ cursor) {
    __shared__ int part[1024];
    const int t = threadIdx.x;
    const int chunk = 100;                        // 1024*100 >= NN, multiple of 4
    const int beg = t * chunk;
    const int end = (beg + chunk < NN) ? beg + chunk : NN;
    int s = 0;
    for (int i = beg; i < end; i += 4) {
        const int4 d4 = *(const int4*)&deg[i];
        s += d4.x + d4.y + d4.z + d4.w;
    }
    part[t] = s;
    __syncthreads();
    for (int off = 1; off < 1024; off <<= 1) {
        int other = (t >= off) ? part[t - off] : 0;
        __syncthreads();
        part[t] += other;
        __syncthreads();
    }
    int run = part[t] - s;
    for (int i = beg; i < end; i += 4) {
        const int4 d4 = *(const int4*)&deg[i];    // read BEFORE cursor write (alias)
        int4 r;
        r.x = run;
        r.y = r.x + d4.x;
        r.z = r.y + d4.y;
        r.w = r.z + d4.z;
        run = r.w + d4.w;
        *(int4*)&rowstart[i] = r;
        *(int4*)&cursor[i] = r;
    }
    if (t == 0) rowstart[NN] = NE;
}

__global__ void k_fill(const int* __restrict__ dst, const int* __restrict__ srcv,
                       const float* __restrict__ ew, int* __restrict__ cursor,
                       int* __restrict__ csr_src, float* __restrict__ csr_w) {
    for (int e = blockIdx.x * blockDim.x + threadIdx.x; e < NE; e += gridDim.x * blockDim.x) {
        int pos = atomicAdd(&cursor[dst[e]], 1);
        csr_src[pos] = srcv[e];
        csr_w[pos] = ew[e];
    }
}

// ---------------- batch boundaries (batch is sorted) ----------------

__global__ void k_bounds(const int* __restrict__ batch, int* __restrict__ bstart) {
    int b = blockIdx.x * blockDim.x + threadIdx.x;
    if (b > NBATCH) return;
    int lo = 0, hi = NN;
    while (lo < hi) {
        int mid = (lo + hi) >> 1;
        if (batch[mid] < b) lo = mid + 1; else hi = mid;
    }
    bstart[b] = lo;
}

// ---------------- kernels ----------------

__global__ void k_gather(const int* __restrict__ xi, const float* __restrict__ emb,
                         float* __restrict__ x0) {
    int total = NN * 4;
    for (int idx = blockIdx.x * blockDim.x + threadIdx.x; idx < total; idx += gridDim.x * blockDim.x) {
        int n = idx >> 2, seg = idx & 3;
        *(float4*)&x0[(size_t)n * 16 + seg * 4] =
            *(const float4*)&emb[((size_t)xi[n] << 4) + seg * 4];
    }
}

// agg[n,:] = sum over dst-sorted edge range of x[csr_src[i],:] * csr_w[i]
template <int D>
__global__ void k_aggregate(const float* __restrict__ x, const int* __restrict__ csr_src,
                            const float* __restrict__ csr_w, const int* __restrict__ rowstart,
                            float* __restrict__ agg) {
    constexpr int LPN = (D >= 64) ? 16 : (D / 4);
    constexpr int SEG = D / (4 * LPN);
    constexpr int EP  = 64 / LPN;
    const int n  = blockIdx.x * (blockDim.x >> 6) + (threadIdx.x >> 6);
    const int lane = threadIdx.x & 63;
    const int sl   = lane % LPN;
    const int eg   = lane / LPN;
    if (n >= NN) return;
    const int beg = rowstart[n], end = rowstart[n + 1];
    float4 acc[SEG], acc2[SEG];
#pragma unroll
    for (int t = 0; t < SEG; ++t) { acc[t] = {0.f, 0.f, 0.f, 0.f}; acc2[t] = {0.f, 0.f, 0.f, 0.f}; }
    int i = beg + eg;
    for (; i + EP < end; i += 2 * EP) {
        const int   s0 = csr_src[i];
        const float w0 = csr_w[i];
        const int   s1 = csr_src[i + EP];
        const float w1 = csr_w[i + EP];
#pragma unroll
        for (int t = 0; t < SEG; ++t) {
            const float4 v0 = *(const float4*)&x[(size_t)s0 * D + (sl + t * LPN) * 4];
            const float4 v1 = *(const float4*)&x[(size_t)s1 * D + (sl + t * LPN) * 4];
            acc[t].x += v0.x * w0; acc[t].y += v0.y * w0; acc[t].z += v0.z * w0; acc[t].w += v0.w * w0;
            acc2[t].x += v1.x * w1; acc2[t].y += v1.y * w1; acc2[t].z += v1.z * w1; acc2[t].w += v1.w * w1;
        }
    }
    if (i < end) {
        const int   s0 = csr_src[i];
        const float w0 = csr_w[i];
#pragma unroll
        for (int t = 0; t < SEG; ++t) {
            const float4 v0 = *(const float4*)&x[(size_t)s0 * D + (sl + t * LPN) * 4];
            acc[t].x += v0.x * w0; acc[t].y += v0.y * w0; acc[t].z += v0.z * w0; acc[t].w += v0.w * w0;
        }
    }
#pragma unroll
    for (int t = 0; t < SEG; ++t) {
        acc[t].x += acc2[t].x; acc[t].y += acc2[t].y; acc[t].z += acc2[t].z; acc[t].w += acc2[t].w;
    }
#pragma unroll
    for (int m = LPN; m < 64; m <<= 1) {
#pragma unroll
        for (int t = 0; t < SEG; ++t) {
            acc[t].x += __shfl_xor(acc[t].x, m);
            acc[t].y += __shfl_xor(acc[t].y, m);
            acc[t].z += __shfl_xor(acc[t].z, m);
            acc[t].w += __shfl_xor(acc[t].w, m);
        }
    }
    if (eg == 0) {
#pragma unroll
        for (int t = 0; t < SEG; ++t)
            *(float4*)&agg[(size_t)n * D + (sl + t * LPN) * 4] = acc[t];
    }
}

// out[N,DOUT] = agg @ wrel + xin @ wroot + brel
// 64x64 tile, BK=16, 4x4 micro-tile, VGPR ~112-125 (frozen structure).
// A-stream loads software-pipelined: issued after LDS write of current tile,
// overlapping the 16-k-step compute (W loads stay at loop top — L2-hot).
template <int DIN, int DOUT>
__global__ __launch_bounds__(256) void k_conv_gemm(
        const float* __restrict__ agg, const float* __restrict__ xin,
        const float* __restrict__ wrel, const float* __restrict__ brel,
        const float* __restrict__ wroot, float* __restrict__ out) {
    constexpr int BK = 16;
    constexpr int AS = 68;
    __shared__ float sAa[BK][AS];
    __shared__ float sAx[BK][AS];
    __shared__ float sWr[BK][64];
    __shared__ float sWo[BK][64];

    const int tid = threadIdx.x;
    const int c0 = blockIdx.x * 64;
    const int n0 = blockIdx.y * 64;
    const int tr = tid >> 4;
    const int tc = tid & 15;

    const int ar = tid >> 2;
    const int ac = (tid & 3) * 4;
    const int wkr = tid >> 4;
    const int wc = (tid & 15) * 4;
    int an = n0 + ar; if (an >= NN) an = NN - 1;

    float acc[4][4] = {};

    // prologue: first A tile
    float4 a4 = *(const float4*)&agg[(size_t)an * DIN + ac];
    float4 x4 = *(const float4*)&xin[(size_t)an * DIN + ac];

    for (int kk = 0; kk < DIN; kk += BK) {
        const float4 wr4 = *(const float4*)&wrel[(size_t)(kk + wkr) * DOUT + c0 + wc];
        const float4 wo4 = *(const float4*)&wroot[(size_t)(kk + wkr) * DOUT + c0 + wc];
        __syncthreads();
        sAa[ac + 0][ar] = a4.x; sAa[ac + 1][ar] = a4.y; sAa[ac + 2][ar] = a4.z; sAa[ac + 3][ar] = a4.w;
        sAx[ac + 0][ar] = x4.x; sAx[ac + 1][ar] = x4.y; sAx[ac + 2][ar] = x4.z; sAx[ac + 3][ar] = x4.w;
        *(float4*)&sWr[wkr][wc] = wr4;
        *(float4*)&sWo[wkr][wc] = wo4;
        __syncthreads();
        if (kk + BK < DIN) {                       // prefetch next A tile, overlaps compute
            a4 = *(const float4*)&agg[(size_t)an * DIN + kk + BK + ac];
            x4 = *(const float4*)&xin[(size_t)an * DIN + kk + BK + ac];
        }
#pragma unroll
        for (int k = 0; k < BK; ++k) {
            const float4 aA = *(const float4*)&sAa[k][tr * 4];
            const float4 aX = *(const float4*)&sAx[k][tr * 4];
            const float4 br = *(const float4*)&sWr[k][tc * 4];
            const float4 bo = *(const float4*)&sWo[k][tc * 4];
            const float a_[4] = {aA.x, aA.y, aA.z, aA.w};
            const float x_[4] = {aX.x, aX.y, aX.z, aX.w};
            const float r_[4] = {br.x, br.y, br.z, br.w};
            const float o_[4] = {bo.x, bo.y, bo.z, bo.w};
#pragma unroll
            for (int i = 0; i < 4; ++i)
#pragma unroll
                for (int j = 0; j < 4; ++j)
                    acc[i][j] += a_[i] * r_[j] + x_[i] * o_[j];
        }
    }

    const float4 b4 = *(const float4*)&brel[c0 + tc * 4];
    const float bb[4] = {b4.x, b4.y, b4.z, b4.w};
#pragma unroll
    for (int i = 0; i < 4; ++i) {
        const int n = n0 + tr * 4 + i;
        if (n < NN) {
            float4 o;
            o.x = acc[i][0] + bb[0];
            o.y = acc[i][1] + bb[1];
            o.z = acc[i][2] + bb[2];
            o.w = acc[i][3] + bb[3];
            *(float4*)&out[(size_t)n * DOUT + c0 + tc * 4] = o;
        }
    }
}

// graph-norm + lrelu, batch-contiguous, no atomics, 2 global passes, float4 cols.
// block 256 = 16 col-lanes (x4 cols) x 16 row-groups; grid (NBATCH, D/64).
// var(xc) = E[x^2] - m^2 (2a - a^2)  with m = E[x], xc = x - a*m.
template <int D>
__global__ __launch_bounds__(256) void k_graphnorm(
        float* __restrict__ x, const int* __restrict__ bstart,
        const float* __restrict__ a, const float* __restrict__ g,
        const float* __restrict__ bb) {
    __shared__ float4 reds[256];
    __shared__ float4 redq[256];
    __shared__ float smean[64];
    __shared__ float sinv[64];
    const int b = blockIdx.x;
    const int col0 = blockIdx.y * 64;
    const int c4 = (threadIdx.x & 15) * 4;        // local col offset (0..60)
    const int rg = threadIdx.x >> 4;              // 0..15
    const int beg = bstart[b], end = bstart[b + 1];
    const float cntf = fmaxf((float)(end - beg), 1.f);

    float4 s = {0.f, 0.f, 0.f, 0.f}, q = {0.f, 0.f, 0.f, 0.f};
    for (int r = beg + rg; r < end; r += 16) {
        const float4 v = *(const float4*)&x[(size_t)r * D + col0 + c4];
        s.x += v.x; s.y += v.y; s.z += v.z; s.w += v.w;
        q.x += v.x * v.x; q.y += v.y * v.y; q.z += v.z * v.z; q.w += v.w * v.w;
    }
    reds[threadIdx.x] = s;
    redq[threadIdx.x] = q;
    __syncthreads();
    if (rg == 0) {                                // threads 0..15
        float4 S = reds[threadIdx.x], Q = redq[threadIdx.x];
        for (int k = 1; k < 16; ++k) {
            const float4 s2 = reds[threadIdx.x + 16 * k];
            const float4 q2 = redq[threadIdx.x + 16 * k];
            S.x += s2.x; S.y += s2.y; S.z += s2.z; S.w += s2.w;
            Q.x += q2.x; Q.y += q2.y; Q.z += q2.z; Q.w += q2.w;
        }
        const float4 al = *(const float4*)&a[col0 + c4];
        const float Sv[4] = {S.x, S.y, S.z, S.w};
        const float Qv[4] = {Q.x, Q.y, Q.z, Q.w};
        const float av[4] = {al.x, al.y, al.z, al.w};
#pragma unroll
        for (int c = 0; c < 4; ++c) {
            const float m = Sv[c] / cntf;
            const float ex2 = Qv[c] / cntf;
            const float var = fmaxf(ex2 - m * m * (2.f * av[c] - av[c] * av[c]), 0.f);
            smean[c4 + c] = m;
            sinv[c4 + c] = 1.f / sqrtf(var + EPS);
        }
    }
    __syncthreads();
    const float4 mean4 = *(const float4*)&smean[c4];
    const float4 inv4 = *(const float4*)&sinv[c4];
    const float4 al4 = *(const float4*)&a[col0 + c4];
    const float4 g4 = *(const float4*)&g[col0 + c4];
    const float4 bb4 = *(const float4*)&bb[col0 + c4];
    for (int r = beg + rg; r < end; r += 16) {
        float4 v = *(const float4*)&x[(size_t)r * D + col0 + c4];
        v.x = lrelu(g4.x * (v.x - al4.x * mean4.x) * inv4.x + bb4.x);
        v.y = lrelu(g4.y * (v.y - al4.y * mean4.y) * inv4.y + bb4.y);
        v.z = lrelu(g4.z * (v.z - al4.z * mean4.z) * inv4.z + bb4.z);
        v.w = lrelu(g4.w * (v.w - al4.w * mean4.w) * inv4.w + bb4.w);
        *(float4*)&x[(size_t)r * D + col0 + c4] = v;
    }
}

// graph-feature mean into h0 (stride 272, cols 0..255), float4 cols.
__global__ __launch_bounds__(256) void k_gf2(const float* __restrict__ x3,
                                             const int* __restrict__ bstart,
                                             float* __restrict__ h0) {
    __shared__ float4 red[256];
    const int b = blockIdx.x;
    const int col0 = blockIdx.y * 64;
    const int c4 = (threadIdx.x & 15) * 4;
    const int rg = threadIdx.x >> 4;
    const int beg = bstart[b], end = bstart[b + 1];
    const float cntf = fmaxf((float)(end - beg), 1.f);
    float4 s = {0.f, 0.f, 0.f, 0.f};
    for (int r = beg + rg; r < end; r += 16) {
        const float4 v = *(const float4*)&x3[(size_t)r * 256 + col0 + c4];
        s.x += v.x; s.y += v.y; s.z += v.z; s.w += v.w;
    }
    red[threadIdx.x] = s;
    __syncthreads();
    if (rg == 0) {
        float4 S = red[threadIdx.x];
        for (int k = 1; k < 16; ++k) {
            const float4 s2 = red[threadIdx.x + 16 * k];
            S.x += s2.x; S.y += s2.y; S.z += s2.z; S.w += s2.w;
        }
        S.x /= cntf; S.y /= cntf; S.z /= cntf; S.w /= cntf;
        *(float4*)&h0[b * 272 + col0 + c4] = S;
    }
}

__global__ void k_demo(const float* __restrict__ dg, const float* __restrict__ w,
                       const float* __restrict__ b, float* __restrict__ h0) {
    int idx = blockIdx.x * blockDim.x + threadIdx.x;
    if (idx < NBATCH * 16) {
        int i = idx >> 4, j = idx & 15;
        float acc = b[j];
        for (int k = 0; k < 4; ++k) acc += dg[i * 4 + k] * w[k * 16 + j];
        h0[i * 272 + 256 + j] = acc;
    }
}

// fused linear + batch-norm + lrelu: one block per output column.
__global__ __launch_bounds__(128) void k_lin_bn(const float* __restrict__ in,
                                                const float* __restrict__ w,
                                                const float* __restrict__ bias,
                                                const float* __restrict__ g,
                                                const float* __restrict__ bb,
                                                float* __restrict__ out,
                                                int rows, int K, int C) {
    __shared__ float s1[128], s2[128];
    const int j = blockIdx.x;
    const int t = threadIdx.x;
    float v = 0.f;
    if (t < rows) {
        v = bias[j];
        for (int k = 0; k < K; ++k) v += in[t * K + k] * w[k * C + j];
    }
    s1[t] = (t < rows) ? v : 0.f;
    s2[t] = (t < rows) ? v * v : 0.f;
    __syncthreads();
    for (int off = 64; off > 0; off >>= 1) {
        if (t < off) { s1[t] += s1[t + off]; s2[t] += s2[t + off]; }
        __syncthreads();
    }
    const float m = s1[0] / rows;
    const float var = fmaxf(s2[0] / rows - m * m, 0.f);
    const float inv = 1.f / sqrtf(var + EPS);
    if (t < rows) out[t * C + j] = lrelu(g[j] * (v - m) * inv + bb[j]);
}

__global__ void k_linear(const float* __restrict__ in, const float* __restrict__ w,
                         const float* __restrict__ b, float* __restrict__ out,
                         int rows, int K, int D) {
    int total = rows * D;
    for (int idx = blockIdx.x * blockDim.x + threadIdx.x; idx < total; idx += gridDim.x * blockDim.x) {
        int i = idx / D, j = idx - i * D;
        float acc = b[j];
        for (int k = 0; k < K; ++k) acc += in[i * K + k] * w[k * D + j];
        out[idx] = acc;
    }
}

// ---------------- launcher ----------------

extern "C" void kernel_launch(void* const* d_in, const int* in_sizes, int n_in,
                              void* d_out, int out_size, void* d_ws, size_t ws_size,
                              hipStream_t stream) {
    const int*   x_idx  = (const int*)d_in[0];
    const int*   ei     = (const int*)d_in[1];
    const float* eattr  = (const float*)d_in[2];
    const int*   batch  = (const int*)d_in[3];
    const float* demog  = (const float*)d_in[4];
    const float* emb    = (const float*)d_in[5];
    const float* wrel1  = (const float*)d_in[6];
    const float* brel1  = (const float*)d_in[7];
    const float* wroot1 = (const float*)d_in[8];
    const float* wrel2  = (const float*)d_in[9];
    const float* brel2  = (const float*)d_in[10];
    const float* wroot2 = (const float*)d_in[11];
    const float* wrel3  = (const float*)d_in[12];
    const float* brel3  = (const float*)d_in[13];
    const float* wroot3 = (const float*)d_in[14];
    const float* gn1g = (const float*)d_in[15];
    const float* gn1b = (const float*)d_in[16];
    const float* gn1a = (const float*)d_in[17];
    const float* gn2g = (const float*)d_in[18];
    const float* gn2b = (const float*)d_in[19];
    const float* gn2a = (const float*)d_in[20];
    const float* dw   = (const float*)d_in[21];
    const float* db   = (const float*)d_in[22];
    const float* l1w  = (const float*)d_in[23];
    const float* l1b  = (const float*)d_in[24];
    const float* bn1g = (const float*)d_in[25];
    const float* bn1b = (const float*)d_in[26];
    const float* l2w  = (const float*)d_in[27];
    const float* l2b  = (const float*)d_in[28];
    const float* bn2g = (const float*)d_in[29];
    const float* bn2b = (const float*)d_in[30];
    const float* l3w  = (const float*)d_in[31];
    const float* l3b  = (const float*)d_in[32];
    float* out = (float*)d_out;

    float* W    = (float*)d_ws;
    float* x2   = W;
    float* agg2 = W + 12800000;
    float* x3   = W + 25600000;
    float* x1   = W + 25600000;
    float* agg1 = W + 32000000;
    float* x0   = W + 38400000;
    float* agg0 = W + 40000000;
    int*   csr_src  = (int*)(W + 51200000);      // NE
    float* csr_w    = W + 52800000;              // NE
    int*   rowstart = (int*)(W + 54400000);      // NN+1
    int*   deg      = (int*)(W + 54520000);      // NN (aliased as cursor)
    int*   bstart   = (int*)(W + 54640000);      // NBATCH+1
    float* h0   = W + 54641000;                  // 100*272
    float* h1   = h0 + 27200;                    // 100*128
    float* h2   = h1 + 12800;                    // 100*64

    const int* src = ei;
    const int* dst = ei + NE;

    auto gsz = [](long long t) {
        long long b = (t + 255) / 256;
        return (int)(b > 524288 ? 524288 : b);
    };
    const int nrow_blk = (NN + 63) / 64;     // 1563
    const int nagg_blk = (NN + 3) / 4;       // 4 waves/block, 1 node/wave

    // ---- CSR build (by dst); cursor aliases deg ----
    hipMemsetAsync(deg, 0, NN * sizeof(int), stream);
    k_hist<<<gsz(NE), 256, 0, stream>>>(dst, deg);
    k_scan<<<1, 1024, 0, stream>>>(deg, rowstart, deg);
    k_fill<<<gsz(NE), 256, 0, stream>>>(dst, src, eattr, deg, csr_src, csr_w);

    // batch boundaries (batch sorted)
    k_bounds<<<1, 128, 0, stream>>>(batch, bstart);

    // x0 = emb[x_idx]
    k_gather<<<gsz((long long)NN * 4), 256, 0, stream>>>(x_idx, emb, x0);

    // conv1: 16 -> 64
    k_aggregate<16><<<nagg_blk, 256, 0, stream>>>(x0, csr_src, csr_w, rowstart, agg0);
    k_conv_gemm<16, 64><<<dim3(1, nrow_blk), 256, 0, stream>>>(agg0, x0, wrel1, brel1, wroot1, x1);
    k_graphnorm<64><<<dim3(NBATCH, 1), 256, 0, stream>>>(x1, bstart, gn1a, gn1g, gn1b);

    // conv2: 64 -> 128
    k_aggregate<64><<<nagg_blk, 256, 0, stream>>>(x1, csr_src, csr_w, rowstart, agg1);
    k_conv_gemm<64, 128><<<dim3(2, nrow_blk), 256, 0, stream>>>(agg1, x1, wrel2, brel2, wroot2, x2);
    k_graphnorm<128><<<dim3(NBATCH, 2), 256, 0, stream>>>(x2, bstart, gn2a, gn2g, gn2b);

    // conv3: 128 -> 256
    k_aggregate<128><<<nagg_blk, 256, 0, stream>>>(x2, csr_src, csr_w, rowstart, agg2);
    k_conv_gemm<128, 256><<<dim3(4, nrow_blk), 256, 0, stream>>>(agg2, x2, wrel3, brel3, wroot3, x3);

    // head
    k_gf2<<<dim3(NBATCH, 4), 256, 0, stream>>>(x3, bstart, h0);
    k_demo<<<(NBATCH * 16 + 255) / 256, 256, 0, stream>>>(demog, dw, db, h0);

    k_lin_bn<<<128, 128, 0, stream>>>(h0, l1w, l1b, bn1g, bn1b, h1, NBATCH, 272, 128);
    k_lin_bn<<<64, 128, 0, stream>>>(h1, l2w, l2b, bn2g, bn2b, h2, NBATCH, 128, 64);
    k_linear<<<gsz(NBATCH * 3), 256, 0, stream>>>(h2, l3w, l3b, out, NBATCH, 64, 3);
}

// Round 11
// 901.459 us; speedup vs baseline: 2.2498x; 1.2938x over previous
//
#include <hip/hip_runtime.h>

// Problem constants (from reference)
#define NN 100000      // nodes
#define NE 1600000     // edges
#define NBATCH 100     // graphs
constexpr float EPS = 1e-5f;

typedef unsigned short ushort_t;
typedef unsigned int uint_t;

using short8 = __attribute__((ext_vector_type(8))) short;   // 8 bf16 (4 VGPRs)
using floatx4 = __attribute__((ext_vector_type(4))) float;  // 4 fp32 acc

__device__ __forceinline__ float lrelu(float x) { return x > 0.f ? x : 0.01f * x; }

__device__ __forceinline__ float b2f(ushort_t u) {
    union { uint_t i; float f; } c; c.i = ((uint_t)u) << 16; return c.f;
}
__device__ __forceinline__ ushort_t f2b(float f) {
    union { float f; uint_t i; } c; c.f = f;
    uint_t u = c.i;
    return (ushort_t)((u + 0x7FFFu + ((u >> 16) & 1u)) >> 16);   // RNE
}
__device__ __forceinline__ void unpack8(const uint4 u, float* f) {
    f[0] = b2f(u.x & 0xffff); f[1] = b2f(u.x >> 16);
    f[2] = b2f(u.y & 0xffff); f[3] = b2f(u.y >> 16);
    f[4] = b2f(u.z & 0xffff); f[5] = b2f(u.z >> 16);
    f[6] = b2f(u.w & 0xffff); f[7] = b2f(u.w >> 16);
}

// ---------------- CSR build ----------------

__global__ void k_hist(const int* __restrict__ dst, int* __restrict__ deg) {
    for (int e = blockIdx.x * blockDim.x + threadIdx.x; e < NE; e += gridDim.x * blockDim.x)
        atomicAdd(&deg[dst[e]], 1);
}

__global__ __launch_bounds__(1024) void k_scan(const int* __restrict__ deg,
                                               int* __restrict__ rowstart,
                                               int* __restrict__ cursor) {
    __shared__ int part[1024];
    const int t = threadIdx.x;
    const int chunk = 100;
    const int beg = t * chunk;
    const int end = (beg + chunk < NN) ? beg + chunk : NN;
    int s = 0;
    for (int i = beg; i < end; i += 4) {
        const int4 d4 = *(const int4*)&deg[i];
        s += d4.x + d4.y + d4.z + d4.w;
    }
    part[t] = s;
    __syncthreads();
    for (int off = 1; off < 1024; off <<= 1) {
        int other = (t >= off) ? part[t - off] : 0;
        __syncthreads();
        part[t] += other;
        __syncthreads();
    }
    int run = part[t] - s;
    for (int i = beg; i < end; i += 4) {
        const int4 d4 = *(const int4*)&deg[i];    // read BEFORE cursor write (alias)
        int4 r;
        r.x = run; r.y = r.x + d4.x; r.z = r.y + d4.y; r.w = r.z + d4.z;
        run = r.w + d4.w;
        *(int4*)&rowstart[i] = r;
        *(int4*)&cursor[i] = r;
    }
    if (t == 0) rowstart[NN] = NE;
}

__global__ void k_fill(const int* __restrict__ dst, const int* __restrict__ srcv,
                       const float* __restrict__ ew, int* __restrict__ cursor,
                       int* __restrict__ csr_src, float* __restrict__ csr_w) {
    for (int e = blockIdx.x * blockDim.x + threadIdx.x; e < NE; e += gridDim.x * blockDim.x) {
        int pos = atomicAdd(&cursor[dst[e]], 1);
        csr_src[pos] = srcv[e];
        csr_w[pos] = ew[e];
    }
}

__global__ void k_bounds(const int* __restrict__ batch, int* __restrict__ bstart) {
    int b = blockIdx.x * blockDim.x + threadIdx.x;
    if (b > NBATCH) return;
    int lo = 0, hi = NN;
    while (lo < hi) {
        int mid = (lo + hi) >> 1;
        if (batch[mid] < b) lo = mid + 1; else hi = mid;
    }
    bstart[b] = lo;
}

// ---------------- weight pack: wcatT[n*K2 + k], k<K from wrel, k>=K from wroot (bf16) ---------

__global__ void k_wpack(const float* __restrict__ wr1, const float* __restrict__ wo1,
                        const float* __restrict__ wr2, const float* __restrict__ wo2,
                        const float* __restrict__ wr3, const float* __restrict__ wo3,
                        ushort_t* __restrict__ w1T, ushort_t* __restrict__ w2T,
                        ushort_t* __restrict__ w3T) {
    int idx = blockIdx.x * blockDim.x + threadIdx.x;
    if (idx < 2048) {                                  // conv1: DOUT=64, K2=32
        int n = idx >> 5, k = idx & 31;
        float v = (k < 16) ? wr1[k * 64 + n] : wo1[(k - 16) * 64 + n];
        w1T[idx] = f2b(v);
    } else if (idx < 2048 + 16384) {                   // conv2: DOUT=128, K2=128
        int l = idx - 2048; int n = l >> 7, k = l & 127;
        float v = (k < 64) ? wr2[k * 128 + n] : wo2[(k - 64) * 128 + n];
        w2T[l] = f2b(v);
    } else if (idx < 2048 + 16384 + 65536) {           // conv3: DOUT=256, K2=256
        int l = idx - 18432; int n = l >> 8, k = l & 255;
        float v = (k < 128) ? wr3[k * 256 + n] : wo3[(k - 128) * 256 + n];
        w3T[l] = f2b(v);
    }
}

// ---------------- embedding gather -> bf16 x-half of xcat0 (cols 16..31, stride 32) ----------

__global__ void k_gather_b(const int* __restrict__ xi, const float* __restrict__ emb,
                           ushort_t* __restrict__ xcat0) {
    int n = blockIdx.x * blockDim.x + threadIdx.x;
    if (n >= NN) return;
    const float* e = emb + ((size_t)xi[n] << 4);
    uint_t u[8];
#pragma unroll
    for (int j = 0; j < 8; ++j)
        u[j] = (uint_t)f2b(e[2 * j]) | ((uint_t)f2b(e[2 * j + 1]) << 16);
    uint4* o = (uint4*)(xcat0 + (size_t)n * 32 + 16);
    o[0] = {u[0], u[1], u[2], u[3]};
    o[1] = {u[4], u[5], u[6], u[7]};
}

// ---------------- aggregate (bf16 in/out): xcat row = [agg(0..D-1) | x(D..2D-1)] ------------
// one wave per node; EP edge-groups in parallel, 2x unrolled; shfl_xor reduce.

template <int D>
__global__ void k_aggregate_b(ushort_t* __restrict__ xcat, const int* __restrict__ csr_src,
                              const float* __restrict__ csr_w, const int* __restrict__ rowstart) {
    constexpr int LPN = D / 8;           // lanes per node (8 bf16 each)
    constexpr int EP = 64 / LPN;
    const int n = blockIdx.x * 4 + (threadIdx.x >> 6);
    const int lane = threadIdx.x & 63;
    const int sl = lane % LPN;
    const int eg = lane / LPN;
    if (n >= NN) return;
    const int beg = rowstart[n], end = rowstart[n + 1];
    float a0[8] = {}, a1[8] = {};
    int i = beg + eg;
    for (; i + EP < end; i += 2 * EP) {
        const int s0 = csr_src[i];       const float w0 = csr_w[i];
        const int s1 = csr_src[i + EP];  const float w1 = csr_w[i + EP];
        const uint4 u0 = *(const uint4*)(xcat + (size_t)s0 * (2 * D) + D + sl * 8);
        const uint4 u1 = *(const uint4*)(xcat + (size_t)s1 * (2 * D) + D + sl * 8);
        float f0[8], f1[8];
        unpack8(u0, f0); unpack8(u1, f1);
#pragma unroll
        for (int j = 0; j < 8; ++j) { a0[j] += f0[j] * w0; a1[j] += f1[j] * w1; }
    }
    if (i < end) {
        const int s0 = csr_src[i];
        const float w0 = csr_w[i];
        const uint4 u0 = *(const uint4*)(xcat + (size_t)s0 * (2 * D) + D + sl * 8);
        float f0[8];
        unpack8(u0, f0);
#pragma unroll
        for (int j = 0; j < 8; ++j) a0[j] += f0[j] * w0;
    }
#pragma unroll
    for (int j = 0; j < 8; ++j) a0[j] += a1[j];
#pragma unroll
    for (int m = LPN; m < 64; m <<= 1)
#pragma unroll
        for (int j = 0; j < 8; ++j) a0[j] += __shfl_xor(a0[j], m);
    if (eg == 0) {
        uint_t u[4];
#pragma unroll
        for (int j = 0; j < 4; ++j)
            u[j] = (uint_t)f2b(a0[2 * j]) | ((uint_t)f2b(a0[2 * j + 1]) << 16);
        *(uint4*)(xcat + (size_t)n * (2 * D) + sl * 8) = {u[0], u[1], u[2], u[3]};
    }
}

// ---------------- conv GEMM via bf16 MFMA ---------------------------------------------------
// out[n, 0..DOUT) = xcat[n, 0..K2) @ wcatT^T + brel   (K2 = 2*DIN, [agg|x] @ [wrel;wroot])
// wave = 16-row tile x full DOUT. Layouts (HW-verified per guide):
//   A[m=lane&15][k=quad*8+j], B^T rows loaded identically, C/D: col=lane&15, row=quad*4+reg.

template <int K2, int DOUT, bool BOUT>
__global__ __launch_bounds__(256) void k_conv_mfma(
        const ushort_t* __restrict__ xcat, const ushort_t* __restrict__ wcatT,
        const float* __restrict__ brel, void* __restrict__ outp) {
    constexpr int NCT = DOUT / 16;
    const int lane = threadIdx.x & 63;
    const int wv = threadIdx.x >> 6;
    const int r0 = blockIdx.x * 64 + wv * 16;
    if (r0 >= NN) return;                    // NN % 16 == 0: tiles never straddle
    const int m = lane & 15;
    const int quad = lane >> 4;

    floatx4 acc[NCT] = {};

    const ushort_t* arow = xcat + (size_t)(r0 + m) * K2 + quad * 8;
    for (int kk = 0; kk < K2; kk += 32) {
        const short8 a = *(const short8*)(arow + kk);
#pragma unroll
        for (int c = 0; c < NCT; ++c) {
            const short8 b = *(const short8*)(wcatT + (size_t)(c * 16 + m) * K2 + kk + quad * 8);
            acc[c] = __builtin_amdgcn_mfma_f32_16x16x32_bf16(a, b, acc[c], 0, 0, 0);
        }
    }
#pragma unroll
    for (int c = 0; c < NCT; ++c) {
        const int col = c * 16 + m;
        const float bias = brel[col];
#pragma unroll
        for (int r = 0; r < 4; ++r) {
            const int row = r0 + quad * 4 + r;
            const float v = acc[c][r] + bias;
            if constexpr (BOUT) ((ushort_t*)outp)[(size_t)row * DOUT + col] = f2b(v);
            else                ((float*)outp)[(size_t)row * DOUT + col] = v;
        }
    }
}

// ---------------- graph-norm + lrelu: fp32 in -> bf16 out (into xcat x-half) ----------------
// block 256 = 16 col-lanes (x4 cols) x 16 row-groups; grid (NBATCH, D/64).
// var(xc) = E[x^2] - m^2 (2a - a^2), m = E[x], xc = x - a*m.

template <int D, int OST>
__global__ __launch_bounds__(256) void k_graphnorm(
        const float* __restrict__ xf, ushort_t* __restrict__ xout,
        const int* __restrict__ bstart, const float* __restrict__ a,
        const float* __restrict__ g, const float* __restrict__ bb) {
    __shared__ float4 reds[256];
    __shared__ float4 redq[256];
    __shared__ float smean[64];
    __shared__ float sinv[64];
    const int b = blockIdx.x;
    const int col0 = blockIdx.y * 64;
    const int c4 = (threadIdx.x & 15) * 4;
    const int rg = threadIdx.x >> 4;
    const int beg = bstart[b], end = bstart[b + 1];
    const float cntf = fmaxf((float)(end - beg), 1.f);

    float4 s = {0.f, 0.f, 0.f, 0.f}, q = {0.f, 0.f, 0.f, 0.f};
    for (int r = beg + rg; r < end; r += 16) {
        const float4 v = *(const float4*)&xf[(size_t)r * D + col0 + c4];
        s.x += v.x; s.y += v.y; s.z += v.z; s.w += v.w;
        q.x += v.x * v.x; q.y += v.y * v.y; q.z += v.z * v.z; q.w += v.w * v.w;
    }
    reds[threadIdx.x] = s;
    redq[threadIdx.x] = q;
    __syncthreads();
    if (rg == 0) {
        float4 S = reds[threadIdx.x], Q = redq[threadIdx.x];
        for (int k = 1; k < 16; ++k) {
            const float4 s2 = reds[threadIdx.x + 16 * k];
            const float4 q2 = redq[threadIdx.x + 16 * k];
            S.x += s2.x; S.y += s2.y; S.z += s2.z; S.w += s2.w;
            Q.x += q2.x; Q.y += q2.y; Q.z += q2.z; Q.w += q2.w;
        }
        const float4 al = *(const float4*)&a[col0 + c4];
        const float Sv[4] = {S.x, S.y, S.z, S.w};
        const float Qv[4] = {Q.x, Q.y, Q.z, Q.w};
        const float av[4] = {al.x, al.y, al.z, al.w};
#pragma unroll
        for (int c = 0; c < 4; ++c) {
            const float mm = Sv[c] / cntf;
            const float ex2 = Qv[c] / cntf;
            const float var = fmaxf(ex2 - mm * mm * (2.f * av[c] - av[c] * av[c]), 0.f);
            smean[c4 + c] = mm;
            sinv[c4 + c] = 1.f / sqrtf(var + EPS);
        }
    }
    __syncthreads();
    const float4 mean4 = *(const float4*)&smean[c4];
    const float4 inv4 = *(const float4*)&sinv[c4];
    const float4 al4 = *(const float4*)&a[col0 + c4];
    const float4 g4 = *(const float4*)&g[col0 + c4];
    const float4 bb4 = *(const float4*)&bb[col0 + c4];
    for (int r = beg + rg; r < end; r += 16) {
        const float4 v = *(const float4*)&xf[(size_t)r * D + col0 + c4];
        float y0 = lrelu(g4.x * (v.x - al4.x * mean4.x) * inv4.x + bb4.x);
        float y1 = lrelu(g4.y * (v.y - al4.y * mean4.y) * inv4.y + bb4.y);
        float y2 = lrelu(g4.z * (v.z - al4.z * mean4.z) * inv4.z + bb4.z);
        float y3 = lrelu(g4.w * (v.w - al4.w * mean4.w) * inv4.w + bb4.w);
        uint2 o;
        o.x = (uint_t)f2b(y0) | ((uint_t)f2b(y1) << 16);
        o.y = (uint_t)f2b(y2) | ((uint_t)f2b(y3) << 16);
        *(uint2*)&xout[(size_t)r * OST + col0 + c4] = o;
    }
}

// ---------------- graph-feature mean: bf16 x3 -> h0 (stride 272, cols 0..255) ---------------

__global__ __launch_bounds__(256) void k_gf2b(const ushort_t* __restrict__ x3b,
                                              const int* __restrict__ bstart,
                                              float* __restrict__ h0) {
    __shared__ float4 red[256];
    const int b = blockIdx.x;
    const int col0 = blockIdx.y * 64;
    const int c4 = (threadIdx.x & 15) * 4;
    const int rg = threadIdx.x >> 4;
    const int beg = bstart[b], end = bstart[b + 1];
    const float cntf = fmaxf((float)(end - beg), 1.f);
    float4 s = {0.f, 0.f, 0.f, 0.f};
    for (int r = beg + rg; r < end; r += 16) {
        const uint2 u = *(const uint2*)&x3b[(size_t)r * 256 + col0 + c4];
        s.x += b2f(u.x & 0xffff); s.y += b2f(u.x >> 16);
        s.z += b2f(u.y & 0xffff); s.w += b2f(u.y >> 16);
    }
    red[threadIdx.x] = s;
    __syncthreads();
    if (rg == 0) {
        float4 S = red[threadIdx.x];
        for (int k = 1; k < 16; ++k) {
            const float4 s2 = red[threadIdx.x + 16 * k];
            S.x += s2.x; S.y += s2.y; S.z += s2.z; S.w += s2.w;
        }
        S.x /= cntf; S.y /= cntf; S.z /= cntf; S.w /= cntf;
        *(float4*)&h0[b * 272 + col0 + c4] = S;
    }
}

__global__ void k_demo(const float* __restrict__ dg, const float* __restrict__ w,
                       const float* __restrict__ b, float* __restrict__ h0) {
    int idx = blockIdx.x * blockDim.x + threadIdx.x;
    if (idx < NBATCH * 16) {
        int i = idx >> 4, j = idx & 15;
        float acc = b[j];
        for (int k = 0; k < 4; ++k) acc += dg[i * 4 + k] * w[k * 16 + j];
        h0[i * 272 + 256 + j] = acc;
    }
}

// fused linear + batch-norm + lrelu (fp32 head)
__global__ __launch_bounds__(128) void k_lin_bn(const float* __restrict__ in,
                                                const float* __restrict__ w,
                                                const float* __restrict__ bias,
                                                const float* __restrict__ g,
                                                const float* __restrict__ bb,
                                                float* __restrict__ out,
                                                int rows, int K, int C) {
    __shared__ float s1[128], s2[128];
    const int j = blockIdx.x;
    const int t = threadIdx.x;
    float v = 0.f;
    if (t < rows) {
        v = bias[j];
        for (int k = 0; k < K; ++k) v += in[t * K + k] * w[k * C + j];
    }
    s1[t] = (t < rows) ? v : 0.f;
    s2[t] = (t < rows) ? v * v : 0.f;
    __syncthreads();
    for (int off = 64; off > 0; off >>= 1) {
        if (t < off) { s1[t] += s1[t + off]; s2[t] += s2[t + off]; }
        __syncthreads();
    }
    const float m = s1[0] / rows;
    const float var = fmaxf(s2[0] / rows - m * m, 0.f);
    const float inv = 1.f / sqrtf(var + EPS);
    if (t < rows) out[t * C + j] = lrelu(g[j] * (v - m) * inv + bb[j]);
}

__global__ void k_linear(const float* __restrict__ in, const float* __restrict__ w,
                         const float* __restrict__ b, float* __restrict__ out,
                         int rows, int K, int D) {
    int total = rows * D;
    for (int idx = blockIdx.x * blockDim.x + threadIdx.x; idx < total; idx += gridDim.x * blockDim.x) {
        int i = idx / D, j = idx - i * D;
        float acc = b[j];
        for (int k = 0; k < K; ++k) acc += in[i * K + k] * w[k * D + j];
        out[idx] = acc;
    }
}

// ---------------- launcher ----------------

extern "C" void kernel_launch(void* const* d_in, const int* in_sizes, int n_in,
                              void* d_out, int out_size, void* d_ws, size_t ws_size,
                              hipStream_t stream) {
    const int*   x_idx  = (const int*)d_in[0];
    const int*   ei     = (const int*)d_in[1];
    const float* eattr  = (const float*)d_in[2];
    const int*   batch  = (const int*)d_in[3];
    const float* demog  = (const float*)d_in[4];
    const float* emb    = (const float*)d_in[5];
    const float* wrel1  = (const float*)d_in[6];
    const float* brel1  = (const float*)d_in[7];
    const float* wroot1 = (const float*)d_in[8];
    const float* wrel2  = (const float*)d_in[9];
    const float* brel2  = (const float*)d_in[10];
    const float* wroot2 = (const float*)d_in[11];
    const float* wrel3  = (const float*)d_in[12];
    const float* brel3  = (const float*)d_in[13];
    const float* wroot3 = (const float*)d_in[14];
    const float* gn1g = (const float*)d_in[15];
    const float* gn1b = (const float*)d_in[16];
    const float* gn1a = (const float*)d_in[17];
    const float* gn2g = (const float*)d_in[18];
    const float* gn2b = (const float*)d_in[19];
    const float* gn2a = (const float*)d_in[20];
    const float* dw   = (const float*)d_in[21];
    const float* db   = (const float*)d_in[22];
    const float* l1w  = (const float*)d_in[23];
    const float* l1b  = (const float*)d_in[24];
    const float* bn1g = (const float*)d_in[25];
    const float* bn1b = (const float*)d_in[26];
    const float* l2w  = (const float*)d_in[27];
    const float* l2b  = (const float*)d_in[28];
    const float* bn2g = (const float*)d_in[29];
    const float* bn2b = (const float*)d_in[30];
    const float* l3w  = (const float*)d_in[31];
    const float* l3b  = (const float*)d_in[32];
    float* out = (float*)d_out;

    // workspace (float offsets): ~199.7 MB total
    float*    W     = (float*)d_ws;
    float*    xf    = W;                                   // fp32 conv out, 12.8M (conv1/conv2 share)
    ushort_t* x3b   = (ushort_t*)(W + 12800000);           // NN*256 bf16
    ushort_t* xcat0 = (ushort_t*)(W + 25600000);           // NN*32 bf16  [agg0|x0]
    ushort_t* xcat1 = (ushort_t*)(W + 27200000);           // NN*128 bf16 [agg1|x1]
    ushort_t* xcat2 = (ushort_t*)(W + 33600000);           // NN*256 bf16 [agg2|x2]
    ushort_t* w1T   = (ushort_t*)(W + 46400000);           // 2048
    ushort_t* w2T   = w1T + 2048;                          // 16384
    ushort_t* w3T   = w2T + 16384;                         // 65536
    int*      csr_src  = (int*)(W + 46450000);             // NE
    float*    csr_w    = W + 48050000;                     // NE
    int*      rowstart = (int*)(W + 49650000);             // NN+1
    int*      deg      = (int*)(W + 49770000);             // NN (aliased as cursor)
    int*      bstart   = (int*)(W + 49890000);             // NBATCH+1
    float*    h0 = W + 49891000;                           // 100*272
    float*    h1 = h0 + 27200;
    float*    h2 = h1 + 12800;

    const int* src = ei;
    const int* dst = ei + NE;

    auto gsz = [](long long t) {
        long long b = (t + 255) / 256;
        return (int)(b > 524288 ? 524288 : b);
    };
    const int mfma_blk = (NN + 63) / 64;     // 1563 (4 waves x 16 rows)
    const int nagg_blk = (NN + 3) / 4;       // 1 node/wave, 4 waves/block

    // ---- CSR build (by dst); cursor aliases deg ----
    hipMemsetAsync(deg, 0, NN * sizeof(int), stream);
    k_hist<<<gsz(NE), 256, 0, stream>>>(dst, deg);
    k_scan<<<1, 1024, 0, stream>>>(deg, rowstart, deg);
    k_fill<<<gsz(NE), 256, 0, stream>>>(dst, src, eattr, deg, csr_src, csr_w);

    k_bounds<<<1, 128, 0, stream>>>(batch, bstart);
    k_wpack<<<(83968 + 255) / 256, 256, 0, stream>>>(wrel1, wroot1, wrel2, wroot2, wrel3, wroot3,
                                                     w1T, w2T, w3T);

    // x0 (bf16) into xcat0 x-half
    k_gather_b<<<(NN + 255) / 256, 256, 0, stream>>>(x_idx, emb, xcat0);

    // conv1: [agg0|x0](K2=32) @ w1T -> xf (fp32 NN x 64)
    k_aggregate_b<16><<<nagg_blk, 256, 0, stream>>>(xcat0, csr_src, csr_w, rowstart);
    k_conv_mfma<32, 64, false><<<mfma_blk, 256, 0, stream>>>(xcat0, w1T, brel1, xf);
    k_graphnorm<64, 128><<<dim3(NBATCH, 1), 256, 0, stream>>>(xf, xcat1 + 64, bstart, gn1a, gn1g, gn1b);

    // conv2: [agg1|x1](K2=128) @ w2T -> xf (fp32 NN x 128)
    k_aggregate_b<64><<<nagg_blk, 256, 0, stream>>>(xcat1, csr_src, csr_w, rowstart);
    k_conv_mfma<128, 128, false><<<mfma_blk, 256, 0, stream>>>(xcat1, w2T, brel2, xf);
    k_graphnorm<128, 256><<<dim3(NBATCH, 2), 256, 0, stream>>>(xf, xcat2 + 128, bstart, gn2a, gn2g, gn2b);

    // conv3: [agg2|x2](K2=256) @ w3T -> x3b (bf16 NN x 256)
    k_aggregate_b<128><<<nagg_blk, 256, 0, stream>>>(xcat2, csr_src, csr_w, rowstart);
    k_conv_mfma<256, 256, true><<<mfma_blk, 256, 0, stream>>>(xcat2, w3T, brel3, x3b);

    // head
    k_gf2b<<<dim3(NBATCH, 4), 256, 0, stream>>>(x3b, bstart, h0);
    k_demo<<<(NBATCH * 16 + 255) / 256, 256, 0, stream>>>(demog, dw, db, h0);
    k_lin_bn<<<128, 128, 0, stream>>>(h0, l1w, l1b, bn1g, bn1b, h1, NBATCH, 272, 128);
    k_lin_bn<<<64, 128, 0, stream>>>(h1, l2w, l2b, bn2g, bn2b, h2, NBATCH, 128, 64);
    k_linear<<<gsz(NBATCH * 3), 256, 0, stream>>>(h2, l3w, l3b, out, NBATCH, 64, 3);
}

// Round 12
// 883.303 us; speedup vs baseline: 2.2960x; 1.0206x over previous
//
#include <hip/hip_runtime.h>

// Problem constants (from reference)
#define NN 100000      // nodes
#define NE 1600000     // edges
#define NBATCH 100     // graphs
constexpr float EPS = 1e-5f;

typedef unsigned short ushort_t;
typedef unsigned int uint_t;

using short8 = __attribute__((ext_vector_type(8))) short;   // 8 bf16 (4 VGPRs)
using floatx4 = __attribute__((ext_vector_type(4))) float;  // 4 fp32 acc

__device__ __forceinline__ float lrelu(float x) { return x > 0.f ? x : 0.01f * x; }

__device__ __forceinline__ float b2f(ushort_t u) {
    union { uint_t i; float f; } c; c.i = ((uint_t)u) << 16; return c.f;
}
__device__ __forceinline__ ushort_t f2b(float f) {
    union { float f; uint_t i; } c; c.f = f;
    uint_t u = c.i;
    return (ushort_t)((u + 0x7FFFu + ((u >> 16) & 1u)) >> 16);   // RNE
}
__device__ __forceinline__ void unpack8(const uint4 u, float* f) {
    f[0] = b2f(u.x & 0xffff); f[1] = b2f(u.x >> 16);
    f[2] = b2f(u.y & 0xffff); f[3] = b2f(u.y >> 16);
    f[4] = b2f(u.z & 0xffff); f[5] = b2f(u.z >> 16);
    f[6] = b2f(u.w & 0xffff); f[7] = b2f(u.w >> 16);
}

// ---------------- CSR build ----------------

__global__ void k_hist(const int* __restrict__ dst, int* __restrict__ deg) {
    for (int e = blockIdx.x * blockDim.x + threadIdx.x; e < NE; e += gridDim.x * blockDim.x)
        atomicAdd(&deg[dst[e]], 1);
}

__global__ __launch_bounds__(1024) void k_scan(const int* __restrict__ deg,
                                               int* __restrict__ rowstart,
                                               int* __restrict__ cursor) {
    __shared__ int part[1024];
    const int t = threadIdx.x;
    const int chunk = 100;
    const int beg = t * chunk;
    const int end = (beg + chunk < NN) ? beg + chunk : NN;
    int s = 0;
    for (int i = beg; i < end; i += 4) {
        const int4 d4 = *(const int4*)&deg[i];
        s += d4.x + d4.y + d4.z + d4.w;
    }
    part[t] = s;
    __syncthreads();
    for (int off = 1; off < 1024; off <<= 1) {
        int other = (t >= off) ? part[t - off] : 0;
        __syncthreads();
        part[t] += other;
        __syncthreads();
    }
    int run = part[t] - s;
    for (int i = beg; i < end; i += 4) {
        const int4 d4 = *(const int4*)&deg[i];    // read BEFORE cursor write (alias)
        int4 r;
        r.x = run; r.y = r.x + d4.x; r.z = r.y + d4.y; r.w = r.z + d4.z;
        run = r.w + d4.w;
        *(int4*)&rowstart[i] = r;
        *(int4*)&cursor[i] = r;
    }
    if (t == 0) rowstart[NN] = NE;
}

// scatter (src, w) pairs into dst-sorted order — ONE 8B store per edge
__global__ void k_fill(const int* __restrict__ dst, const int* __restrict__ srcv,
                       const float* __restrict__ ew, int* __restrict__ cursor,
                       int2* __restrict__ csr_pair) {
    for (int e = blockIdx.x * blockDim.x + threadIdx.x; e < NE; e += gridDim.x * blockDim.x) {
        int pos = atomicAdd(&cursor[dst[e]], 1);
        csr_pair[pos] = make_int2(srcv[e], __float_as_int(ew[e]));
    }
}

__global__ void k_bounds(const int* __restrict__ batch, int* __restrict__ bstart) {
    int b = blockIdx.x * blockDim.x + threadIdx.x;
    if (b > NBATCH) return;
    int lo = 0, hi = NN;
    while (lo < hi) {
        int mid = (lo + hi) >> 1;
        if (batch[mid] < b) lo = mid + 1; else hi = mid;
    }
    bstart[b] = lo;
}

// ---------------- weight pack: wcatT[n*K2 + k] (bf16) ----------------------------------------

__global__ void k_wpack(const float* __restrict__ wr1, const float* __restrict__ wo1,
                        const float* __restrict__ wr2, const float* __restrict__ wo2,
                        const float* __restrict__ wr3, const float* __restrict__ wo3,
                        ushort_t* __restrict__ w1T, ushort_t* __restrict__ w2T,
                        ushort_t* __restrict__ w3T) {
    int idx = blockIdx.x * blockDim.x + threadIdx.x;
    if (idx < 2048) {                                  // conv1: DOUT=64, K2=32
        int n = idx >> 5, k = idx & 31;
        float v = (k < 16) ? wr1[k * 64 + n] : wo1[(k - 16) * 64 + n];
        w1T[idx] = f2b(v);
    } else if (idx < 2048 + 16384) {                   // conv2: DOUT=128, K2=128
        int l = idx - 2048; int n = l >> 7, k = l & 127;
        float v = (k < 64) ? wr2[k * 128 + n] : wo2[(k - 64) * 128 + n];
        w2T[l] = f2b(v);
    } else if (idx < 2048 + 16384 + 65536) {           // conv3: DOUT=256, K2=256
        int l = idx - 18432; int n = l >> 8, k = l & 255;
        float v = (k < 128) ? wr3[k * 256 + n] : wo3[(k - 128) * 256 + n];
        w3T[l] = f2b(v);
    }
}

// ---------------- embedding gather -> bf16 x-half of xcat0 (cols 16..31, stride 32) ----------

__global__ void k_gather_b(const int* __restrict__ xi, const float* __restrict__ emb,
                           ushort_t* __restrict__ xcat0) {
    int n = blockIdx.x * blockDim.x + threadIdx.x;
    if (n >= NN) return;
    const float* e = emb + ((size_t)xi[n] << 4);
    uint_t u[8];
#pragma unroll
    for (int j = 0; j < 8; ++j)
        u[j] = (uint_t)f2b(e[2 * j]) | ((uint_t)f2b(e[2 * j + 1]) << 16);
    uint4* o = (uint4*)(xcat0 + (size_t)n * 32 + 16);
    o[0] = {u[0], u[1], u[2], u[3]};
    o[1] = {u[4], u[5], u[6], u[7]};
}

// ---------------- aggregate (bf16 in/out): xcat row = [agg(0..D-1) | x(D..2D-1)] ------------

template <int D>
__global__ void k_aggregate_b(ushort_t* __restrict__ xcat, const int2* __restrict__ csr_pair,
                              const int* __restrict__ rowstart) {
    constexpr int LPN = D / 8;           // lanes per node (8 bf16 each)
    constexpr int EP = 64 / LPN;
    const int n = blockIdx.x * 4 + (threadIdx.x >> 6);
    const int lane = threadIdx.x & 63;
    const int sl = lane % LPN;
    const int eg = lane / LPN;
    if (n >= NN) return;
    const int beg = rowstart[n], end = rowstart[n + 1];
    float a0[8] = {}, a1[8] = {};
    int i = beg + eg;
    for (; i + EP < end; i += 2 * EP) {
        const int2 p0 = csr_pair[i];
        const int2 p1 = csr_pair[i + EP];
        const float w0 = __int_as_float(p0.y);
        const float w1 = __int_as_float(p1.y);
        const uint4 u0 = *(const uint4*)(xcat + (size_t)p0.x * (2 * D) + D + sl * 8);
        const uint4 u1 = *(const uint4*)(xcat + (size_t)p1.x * (2 * D) + D + sl * 8);
        float f0[8], f1[8];
        unpack8(u0, f0); unpack8(u1, f1);
#pragma unroll
        for (int j = 0; j < 8; ++j) { a0[j] += f0[j] * w0; a1[j] += f1[j] * w1; }
    }
    if (i < end) {
        const int2 p0 = csr_pair[i];
        const float w0 = __int_as_float(p0.y);
        const uint4 u0 = *(const uint4*)(xcat + (size_t)p0.x * (2 * D) + D + sl * 8);
        float f0[8];
        unpack8(u0, f0);
#pragma unroll
        for (int j = 0; j < 8; ++j) a0[j] += f0[j] * w0;
    }
#pragma unroll
    for (int j = 0; j < 8; ++j) a0[j] += a1[j];
#pragma unroll
    for (int m = LPN; m < 64; m <<= 1)
#pragma unroll
        for (int j = 0; j < 8; ++j) a0[j] += __shfl_xor(a0[j], m);
    if (eg == 0) {
        uint_t u[4];
#pragma unroll
        for (int j = 0; j < 4; ++j)
            u[j] = (uint_t)f2b(a0[2 * j]) | ((uint_t)f2b(a0[2 * j + 1]) << 16);
        *(uint4*)(xcat + (size_t)n * (2 * D) + sl * 8) = {u[0], u[1], u[2], u[3]};
    }
}

// ---------------- conv GEMM via bf16 MFMA ---------------------------------------------------
// out[n, 0..DOUT) = xcat[n, 0..K2) @ wcatT^T + brel   (K2 = 2*DIN)
// Block = 64 rows x full DOUT; wave wv handles CW=DOUT/64 column tiles x 4 row tiles.
// B-fragments reused across 4 row tiles, A across CW col tiles: 16 MFMA per 8 loads.

template <int K2, int DOUT, bool BOUT>
__global__ __launch_bounds__(256) void k_conv_mfma(
        const ushort_t* __restrict__ xcat, const ushort_t* __restrict__ wcatT,
        const float* __restrict__ brel, void* __restrict__ outp) {
    constexpr int CW = DOUT / 64;          // col tiles per wave (1, 2, 4)
    const int lane = threadIdx.x & 63;
    const int wv = threadIdx.x >> 6;
    const int m = lane & 15;
    const int quad = lane >> 4;
    const int r0 = blockIdx.x * 64;

    floatx4 acc[4][CW] = {};

    const ushort_t* arow[4];
#pragma unroll
    for (int r = 0; r < 4; ++r) {
        int an = r0 + r * 16 + m; if (an >= NN) an = NN - 1;
        arow[r] = xcat + (size_t)an * K2 + quad * 8;
    }
    const ushort_t* brow[CW];
#pragma unroll
    for (int c = 0; c < CW; ++c)
        brow[c] = wcatT + (size_t)((wv * CW + c) * 16 + m) * K2 + quad * 8;

    for (int kk = 0; kk < K2; kk += 32) {
        short8 a[4], b[CW];
#pragma unroll
        for (int r = 0; r < 4; ++r) a[r] = *(const short8*)(arow[r] + kk);
#pragma unroll
        for (int c = 0; c < CW; ++c) b[c] = *(const short8*)(brow[c] + kk);
#pragma unroll
        for (int r = 0; r < 4; ++r)
#pragma unroll
            for (int c = 0; c < CW; ++c)
                acc[r][c] = __builtin_amdgcn_mfma_f32_16x16x32_bf16(a[r], b[c], acc[r][c], 0, 0, 0);
    }

#pragma unroll
    for (int c = 0; c < CW; ++c) {
        const int col = (wv * CW + c) * 16 + m;
        const float bias = brel[col];
#pragma unroll
        for (int r = 0; r < 4; ++r) {
#pragma unroll
            for (int rr = 0; rr < 4; ++rr) {
                const int row = r0 + r * 16 + quad * 4 + rr;
                if (row < NN) {
                    const float v = acc[r][c][rr] + bias;
                    if constexpr (BOUT) ((ushort_t*)outp)[(size_t)row * DOUT + col] = f2b(v);
                    else                ((float*)outp)[(size_t)row * DOUT + col] = v;
                }
            }
        }
    }
}

// ---------------- graph-norm + lrelu: fp32 in -> bf16 out (into xcat x-half) ----------------

template <int D, int OST>
__global__ __launch_bounds__(256) void k_graphnorm(
        const float* __restrict__ xf, ushort_t* __restrict__ xout,
        const int* __restrict__ bstart, const float* __restrict__ a,
        const float* __restrict__ g, const float* __restrict__ bb) {
    __shared__ float4 reds[256];
    __shared__ float4 redq[256];
    __shared__ float smean[64];
    __shared__ float sinv[64];
    const int b = blockIdx.x;
    const int col0 = blockIdx.y * 64;
    const int c4 = (threadIdx.x & 15) * 4;
    const int rg = threadIdx.x >> 4;
    const int beg = bstart[b], end = bstart[b + 1];
    const float cntf = fmaxf((float)(end - beg), 1.f);

    float4 s = {0.f, 0.f, 0.f, 0.f}, q = {0.f, 0.f, 0.f, 0.f};
    for (int r = beg + rg; r < end; r += 16) {
        const float4 v = *(const float4*)&xf[(size_t)r * D + col0 + c4];
        s.x += v.x; s.y += v.y; s.z += v.z; s.w += v.w;
        q.x += v.x * v.x; q.y += v.y * v.y; q.z += v.z * v.z; q.w += v.w * v.w;
    }
    reds[threadIdx.x] = s;
    redq[threadIdx.x] = q;
    __syncthreads();
    if (rg == 0) {
        float4 S = reds[threadIdx.x], Q = redq[threadIdx.x];
        for (int k = 1; k < 16; ++k) {
            const float4 s2 = reds[threadIdx.x + 16 * k];
            const float4 q2 = redq[threadIdx.x + 16 * k];
            S.x += s2.x; S.y += s2.y; S.z += s2.z; S.w += s2.w;
            Q.x += q2.x; Q.y += q2.y; Q.z += q2.z; Q.w += q2.w;
        }
        const float4 al = *(const float4*)&a[col0 + c4];
        const float Sv[4] = {S.x, S.y, S.z, S.w};
        const float Qv[4] = {Q.x, Q.y, Q.z, Q.w};
        const float av[4] = {al.x, al.y, al.z, al.w};
#pragma unroll
        for (int c = 0; c < 4; ++c) {
            const float mm = Sv[c] / cntf;
            const float ex2 = Qv[c] / cntf;
            const float var = fmaxf(ex2 - mm * mm * (2.f * av[c] - av[c] * av[c]), 0.f);
            smean[c4 + c] = mm;
            sinv[c4 + c] = 1.f / sqrtf(var + EPS);
        }
    }
    __syncthreads();
    const float4 mean4 = *(const float4*)&smean[c4];
    const float4 inv4 = *(const float4*)&sinv[c4];
    const float4 al4 = *(const float4*)&a[col0 + c4];
    const float4 g4 = *(const float4*)&g[col0 + c4];
    const float4 bb4 = *(const float4*)&bb[col0 + c4];
    for (int r = beg + rg; r < end; r += 16) {
        const float4 v = *(const float4*)&xf[(size_t)r * D + col0 + c4];
        float y0 = lrelu(g4.x * (v.x - al4.x * mean4.x) * inv4.x + bb4.x);
        float y1 = lrelu(g4.y * (v.y - al4.y * mean4.y) * inv4.y + bb4.y);
        float y2 = lrelu(g4.z * (v.z - al4.z * mean4.z) * inv4.z + bb4.z);
        float y3 = lrelu(g4.w * (v.w - al4.w * mean4.w) * inv4.w + bb4.w);
        uint2 o;
        o.x = (uint_t)f2b(y0) | ((uint_t)f2b(y1) << 16);
        o.y = (uint_t)f2b(y2) | ((uint_t)f2b(y3) << 16);
        *(uint2*)&xout[(size_t)r * OST + col0 + c4] = o;
    }
}

// ---------------- graph-feature mean: bf16 x3 -> h0 (stride 272, cols 0..255) ---------------

__global__ __launch_bounds__(256) void k_gf2b(const ushort_t* __restrict__ x3b,
                                              const int* __restrict__ bstart,
                                              float* __restrict__ h0) {
    __shared__ float4 red[256];
    const int b = blockIdx.x;
    const int col0 = blockIdx.y * 64;
    const int c4 = (threadIdx.x & 15) * 4;
    const int rg = threadIdx.x >> 4;
    const int beg = bstart[b], end = bstart[b + 1];
    const float cntf = fmaxf((float)(end - beg), 1.f);
    float4 s = {0.f, 0.f, 0.f, 0.f};
    for (int r = beg + rg; r < end; r += 16) {
        const uint2 u = *(const uint2*)&x3b[(size_t)r * 256 + col0 + c4];
        s.x += b2f(u.x & 0xffff); s.y += b2f(u.x >> 16);
        s.z += b2f(u.y & 0xffff); s.w += b2f(u.y >> 16);
    }
    red[threadIdx.x] = s;
    __syncthreads();
    if (rg == 0) {
        float4 S = red[threadIdx.x];
        for (int k = 1; k < 16; ++k) {
            const float4 s2 = red[threadIdx.x + 16 * k];
            S.x += s2.x; S.y += s2.y; S.z += s2.z; S.w += s2.w;
        }
        S.x /= cntf; S.y /= cntf; S.z /= cntf; S.w /= cntf;
        *(float4*)&h0[b * 272 + col0 + c4] = S;
    }
}

__global__ void k_demo(const float* __restrict__ dg, const float* __restrict__ w,
                       const float* __restrict__ b, float* __restrict__ h0) {
    int idx = blockIdx.x * blockDim.x + threadIdx.x;
    if (idx < NBATCH * 16) {
        int i = idx >> 4, j = idx & 15;
        float acc = b[j];
        for (int k = 0; k < 4; ++k) acc += dg[i * 4 + k] * w[k * 16 + j];
        h0[i * 272 + 256 + j] = acc;
    }
}

// fused linear + batch-norm + lrelu (fp32 head)
__global__ __launch_bounds__(128) void k_lin_bn(const float* __restrict__ in,
                                                const float* __restrict__ w,
                                                const float* __restrict__ bias,
                                                const float* __restrict__ g,
                                                const float* __restrict__ bb,
                                                float* __restrict__ out,
                                                int rows, int K, int C) {
    __shared__ float s1[128], s2[128];
    const int j = blockIdx.x;
    const int t = threadIdx.x;
    float v = 0.f;
    if (t < rows) {
        v = bias[j];
        for (int k = 0; k < K; ++k) v += in[t * K + k] * w[k * C + j];
    }
    s1[t] = (t < rows) ? v : 0.f;
    s2[t] = (t < rows) ? v * v : 0.f;
    __syncthreads();
    for (int off = 64; off > 0; off >>= 1) {
        if (t < off) { s1[t] += s1[t + off]; s2[t] += s2[t + off]; }
        __syncthreads();
    }
    const float m = s1[0] / rows;
    const float var = fmaxf(s2[0] / rows - m * m, 0.f);
    const float inv = 1.f / sqrtf(var + EPS);
    if (t < rows) out[t * C + j] = lrelu(g[j] * (v - m) * inv + bb[j]);
}

__global__ void k_linear(const float* __restrict__ in, const float* __restrict__ w,
                         const float* __restrict__ b, float* __restrict__ out,
                         int rows, int K, int D) {
    int total = rows * D;
    for (int idx = blockIdx.x * blockDim.x + threadIdx.x; idx < total; idx += gridDim.x * blockDim.x) {
        int i = idx / D, j = idx - i * D;
        float acc = b[j];
        for (int k = 0; k < K; ++k) acc += in[i * K + k] * w[k * D + j];
        out[idx] = acc;
    }
}

// ---------------- launcher ----------------

extern "C" void kernel_launch(void* const* d_in, const int* in_sizes, int n_in,
                              void* d_out, int out_size, void* d_ws, size_t ws_size,
                              hipStream_t stream) {
    const int*   x_idx  = (const int*)d_in[0];
    const int*   ei     = (const int*)d_in[1];
    const float* eattr  = (const float*)d_in[2];
    const int*   batch  = (const int*)d_in[3];
    const float* demog  = (const float*)d_in[4];
    const float* emb    = (const float*)d_in[5];
    const float* wrel1  = (const float*)d_in[6];
    const float* brel1  = (const float*)d_in[7];
    const float* wroot1 = (const float*)d_in[8];
    const float* wrel2  = (const float*)d_in[9];
    const float* brel2  = (const float*)d_in[10];
    const float* wroot2 = (const float*)d_in[11];
    const float* wrel3  = (const float*)d_in[12];
    const float* brel3  = (const float*)d_in[13];
    const float* wroot3 = (const float*)d_in[14];
    const float* gn1g = (const float*)d_in[15];
    const float* gn1b = (const float*)d_in[16];
    const float* gn1a = (const float*)d_in[17];
    const float* gn2g = (const float*)d_in[18];
    const float* gn2b = (const float*)d_in[19];
    const float* gn2a = (const float*)d_in[20];
    const float* dw   = (const float*)d_in[21];
    const float* db   = (const float*)d_in[22];
    const float* l1w  = (const float*)d_in[23];
    const float* l1b  = (const float*)d_in[24];
    const float* bn1g = (const float*)d_in[25];
    const float* bn1b = (const float*)d_in[26];
    const float* l2w  = (const float*)d_in[27];
    const float* l2b  = (const float*)d_in[28];
    const float* bn2g = (const float*)d_in[29];
    const float* bn2b = (const float*)d_in[30];
    const float* l3w  = (const float*)d_in[31];
    const float* l3b  = (const float*)d_in[32];
    float* out = (float*)d_out;

    float*    W     = (float*)d_ws;
    float*    xf    = W;                                   // fp32 conv out, 12.8M floats
    ushort_t* x3b   = (ushort_t*)(W + 12800000);           // NN*256 bf16
    ushort_t* xcat0 = (ushort_t*)(W + 25600000);           // NN*32 bf16  [agg0|x0]
    ushort_t* xcat1 = (ushort_t*)(W + 27200000);           // NN*128 bf16 [agg1|x1]
    ushort_t* xcat2 = (ushort_t*)(W + 33600000);           // NN*256 bf16 [agg2|x2]
    ushort_t* w1T   = (ushort_t*)(W + 46400000);           // 2048
    ushort_t* w2T   = w1T + 2048;                          // 16384
    ushort_t* w3T   = w2T + 16384;                         // 65536
    int2*     csr_pair = (int2*)(W + 46450000);            // NE int2
    int*      rowstart = (int*)(W + 49650000);             // NN+1
    int*      deg      = (int*)(W + 49770000);             // NN (aliased as cursor)
    int*      bstart   = (int*)(W + 49890000);             // NBATCH+1
    float*    h0 = W + 49891000;                           // 100*272
    float*    h1 = h0 + 27200;
    float*    h2 = h1 + 12800;

    const int* src = ei;
    const int* dst = ei + NE;

    auto gsz = [](long long t) {
        long long b = (t + 255) / 256;
        return (int)(b > 524288 ? 524288 : b);
    };
    const int mfma_blk = (NN + 63) / 64;     // 1563 (64 rows/block)
    const int nagg_blk = (NN + 3) / 4;       // 1 node/wave, 4 waves/block

    // ---- CSR build (by dst); cursor aliases deg ----
    hipMemsetAsync(deg, 0, NN * sizeof(int), stream);
    k_hist<<<gsz(NE), 256, 0, stream>>>(dst, deg);
    k_scan<<<1, 1024, 0, stream>>>(deg, rowstart, deg);
    k_fill<<<gsz(NE), 256, 0, stream>>>(dst, src, eattr, deg, csr_pair);

    k_bounds<<<1, 128, 0, stream>>>(batch, bstart);
    k_wpack<<<(83968 + 255) / 256, 256, 0, stream>>>(wrel1, wroot1, wrel2, wroot2, wrel3, wroot3,
                                                     w1T, w2T, w3T);

    // x0 (bf16) into xcat0 x-half
    k_gather_b<<<(NN + 255) / 256, 256, 0, stream>>>(x_idx, emb, xcat0);

    // conv1: [agg0|x0](K2=32) @ w1T -> xf (fp32 NN x 64)
    k_aggregate_b<16><<<nagg_blk, 256, 0, stream>>>(xcat0, csr_pair, rowstart);
    k_conv_mfma<32, 64, false><<<mfma_blk, 256, 0, stream>>>(xcat0, w1T, brel1, xf);
    k_graphnorm<64, 128><<<dim3(NBATCH, 1), 256, 0, stream>>>(xf, xcat1 + 64, bstart, gn1a, gn1g, gn1b);

    // conv2: [agg1|x1](K2=128) @ w2T -> xf (fp32 NN x 128)
    k_aggregate_b<64><<<nagg_blk, 256, 0, stream>>>(xcat1, csr_pair, rowstart);
    k_conv_mfma<128, 128, false><<<mfma_blk, 256, 0, stream>>>(xcat1, w2T, brel2, xf);
    k_graphnorm<128, 256><<<dim3(NBATCH, 2), 256, 0, stream>>>(xf, xcat2 + 128, bstart, gn2a, gn2g, gn2b);

    // conv3: [agg2|x2](K2=256) @ w3T -> x3b (bf16 NN x 256)
    k_aggregate_b<128><<<nagg_blk, 256, 0, stream>>>(xcat2, csr_pair, rowstart);
    k_conv_mfma<256, 256, true><<<mfma_blk, 256, 0, stream>>>(xcat2, w3T, brel3, x3b);

    // head
    k_gf2b<<<dim3(NBATCH, 4), 256, 0, stream>>>(x3b, bstart, h0);
    k_demo<<<(NBATCH * 16 + 255) / 256, 256, 0, stream>>>(demog, dw, db, h0);
    k_lin_bn<<<128, 128, 0, stream>>>(h0, l1w, l1b, bn1g, bn1b, h1, NBATCH, 272, 128);
    k_lin_bn<<<64, 128, 0, stream>>>(h1, l2w, l2b, bn2g, bn2b, h2, NBATCH, 128, 64);
    k_linear<<<gsz(NBATCH * 3), 256, 0, stream>>>(h2, l3w, l3b, out, NBATCH, 64, 3);
}

// Round 13
// 714.341 us; speedup vs baseline: 2.8391x; 1.2365x over previous
//
#include <hip/hip_runtime.h>

// Problem constants (from reference)
#define NN 100000      // nodes
#define NE 1600000     // edges
#define NBATCH 100     // graphs
#define NBUCK 391      // ceil(NN / 256) coarse buckets for CSR build
constexpr float EPS = 1e-5f;

typedef unsigned short ushort_t;
typedef unsigned int uint_t;

using short8 = __attribute__((ext_vector_type(8))) short;   // 8 bf16 (4 VGPRs)
using floatx4 = __attribute__((ext_vector_type(4))) float;  // 4 fp32 acc

__device__ __forceinline__ float lrelu(float x) { return x > 0.f ? x : 0.01f * x; }

__device__ __forceinline__ float b2f(ushort_t u) {
    union { uint_t i; float f; } c; c.i = ((uint_t)u) << 16; return c.f;
}
__device__ __forceinline__ ushort_t f2b(float f) {
    union { float f; uint_t i; } c; c.f = f;
    uint_t u = c.i;
    return (ushort_t)((u + 0x7FFFu + ((u >> 16) & 1u)) >> 16);   // RNE
}
__device__ __forceinline__ void unpack8(const uint4 u, float* f) {
    f[0] = b2f(u.x & 0xffff); f[1] = b2f(u.x >> 16);
    f[2] = b2f(u.y & 0xffff); f[3] = b2f(u.y >> 16);
    f[4] = b2f(u.z & 0xffff); f[5] = b2f(u.z >> 16);
    f[6] = b2f(u.w & 0xffff); f[7] = b2f(u.w >> 16);
}

// ---------------- bucketed CSR build (write-locality; replaces hist/scan/fill) ---------------

// per-block LDS histogram of coarse buckets -> global totals (grid 256)
__global__ __launch_bounds__(256) void k_bcount(const int* __restrict__ dst,
                                                int* __restrict__ bcnt) {
    __shared__ int h[NBUCK];
    for (int i = threadIdx.x; i < NBUCK; i += 256) h[i] = 0;
    __syncthreads();
    for (int e = blockIdx.x * 256 + threadIdx.x; e < NE; e += gridDim.x * 256)
        atomicAdd(&h[dst[e] >> 8], 1);
    __syncthreads();
    for (int i = threadIdx.x; i < NBUCK; i += 256)
        if (h[i]) atomicAdd(&bcnt[i], h[i]);
}

// scan bucket totals (1 block, 512 threads); also seeds bcur and rowstart[NN]
__global__ __launch_bounds__(512) void k_bscan(const int* __restrict__ bcnt,
                                               int* __restrict__ bbase,
                                               int* __restrict__ bcur,
                                               int* __restrict__ rowstart) {
    __shared__ int s[512];
    const int t = threadIdx.x;
    const int v = (t < NBUCK) ? bcnt[t] : 0;
    s[t] = v;
    __syncthreads();
    for (int off = 1; off < 512; off <<= 1) {
        int o = (t >= off) ? s[t - off] : 0;
        __syncthreads();
        s[t] += o;
        __syncthreads();
    }
    const int excl = s[t] - v;
    if (t < NBUCK) { bbase[t] = excl; bcur[t] = excl; }
    if (t == 0) { bbase[NBUCK] = NE; rowstart[NN] = NE; }
}

// block-chunked scatter into bucket-contiguous ebuf; ONE reservation atomic per
// (block,bucket); payload = (src | local_node<<20, w_bits). Writes are runs ->
// lines assemble in L2 (no partial-line HBM writeback amplification).
__global__ __launch_bounds__(256) void k_bscatter(const int* __restrict__ dst,
                                                  const int* __restrict__ srcv,
                                                  const float* __restrict__ ew,
                                                  int* __restrict__ bcur,
                                                  int2* __restrict__ ebuf) {
    __shared__ int h[NBUCK];
    __shared__ int lcur[NBUCK];
    const int chunk = (NE + gridDim.x - 1) / gridDim.x;
    const int beg = blockIdx.x * chunk;
    const int end = (beg + chunk < NE) ? beg + chunk : NE;
    for (int i = threadIdx.x; i < NBUCK; i += 256) h[i] = 0;
    __syncthreads();
    for (int e = beg + threadIdx.x; e < end; e += 256)
        atomicAdd(&h[dst[e] >> 8], 1);
    __syncthreads();
    for (int i = threadIdx.x; i < NBUCK; i += 256)
        lcur[i] = h[i] ? atomicAdd(&bcur[i], h[i]) : 0;
    __syncthreads();
    for (int e = beg + threadIdx.x; e < end; e += 256) {
        const int d = dst[e];
        const int pos = atomicAdd(&lcur[d >> 8], 1);
        ebuf[pos] = make_int2(srcv[e] | ((d & 255) << 20), __float_as_int(ew[e]));
    }
}

// one block per bucket: LDS node-histogram + scan -> rowstart (coalesced) and
// final csr_pair placement inside the bucket's contiguous ~32KB region.
__global__ __launch_bounds__(256) void k_bfinal(const int2* __restrict__ ebuf,
                                                const int* __restrict__ bbase,
                                                int* __restrict__ rowstart,
                                                int2* __restrict__ csr_pair) {
    __shared__ int h[256];
    __shared__ int cur[256];
    const int b = blockIdx.x;
    const int t = threadIdx.x;
    const int base = bbase[b];
    const int cnt = bbase[b + 1] - base;
    h[t] = 0;
    __syncthreads();
    for (int i = t; i < cnt; i += 256)
        atomicAdd(&h[(ebuf[base + i].x >> 20) & 255], 1);
    __syncthreads();
    const int v = h[t];
    cur[t] = v;
    __syncthreads();
    for (int off = 1; off < 256; off <<= 1) {
        int o = (t >= off) ? cur[t - off] : 0;
        __syncthreads();
        cur[t] += o;
        __syncthreads();
    }
    const int excl = cur[t] - v;
    const int n = (b << 8) + t;
    if (n < NN) rowstart[n] = base + excl;
    __syncthreads();
    cur[t] = excl;
    __syncthreads();
    for (int i = t; i < cnt; i += 256) {
        const int2 p = ebuf[base + i];
        const int loc = (p.x >> 20) & 255;
        const int pos = base + atomicAdd(&cur[loc], 1);
        csr_pair[pos] = make_int2(p.x & 0xFFFFF, p.y);
    }
}

__global__ void k_bounds(const int* __restrict__ batch, int* __restrict__ bstart) {
    int b = blockIdx.x * blockDim.x + threadIdx.x;
    if (b > NBATCH) return;
    int lo = 0, hi = NN;
    while (lo < hi) {
        int mid = (lo + hi) >> 1;
        if (batch[mid] < b) lo = mid + 1; else hi = mid;
    }
    bstart[b] = lo;
}

// ---------------- weight pack: wcatT[n*K2 + k] (bf16) ----------------------------------------

__global__ void k_wpack(const float* __restrict__ wr1, const float* __restrict__ wo1,
                        const float* __restrict__ wr2, const float* __restrict__ wo2,
                        const float* __restrict__ wr3, const float* __restrict__ wo3,
                        ushort_t* __restrict__ w1T, ushort_t* __restrict__ w2T,
                        ushort_t* __restrict__ w3T) {
    int idx = blockIdx.x * blockDim.x + threadIdx.x;
    if (idx < 2048) {                                  // conv1: DOUT=64, K2=32
        int n = idx >> 5, k = idx & 31;
        float v = (k < 16) ? wr1[k * 64 + n] : wo1[(k - 16) * 64 + n];
        w1T[idx] = f2b(v);
    } else if (idx < 2048 + 16384) {                   // conv2: DOUT=128, K2=128
        int l = idx - 2048; int n = l >> 7, k = l & 127;
        float v = (k < 64) ? wr2[k * 128 + n] : wo2[(k - 64) * 128 + n];
        w2T[l] = f2b(v);
    } else if (idx < 2048 + 16384 + 65536) {           // conv3: DOUT=256, K2=256
        int l = idx - 18432; int n = l >> 8, k = l & 255;
        float v = (k < 128) ? wr3[k * 256 + n] : wo3[(k - 128) * 256 + n];
        w3T[l] = f2b(v);
    }
}

// ---------------- embedding gather -> bf16 x-half of xcat0 (cols 16..31, stride 32) ----------

__global__ void k_gather_b(const int* __restrict__ xi, const float* __restrict__ emb,
                           ushort_t* __restrict__ xcat0) {
    int n = blockIdx.x * blockDim.x + threadIdx.x;
    if (n >= NN) return;
    const float* e = emb + ((size_t)xi[n] << 4);
    uint_t u[8];
#pragma unroll
    for (int j = 0; j < 8; ++j)
        u[j] = (uint_t)f2b(e[2 * j]) | ((uint_t)f2b(e[2 * j + 1]) << 16);
    uint4* o = (uint4*)(xcat0 + (size_t)n * 32 + 16);
    o[0] = {u[0], u[1], u[2], u[3]};
    o[1] = {u[4], u[5], u[6], u[7]};
}

// ---------------- aggregate (bf16 in/out): xcat row = [agg(0..D-1) | x(D..2D-1)] ------------

template <int D>
__global__ void k_aggregate_b(ushort_t* __restrict__ xcat, const int2* __restrict__ csr_pair,
                              const int* __restrict__ rowstart) {
    constexpr int LPN = D / 8;           // lanes per node (8 bf16 each)
    constexpr int EP = 64 / LPN;
    const int n = blockIdx.x * 4 + (threadIdx.x >> 6);
    const int lane = threadIdx.x & 63;
    const int sl = lane % LPN;
    const int eg = lane / LPN;
    if (n >= NN) return;
    const int beg = rowstart[n], end = rowstart[n + 1];
    float a0[8] = {}, a1[8] = {};
    int i = beg + eg;
    for (; i + EP < end; i += 2 * EP) {
        const int2 p0 = csr_pair[i];
        const int2 p1 = csr_pair[i + EP];
        const float w0 = __int_as_float(p0.y);
        const float w1 = __int_as_float(p1.y);
        const uint4 u0 = *(const uint4*)(xcat + (size_t)p0.x * (2 * D) + D + sl * 8);
        const uint4 u1 = *(const uint4*)(xcat + (size_t)p1.x * (2 * D) + D + sl * 8);
        float f0[8], f1[8];
        unpack8(u0, f0); unpack8(u1, f1);
#pragma unroll
        for (int j = 0; j < 8; ++j) { a0[j] += f0[j] * w0; a1[j] += f1[j] * w1; }
    }
    if (i < end) {
        const int2 p0 = csr_pair[i];
        const float w0 = __int_as_float(p0.y);
        const uint4 u0 = *(const uint4*)(xcat + (size_t)p0.x * (2 * D) + D + sl * 8);
        float f0[8];
        unpack8(u0, f0);
#pragma unroll
        for (int j = 0; j < 8; ++j) a0[j] += f0[j] * w0;
    }
#pragma unroll
    for (int j = 0; j < 8; ++j) a0[j] += a1[j];
#pragma unroll
    for (int m = LPN; m < 64; m <<= 1)
#pragma unroll
        for (int j = 0; j < 8; ++j) a0[j] += __shfl_xor(a0[j], m);
    if (eg == 0) {
        uint_t u[4];
#pragma unroll
        for (int j = 0; j < 4; ++j)
            u[j] = (uint_t)f2b(a0[2 * j]) | ((uint_t)f2b(a0[2 * j + 1]) << 16);
        *(uint4*)(xcat + (size_t)n * (2 * D) + sl * 8) = {u[0], u[1], u[2], u[3]};
    }
}

// ---------------- conv GEMM via bf16 MFMA ---------------------------------------------------
// Block = 64 rows x full DOUT; wave wv handles CW=DOUT/64 column tiles x 4 row tiles.

template <int K2, int DOUT, bool BOUT>
__global__ __launch_bounds__(256) void k_conv_mfma(
        const ushort_t* __restrict__ xcat, const ushort_t* __restrict__ wcatT,
        const float* __restrict__ brel, void* __restrict__ outp) {
    constexpr int CW = DOUT / 64;          // col tiles per wave (1, 2, 4)
    const int lane = threadIdx.x & 63;
    const int wv = threadIdx.x >> 6;
    const int m = lane & 15;
    const int quad = lane >> 4;
    const int r0 = blockIdx.x * 64;

    floatx4 acc[4][CW] = {};

    const ushort_t* arow[4];
#pragma unroll
    for (int r = 0; r < 4; ++r) {
        int an = r0 + r * 16 + m; if (an >= NN) an = NN - 1;
        arow[r] = xcat + (size_t)an * K2 + quad * 8;
    }
    const ushort_t* brow[CW];
#pragma unroll
    for (int c = 0; c < CW; ++c)
        brow[c] = wcatT + (size_t)((wv * CW + c) * 16 + m) * K2 + quad * 8;

    for (int kk = 0; kk < K2; kk += 32) {
        short8 a[4], b[CW];
#pragma unroll
        for (int r = 0; r < 4; ++r) a[r] = *(const short8*)(arow[r] + kk);
#pragma unroll
        for (int c = 0; c < CW; ++c) b[c] = *(const short8*)(brow[c] + kk);
#pragma unroll
        for (int r = 0; r < 4; ++r)
#pragma unroll
            for (int c = 0; c < CW; ++c)
                acc[r][c] = __builtin_amdgcn_mfma_f32_16x16x32_bf16(a[r], b[c], acc[r][c], 0, 0, 0);
    }

#pragma unroll
    for (int c = 0; c < CW; ++c) {
        const int col = (wv * CW + c) * 16 + m;
        const float bias = brel[col];
#pragma unroll
        for (int r = 0; r < 4; ++r) {
#pragma unroll
            for (int rr = 0; rr < 4; ++rr) {
                const int row = r0 + r * 16 + quad * 4 + rr;
                if (row < NN) {
                    const float v = acc[r][c][rr] + bias;
                    if constexpr (BOUT) ((ushort_t*)outp)[(size_t)row * DOUT + col] = f2b(v);
                    else                ((float*)outp)[(size_t)row * DOUT + col] = v;
                }
            }
        }
    }
}

// ---------------- graph-norm + lrelu: fp32 in -> bf16 out (into xcat x-half) ----------------

template <int D, int OST>
__global__ __launch_bounds__(256) void k_graphnorm(
        const float* __restrict__ xf, ushort_t* __restrict__ xout,
        const int* __restrict__ bstart, const float* __restrict__ a,
        const float* __restrict__ g, const float* __restrict__ bb) {
    __shared__ float4 reds[256];
    __shared__ float4 redq[256];
    __shared__ float smean[64];
    __shared__ float sinv[64];
    const int b = blockIdx.x;
    const int col0 = blockIdx.y * 64;
    const int c4 = (threadIdx.x & 15) * 4;
    const int rg = threadIdx.x >> 4;
    const int beg = bstart[b], end = bstart[b + 1];
    const float cntf = fmaxf((float)(end - beg), 1.f);

    float4 s = {0.f, 0.f, 0.f, 0.f}, q = {0.f, 0.f, 0.f, 0.f};
    for (int r = beg + rg; r < end; r += 16) {
        const float4 v = *(const float4*)&xf[(size_t)r * D + col0 + c4];
        s.x += v.x; s.y += v.y; s.z += v.z; s.w += v.w;
        q.x += v.x * v.x; q.y += v.y * v.y; q.z += v.z * v.z; q.w += v.w * v.w;
    }
    reds[threadIdx.x] = s;
    redq[threadIdx.x] = q;
    __syncthreads();
    if (rg == 0) {
        float4 S = reds[threadIdx.x], Q = redq[threadIdx.x];
        for (int k = 1; k < 16; ++k) {
            const float4 s2 = reds[threadIdx.x + 16 * k];
            const float4 q2 = redq[threadIdx.x + 16 * k];
            S.x += s2.x; S.y += s2.y; S.z += s2.z; S.w += s2.w;
            Q.x += q2.x; Q.y += q2.y; Q.z += q2.z; Q.w += q2.w;
        }
        const float4 al = *(const float4*)&a[col0 + c4];
        const float Sv[4] = {S.x, S.y, S.z, S.w};
        const float Qv[4] = {Q.x, Q.y, Q.z, Q.w};
        const float av[4] = {al.x, al.y, al.z, al.w};
#pragma unroll
        for (int c = 0; c < 4; ++c) {
            const float mm = Sv[c] / cntf;
            const float ex2 = Qv[c] / cntf;
            const float var = fmaxf(ex2 - mm * mm * (2.f * av[c] - av[c] * av[c]), 0.f);
            smean[c4 + c] = mm;
            sinv[c4 + c] = 1.f / sqrtf(var + EPS);
        }
    }
    __syncthreads();
    const float4 mean4 = *(const float4*)&smean[c4];
    const float4 inv4 = *(const float4*)&sinv[c4];
    const float4 al4 = *(const float4*)&a[col0 + c4];
    const float4 g4 = *(const float4*)&g[col0 + c4];
    const float4 bb4 = *(const float4*)&bb[col0 + c4];
    for (int r = beg + rg; r < end; r += 16) {
        const float4 v = *(const float4*)&xf[(size_t)r * D + col0 + c4];
        float y0 = lrelu(g4.x * (v.x - al4.x * mean4.x) * inv4.x + bb4.x);
        float y1 = lrelu(g4.y * (v.y - al4.y * mean4.y) * inv4.y + bb4.y);
        float y2 = lrelu(g4.z * (v.z - al4.z * mean4.z) * inv4.z + bb4.z);
        float y3 = lrelu(g4.w * (v.w - al4.w * mean4.w) * inv4.w + bb4.w);
        uint2 o;
        o.x = (uint_t)f2b(y0) | ((uint_t)f2b(y1) << 16);
        o.y = (uint_t)f2b(y2) | ((uint_t)f2b(y3) << 16);
        *(uint2*)&xout[(size_t)r * OST + col0 + c4] = o;
    }
}

// ---------------- graph-feature mean: bf16 x3 -> h0 (stride 272, cols 0..255) ---------------

__global__ __launch_bounds__(256) void k_gf2b(const ushort_t* __restrict__ x3b,
                                              const int* __restrict__ bstart,
                                              float* __restrict__ h0) {
    __shared__ float4 red[256];
    const int b = blockIdx.x;
    const int col0 = blockIdx.y * 64;
    const int c4 = (threadIdx.x & 15) * 4;
    const int rg = threadIdx.x >> 4;
    const int beg = bstart[b], end = bstart[b + 1];
    const float cntf = fmaxf((float)(end - beg), 1.f);
    float4 s = {0.f, 0.f, 0.f, 0.f};
    for (int r = beg + rg; r < end; r += 16) {
        const uint2 u = *(const uint2*)&x3b[(size_t)r * 256 + col0 + c4];
        s.x += b2f(u.x & 0xffff); s.y += b2f(u.x >> 16);
        s.z += b2f(u.y & 0xffff); s.w += b2f(u.y >> 16);
    }
    red[threadIdx.x] = s;
    __syncthreads();
    if (rg == 0) {
        float4 S = red[threadIdx.x];
        for (int k = 1; k < 16; ++k) {
            const float4 s2 = red[threadIdx.x + 16 * k];
            S.x += s2.x; S.y += s2.y; S.z += s2.z; S.w += s2.w;
        }
        S.x /= cntf; S.y /= cntf; S.z /= cntf; S.w /= cntf;
        *(float4*)&h0[b * 272 + col0 + c4] = S;
    }
}

__global__ void k_demo(const float* __restrict__ dg, const float* __restrict__ w,
                       const float* __restrict__ b, float* __restrict__ h0) {
    int idx = blockIdx.x * blockDim.x + threadIdx.x;
    if (idx < NBATCH * 16) {
        int i = idx >> 4, j = idx & 15;
        float acc = b[j];
        for (int k = 0; k < 4; ++k) acc += dg[i * 4 + k] * w[k * 16 + j];
        h0[i * 272 + 256 + j] = acc;
    }
}

// fused linear + batch-norm + lrelu (fp32 head)
__global__ __launch_bounds__(128) void k_lin_bn(const float* __restrict__ in,
                                                const float* __restrict__ w,
                                                const float* __restrict__ bias,
                                                const float* __restrict__ g,
                                                const float* __restrict__ bb,
                                                float* __restrict__ out,
                                                int rows, int K, int C) {
    __shared__ float s1[128], s2[128];
    const int j = blockIdx.x;
    const int t = threadIdx.x;
    float v = 0.f;
    if (t < rows) {
        v = bias[j];
        for (int k = 0; k < K; ++k) v += in[t * K + k] * w[k * C + j];
    }
    s1[t] = (t < rows) ? v : 0.f;
    s2[t] = (t < rows) ? v * v : 0.f;
    __syncthreads();
    for (int off = 64; off > 0; off >>= 1) {
        if (t < off) { s1[t] += s1[t + off]; s2[t] += s2[t + off]; }
        __syncthreads();
    }
    const float m = s1[0] / rows;
    const float var = fmaxf(s2[0] / rows - m * m, 0.f);
    const float inv = 1.f / sqrtf(var + EPS);
    if (t < rows) out[t * C + j] = lrelu(g[j] * (v - m) * inv + bb[j]);
}

__global__ void k_linear(const float* __restrict__ in, const float* __restrict__ w,
                         const float* __restrict__ b, float* __restrict__ out,
                         int rows, int K, int D) {
    int total = rows * D;
    for (int idx = blockIdx.x * blockDim.x + threadIdx.x; idx < total; idx += gridDim.x * blockDim.x) {
        int i = idx / D, j = idx - i * D;
        float acc = b[j];
        for (int k = 0; k < K; ++k) acc += in[i * K + k] * w[k * D + j];
        out[idx] = acc;
    }
}

// ---------------- launcher ----------------

extern "C" void kernel_launch(void* const* d_in, const int* in_sizes, int n_in,
                              void* d_out, int out_size, void* d_ws, size_t ws_size,
                              hipStream_t stream) {
    const int*   x_idx  = (const int*)d_in[0];
    const int*   ei     = (const int*)d_in[1];
    const float* eattr  = (const float*)d_in[2];
    const int*   batch  = (const int*)d_in[3];
    const float* demog  = (const float*)d_in[4];
    const float* emb    = (const float*)d_in[5];
    const float* wrel1  = (const float*)d_in[6];
    const float* brel1  = (const float*)d_in[7];
    const float* wroot1 = (const float*)d_in[8];
    const float* wrel2  = (const float*)d_in[9];
    const float* brel2  = (const float*)d_in[10];
    const float* wroot2 = (const float*)d_in[11];
    const float* wrel3  = (const float*)d_in[12];
    const float* brel3  = (const float*)d_in[13];
    const float* wroot3 = (const float*)d_in[14];
    const float* gn1g = (const float*)d_in[15];
    const float* gn1b = (const float*)d_in[16];
    const float* gn1a = (const float*)d_in[17];
    const float* gn2g = (const float*)d_in[18];
    const float* gn2b = (const float*)d_in[19];
    const float* gn2a = (const float*)d_in[20];
    const float* dw   = (const float*)d_in[21];
    const float* db   = (const float*)d_in[22];
    const float* l1w  = (const float*)d_in[23];
    const float* l1b  = (const float*)d_in[24];
    const float* bn1g = (const float*)d_in[25];
    const float* bn1b = (const float*)d_in[26];
    const float* l2w  = (const float*)d_in[27];
    const float* l2b  = (const float*)d_in[28];
    const float* bn2g = (const float*)d_in[29];
    const float* bn2b = (const float*)d_in[30];
    const float* l3w  = (const float*)d_in[31];
    const float* l3b  = (const float*)d_in[32];
    float* out = (float*)d_out;

    float*    W     = (float*)d_ws;
    float*    xf    = W;                                   // fp32 conv out, 12.8M floats
    int2*     ebuf  = (int2*)W;                            // NE int2 (CSR build only; dead before conv1)
    ushort_t* x3b   = (ushort_t*)(W + 12800000);           // NN*256 bf16
    ushort_t* xcat0 = (ushort_t*)(W + 25600000);           // NN*32 bf16  [agg0|x0]
    ushort_t* xcat1 = (ushort_t*)(W + 27200000);           // NN*128 bf16 [agg1|x1]
    ushort_t* xcat2 = (ushort_t*)(W + 33600000);           // NN*256 bf16 [agg2|x2]
    ushort_t* w1T   = (ushort_t*)(W + 46400000);           // 2048
    ushort_t* w2T   = w1T + 2048;                          // 16384
    ushort_t* w3T   = w2T + 16384;                         // 65536
    int2*     csr_pair = (int2*)(W + 46450000);            // NE int2
    int*      rowstart = (int*)(W + 49650000);             // NN+1
    int*      bstart   = (int*)(W + 49760000);             // NBATCH+1
    int*      bcnt     = (int*)(W + 49761000);             // NBUCK
    int*      bbase    = (int*)(W + 49762000);             // NBUCK+1
    int*      bcur     = (int*)(W + 49763000);             // NBUCK
    float*    h0 = W + 49770000;                           // 100*272
    float*    h1 = h0 + 27200;
    float*    h2 = h1 + 12800;

    const int* src = ei;
    const int* dst = ei + NE;

    auto gsz = [](long long t) {
        long long b = (t + 255) / 256;
        return (int)(b > 524288 ? 524288 : b);
    };
    const int mfma_blk = (NN + 63) / 64;     // 1563 (64 rows/block)
    const int nagg_blk = (NN + 3) / 4;       // 1 node/wave, 4 waves/block

    // ---- bucketed CSR build (by dst) ----
    hipMemsetAsync(bcnt, 0, NBUCK * sizeof(int), stream);
    k_bcount<<<256, 256, 0, stream>>>(dst, bcnt);
    k_bscan<<<1, 512, 0, stream>>>(bcnt, bbase, bcur, rowstart);
    k_bscatter<<<256, 256, 0, stream>>>(dst, src, eattr, bcur, ebuf);
    k_bfinal<<<NBUCK, 256, 0, stream>>>(ebuf, bbase, rowstart, csr_pair);

    k_bounds<<<1, 128, 0, stream>>>(batch, bstart);
    k_wpack<<<(83968 + 255) / 256, 256, 0, stream>>>(wrel1, wroot1, wrel2, wroot2, wrel3, wroot3,
                                                     w1T, w2T, w3T);

    // x0 (bf16) into xcat0 x-half
    k_gather_b<<<(NN + 255) / 256, 256, 0, stream>>>(x_idx, emb, xcat0);

    // conv1: [agg0|x0](K2=32) @ w1T -> xf (fp32 NN x 64)
    k_aggregate_b<16><<<nagg_blk, 256, 0, stream>>>(xcat0, csr_pair, rowstart);
    k_conv_mfma<32, 64, false><<<mfma_blk, 256, 0, stream>>>(xcat0, w1T, brel1, xf);
    k_graphnorm<64, 128><<<dim3(NBATCH, 1), 256, 0, stream>>>(xf, xcat1 + 64, bstart, gn1a, gn1g, gn1b);

    // conv2: [agg1|x1](K2=128) @ w2T -> xf (fp32 NN x 128)
    k_aggregate_b<64><<<nagg_blk, 256, 0, stream>>>(xcat1, csr_pair, rowstart);
    k_conv_mfma<128, 128, false><<<mfma_blk, 256, 0, stream>>>(xcat1, w2T, brel2, xf);
    k_graphnorm<128, 256><<<dim3(NBATCH, 2), 256, 0, stream>>>(xf, xcat2 + 128, bstart, gn2a, gn2g, gn2b);

    // conv3: [agg2|x2](K2=256) @ w3T -> x3b (bf16 NN x 256)
    k_aggregate_b<128><<<nagg_blk, 256, 0, stream>>>(xcat2, csr_pair, rowstart);
    k_conv_mfma<256, 256, true><<<mfma_blk, 256, 0, stream>>>(xcat2, w3T, brel3, x3b);

    // head
    k_gf2b<<<dim3(NBATCH, 4), 256, 0, stream>>>(x3b, bstart, h0);
    k_demo<<<(NBATCH * 16 + 255) / 256, 256, 0, stream>>>(demog, dw, db, h0);
    k_lin_bn<<<128, 128, 0, stream>>>(h0, l1w, l1b, bn1g, bn1b, h1, NBATCH, 272, 128);
    k_lin_bn<<<64, 128, 0, stream>>>(h1, l2w, l2b, bn2g, bn2b, h2, NBATCH, 128, 64);
    k_linear<<<gsz(NBATCH * 3), 256, 0, stream>>>(h2, l3w, l3b, out, NBATCH, 64, 3);
}

// Round 14
// 668.268 us; speedup vs baseline: 3.0348x; 1.0689x over previous
//
#include <hip/hip_runtime.h>

// Problem constants (from reference)
#define NN 100000      // nodes
#define NE 1600000     // edges
#define NBATCH 100     // graphs
#define NBUCK 391      // ceil(NN / 256) coarse buckets for CSR build
constexpr float EPS = 1e-5f;

typedef unsigned short ushort_t;
typedef unsigned int uint_t;

using short8 = __attribute__((ext_vector_type(8))) short;   // 8 bf16 (4 VGPRs)
using floatx4 = __attribute__((ext_vector_type(4))) float;  // 4 fp32 acc

__device__ __forceinline__ float lrelu(float x) { return x > 0.f ? x : 0.01f * x; }

__device__ __forceinline__ float b2f(ushort_t u) {
    union { uint_t i; float f; } c; c.i = ((uint_t)u) << 16; return c.f;
}
__device__ __forceinline__ ushort_t f2b(float f) {
    union { float f; uint_t i; } c; c.f = f;
    uint_t u = c.i;
    return (ushort_t)((u + 0x7FFFu + ((u >> 16) & 1u)) >> 16);   // RNE
}
__device__ __forceinline__ void unpack8(const uint4 u, float* f) {
    f[0] = b2f(u.x & 0xffff); f[1] = b2f(u.x >> 16);
    f[2] = b2f(u.y & 0xffff); f[3] = b2f(u.y >> 16);
    f[4] = b2f(u.z & 0xffff); f[5] = b2f(u.z >> 16);
    f[6] = b2f(u.w & 0xffff); f[7] = b2f(u.w >> 16);
}

// ---------------- bucketed CSR build ----------------

__global__ __launch_bounds__(256) void k_bcount(const int* __restrict__ dst,
                                                int* __restrict__ bcnt) {
    __shared__ int h[NBUCK];
    for (int i = threadIdx.x; i < NBUCK; i += 256) h[i] = 0;
    __syncthreads();
    for (int e = blockIdx.x * 256 + threadIdx.x; e < NE; e += gridDim.x * 256)
        atomicAdd(&h[dst[e] >> 8], 1);
    __syncthreads();
    for (int i = threadIdx.x; i < NBUCK; i += 256)
        if (h[i]) atomicAdd(&bcnt[i], h[i]);
}

__global__ __launch_bounds__(512) void k_bscan(const int* __restrict__ bcnt,
                                               int* __restrict__ bbase,
                                               int* __restrict__ bcur,
                                               int* __restrict__ rowstart) {
    __shared__ int s[512];
    const int t = threadIdx.x;
    const int v = (t < NBUCK) ? bcnt[t] : 0;
    s[t] = v;
    __syncthreads();
    for (int off = 1; off < 512; off <<= 1) {
        int o = (t >= off) ? s[t - off] : 0;
        __syncthreads();
        s[t] += o;
        __syncthreads();
    }
    const int excl = s[t] - v;
    if (t < NBUCK) { bbase[t] = excl; bcur[t] = excl; }
    if (t == 0) { bbase[NBUCK] = NE; rowstart[NN] = NE; }
}

__global__ __launch_bounds__(256) void k_bscatter(const int* __restrict__ dst,
                                                  const int* __restrict__ srcv,
                                                  const float* __restrict__ ew,
                                                  int* __restrict__ bcur,
                                                  int2* __restrict__ ebuf) {
    __shared__ int h[NBUCK];
    __shared__ int lcur[NBUCK];
    const int chunk = (NE + gridDim.x - 1) / gridDim.x;
    const int beg = blockIdx.x * chunk;
    const int end = (beg + chunk < NE) ? beg + chunk : NE;
    for (int i = threadIdx.x; i < NBUCK; i += 256) h[i] = 0;
    __syncthreads();
    for (int e = beg + threadIdx.x; e < end; e += 256)
        atomicAdd(&h[dst[e] >> 8], 1);
    __syncthreads();
    for (int i = threadIdx.x; i < NBUCK; i += 256)
        lcur[i] = h[i] ? atomicAdd(&bcur[i], h[i]) : 0;
    __syncthreads();
    for (int e = beg + threadIdx.x; e < end; e += 256) {
        const int d = dst[e];
        const int pos = atomicAdd(&lcur[d >> 8], 1);
        ebuf[pos] = make_int2(srcv[e] | ((d & 255) << 20), __float_as_int(ew[e]));
    }
}

__global__ __launch_bounds__(256) void k_bfinal(const int2* __restrict__ ebuf,
                                                const int* __restrict__ bbase,
                                                int* __restrict__ rowstart,
                                                int2* __restrict__ csr_pair) {
    __shared__ int h[256];
    __shared__ int cur[256];
    const int b = blockIdx.x;
    const int t = threadIdx.x;
    const int base = bbase[b];
    const int cnt = bbase[b + 1] - base;
    h[t] = 0;
    __syncthreads();
    for (int i = t; i < cnt; i += 256)
        atomicAdd(&h[(ebuf[base + i].x >> 20) & 255], 1);
    __syncthreads();
    const int v = h[t];
    cur[t] = v;
    __syncthreads();
    for (int off = 1; off < 256; off <<= 1) {
        int o = (t >= off) ? cur[t - off] : 0;
        __syncthreads();
        cur[t] += o;
        __syncthreads();
    }
    const int excl = cur[t] - v;
    const int n = (b << 8) + t;
    if (n < NN) rowstart[n] = base + excl;
    __syncthreads();
    cur[t] = excl;
    __syncthreads();
    for (int i = t; i < cnt; i += 256) {
        const int2 p = ebuf[base + i];
        const int loc = (p.x >> 20) & 255;
        const int pos = base + atomicAdd(&cur[loc], 1);
        csr_pair[pos] = make_int2(p.x & 0xFFFFF, p.y);
    }
}

__global__ void k_bounds(const int* __restrict__ batch, int* __restrict__ bstart) {
    int b = blockIdx.x * blockDim.x + threadIdx.x;
    if (b > NBATCH) return;
    int lo = 0, hi = NN;
    while (lo < hi) {
        int mid = (lo + hi) >> 1;
        if (batch[mid] < b) lo = mid + 1; else hi = mid;
    }
    bstart[b] = lo;
}

// ---------------- weight pack ----------------------------------------------------------------

__global__ void k_wpack(const float* __restrict__ wr1, const float* __restrict__ wo1,
                        const float* __restrict__ wr2, const float* __restrict__ wo2,
                        const float* __restrict__ wr3, const float* __restrict__ wo3,
                        ushort_t* __restrict__ w1T, ushort_t* __restrict__ w2T,
                        ushort_t* __restrict__ w3T) {
    int idx = blockIdx.x * blockDim.x + threadIdx.x;
    if (idx < 2048) {                                  // conv1: DOUT=64, K2=32
        int n = idx >> 5, k = idx & 31;
        float v = (k < 16) ? wr1[k * 64 + n] : wo1[(k - 16) * 64 + n];
        w1T[idx] = f2b(v);
    } else if (idx < 2048 + 16384) {                   // conv2: DOUT=128, K2=128
        int l = idx - 2048; int n = l >> 7, k = l & 127;
        float v = (k < 64) ? wr2[k * 128 + n] : wo2[(k - 64) * 128 + n];
        w2T[l] = f2b(v);
    } else if (idx < 2048 + 16384 + 65536) {           // conv3: DOUT=256, K2=256
        int l = idx - 18432; int n = l >> 8, k = l & 255;
        float v = (k < 128) ? wr3[k * 256 + n] : wo3[(k - 128) * 256 + n];
        w3T[l] = f2b(v);
    }
}

// ---------------- embedding gather -> bf16 x-half of xcat0 ----------------------------------

__global__ void k_gather_b(const int* __restrict__ xi, const float* __restrict__ emb,
                           ushort_t* __restrict__ xcat0) {
    int n = blockIdx.x * blockDim.x + threadIdx.x;
    if (n >= NN) return;
    const float* e = emb + ((size_t)xi[n] << 4);
    uint_t u[8];
#pragma unroll
    for (int j = 0; j < 8; ++j)
        u[j] = (uint_t)f2b(e[2 * j]) | ((uint_t)f2b(e[2 * j + 1]) << 16);
    uint4* o = (uint4*)(xcat0 + (size_t)n * 32 + 16);
    o[0] = {u[0], u[1], u[2], u[3]};
    o[1] = {u[4], u[5], u[6], u[7]};
}

// ---------------- aggregate (bf16 in/out) ----------------------------------------------------

template <int D>
__global__ void k_aggregate_b(ushort_t* __restrict__ xcat, const int2* __restrict__ csr_pair,
                              const int* __restrict__ rowstart) {
    constexpr int LPN = D / 8;
    constexpr int EP = 64 / LPN;
    const int n = blockIdx.x * 4 + (threadIdx.x >> 6);
    const int lane = threadIdx.x & 63;
    const int sl = lane % LPN;
    const int eg = lane / LPN;
    if (n >= NN) return;
    const int beg = rowstart[n], end = rowstart[n + 1];
    float a0[8] = {}, a1[8] = {};
    int i = beg + eg;
    for (; i + EP < end; i += 2 * EP) {
        const int2 p0 = csr_pair[i];
        const int2 p1 = csr_pair[i + EP];
        const float w0 = __int_as_float(p0.y);
        const float w1 = __int_as_float(p1.y);
        const uint4 u0 = *(const uint4*)(xcat + (size_t)p0.x * (2 * D) + D + sl * 8);
        const uint4 u1 = *(const uint4*)(xcat + (size_t)p1.x * (2 * D) + D + sl * 8);
        float f0[8], f1[8];
        unpack8(u0, f0); unpack8(u1, f1);
#pragma unroll
        for (int j = 0; j < 8; ++j) { a0[j] += f0[j] * w0; a1[j] += f1[j] * w1; }
    }
    if (i < end) {
        const int2 p0 = csr_pair[i];
        const float w0 = __int_as_float(p0.y);
        const uint4 u0 = *(const uint4*)(xcat + (size_t)p0.x * (2 * D) + D + sl * 8);
        float f0[8];
        unpack8(u0, f0);
#pragma unroll
        for (int j = 0; j < 8; ++j) a0[j] += f0[j] * w0;
    }
#pragma unroll
    for (int j = 0; j < 8; ++j) a0[j] += a1[j];
#pragma unroll
    for (int m = LPN; m < 64; m <<= 1)
#pragma unroll
        for (int j = 0; j < 8; ++j) a0[j] += __shfl_xor(a0[j], m);
    if (eg == 0) {
        uint_t u[4];
#pragma unroll
        for (int j = 0; j < 4; ++j)
            u[j] = (uint_t)f2b(a0[2 * j]) | ((uint_t)f2b(a0[2 * j + 1]) << 16);
        *(uint4*)(xcat + (size_t)n * (2 * D) + sl * 8) = {u[0], u[1], u[2], u[3]};
    }
}

// ---------------- conv GEMM via bf16 MFMA ---------------------------------------------------
// MODE 0: fp32 out. MODE 2: no main output — fuse graph-feature segment-sum into
// epilogue (rows batch-sorted; per-segment cross-quad shfl reduce, one atomicAdd
// per (block, col) into gfacc[NBATCH x 256]).

template <int K2, int DOUT, int MODE>
__global__ __launch_bounds__(256) void k_conv_mfma(
        const ushort_t* __restrict__ xcat, const ushort_t* __restrict__ wcatT,
        const float* __restrict__ brel, float* __restrict__ outp,
        const int* __restrict__ batch, const int* __restrict__ bstart,
        float* __restrict__ gfacc) {
    constexpr int CW = DOUT / 64;          // col tiles per wave (1, 2, 4)
    const int lane = threadIdx.x & 63;
    const int wv = threadIdx.x >> 6;
    const int m = lane & 15;
    const int quad = lane >> 4;
    const int r0 = blockIdx.x * 64;

    floatx4 acc[4][CW] = {};

    const ushort_t* arow[4];
#pragma unroll
    for (int r = 0; r < 4; ++r) {
        int an = r0 + r * 16 + m; if (an >= NN) an = NN - 1;
        arow[r] = xcat + (size_t)an * K2 + quad * 8;
    }
    const ushort_t* brow[CW];
#pragma unroll
    for (int c = 0; c < CW; ++c)
        brow[c] = wcatT + (size_t)((wv * CW + c) * 16 + m) * K2 + quad * 8;

    for (int kk = 0; kk < K2; kk += 32) {
        short8 a[4], b[CW];
#pragma unroll
        for (int r = 0; r < 4; ++r) a[r] = *(const short8*)(arow[r] + kk);
#pragma unroll
        for (int c = 0; c < CW; ++c) b[c] = *(const short8*)(brow[c] + kk);
#pragma unroll
        for (int r = 0; r < 4; ++r)
#pragma unroll
            for (int c = 0; c < CW; ++c)
                acc[r][c] = __builtin_amdgcn_mfma_f32_16x16x32_bf16(a[r], b[c], acc[r][c], 0, 0, 0);
    }

    float bias[CW];
#pragma unroll
    for (int c = 0; c < CW; ++c) bias[c] = brel[(wv * CW + c) * 16 + m];

    if constexpr (MODE == 0) {
#pragma unroll
        for (int c = 0; c < CW; ++c) {
            const int col = (wv * CW + c) * 16 + m;
#pragma unroll
            for (int r = 0; r < 4; ++r)
#pragma unroll
                for (int rr = 0; rr < 4; ++rr) {
                    const int row = r0 + r * 16 + quad * 4 + rr;
                    if (row < NN)
                        outp[(size_t)row * DOUT + col] = acc[r][c][rr] + bias[c];
                }
        }
    } else {
        // graph-feature fusion: sum (acc + bias) per batch segment, atomic per col
        const int rtop = (r0 + 63 < NN) ? r0 + 63 : NN - 1;
        const int sb0 = batch[r0];
        const int sb1 = batch[rtop];
        for (int sb = sb0; sb <= sb1; ++sb) {
            const int lo = (bstart[sb] > r0) ? bstart[sb] : r0;
            int hi = bstart[sb + 1];
            if (hi > r0 + 64) hi = r0 + 64;
            float s[CW];
#pragma unroll
            for (int c = 0; c < CW; ++c) s[c] = 0.f;
#pragma unroll
            for (int r = 0; r < 4; ++r)
#pragma unroll
                for (int rr = 0; rr < 4; ++rr) {
                    const int row = r0 + r * 16 + quad * 4 + rr;
                    if (row >= lo && row < hi) {
#pragma unroll
                        for (int c = 0; c < CW; ++c) s[c] += acc[r][c][rr] + bias[c];
                    }
                }
#pragma unroll
            for (int c = 0; c < CW; ++c) {
                s[c] += __shfl_xor(s[c], 16);
                s[c] += __shfl_xor(s[c], 32);
            }
            if (quad == 0) {
#pragma unroll
                for (int c = 0; c < CW; ++c)
                    atomicAdd(&gfacc[sb * 256 + (wv * CW + c) * 16 + m], s[c]);
            }
        }
    }
}

// finalize graph features: h0[b*272 + c] = gfacc[b*256+c] / cnt[b]
__global__ void k_gffin(const float* __restrict__ gfacc, const int* __restrict__ bstart,
                        float* __restrict__ h0) {
    int idx = blockIdx.x * blockDim.x + threadIdx.x;
    if (idx >= NBATCH * 256) return;
    int b = idx >> 8, c = idx & 255;
    float cnt = fmaxf((float)(bstart[b + 1] - bstart[b]), 1.f);
    h0[b * 272 + c] = gfacc[idx] / cnt;
}

// ---------------- graph-norm + lrelu: fp32 in -> bf16 out (into xcat x-half) ----------------

template <int D, int OST>
__global__ __launch_bounds__(256) void k_graphnorm(
        const float* __restrict__ xf, ushort_t* __restrict__ xout,
        const int* __restrict__ bstart, const float* __restrict__ a,
        const float* __restrict__ g, const float* __restrict__ bb) {
    __shared__ float4 reds[256];
    __shared__ float4 redq[256];
    __shared__ float smean[64];
    __shared__ float sinv[64];
    const int b = blockIdx.x;
    const int col0 = blockIdx.y * 64;
    const int c4 = (threadIdx.x & 15) * 4;
    const int rg = threadIdx.x >> 4;
    const int beg = bstart[b], end = bstart[b + 1];
    const float cntf = fmaxf((float)(end - beg), 1.f);

    float4 s = {0.f, 0.f, 0.f, 0.f}, q = {0.f, 0.f, 0.f, 0.f};
    for (int r = beg + rg; r < end; r += 16) {
        const float4 v = *(const float4*)&xf[(size_t)r * D + col0 + c4];
        s.x += v.x; s.y += v.y; s.z += v.z; s.w += v.w;
        q.x += v.x * v.x; q.y += v.y * v.y; q.z += v.z * v.z; q.w += v.w * v.w;
    }
    reds[threadIdx.x] = s;
    redq[threadIdx.x] = q;
    __syncthreads();
    if (rg == 0) {
        float4 S = reds[threadIdx.x], Q = redq[threadIdx.x];
        for (int k = 1; k < 16; ++k) {
            const float4 s2 = reds[threadIdx.x + 16 * k];
            const float4 q2 = redq[threadIdx.x + 16 * k];
            S.x += s2.x; S.y += s2.y; S.z += s2.z; S.w += s2.w;
            Q.x += q2.x; Q.y += q2.y; Q.z += q2.z; Q.w += q2.w;
        }
        const float4 al = *(const float4*)&a[col0 + c4];
        const float Sv[4] = {S.x, S.y, S.z, S.w};
        const float Qv[4] = {Q.x, Q.y, Q.z, Q.w};
        const float av[4] = {al.x, al.y, al.z, al.w};
#pragma unroll
        for (int c = 0; c < 4; ++c) {
            const float mm = Sv[c] / cntf;
            const float ex2 = Qv[c] / cntf;
            const float var = fmaxf(ex2 - mm * mm * (2.f * av[c] - av[c] * av[c]), 0.f);
            smean[c4 + c] = mm;
            sinv[c4 + c] = 1.f / sqrtf(var + EPS);
        }
    }
    __syncthreads();
    const float4 mean4 = *(const float4*)&smean[c4];
    const float4 inv4 = *(const float4*)&sinv[c4];
    const float4 al4 = *(const float4*)&a[col0 + c4];
    const float4 g4 = *(const float4*)&g[col0 + c4];
    const float4 bb4 = *(const float4*)&bb[col0 + c4];
    for (int r = beg + rg; r < end; r += 16) {
        const float4 v = *(const float4*)&xf[(size_t)r * D + col0 + c4];
        float y0 = lrelu(g4.x * (v.x - al4.x * mean4.x) * inv4.x + bb4.x);
        float y1 = lrelu(g4.y * (v.y - al4.y * mean4.y) * inv4.y + bb4.y);
        float y2 = lrelu(g4.z * (v.z - al4.z * mean4.z) * inv4.z + bb4.z);
        float y3 = lrelu(g4.w * (v.w - al4.w * mean4.w) * inv4.w + bb4.w);
        uint2 o;
        o.x = (uint_t)f2b(y0) | ((uint_t)f2b(y1) << 16);
        o.y = (uint_t)f2b(y2) | ((uint_t)f2b(y3) << 16);
        *(uint2*)&xout[(size_t)r * OST + col0 + c4] = o;
    }
}

__global__ void k_demo(const float* __restrict__ dg, const float* __restrict__ w,
                       const float* __restrict__ b, float* __restrict__ h0) {
    int idx = blockIdx.x * blockDim.x + threadIdx.x;
    if (idx < NBATCH * 16) {
        int i = idx >> 4, j = idx & 15;
        float acc = b[j];
        for (int k = 0; k < 4; ++k) acc += dg[i * 4 + k] * w[k * 16 + j];
        h0[i * 272 + 256 + j] = acc;
    }
}

// fused linear + batch-norm + lrelu (fp32 head)
__global__ __launch_bounds__(128) void k_lin_bn(const float* __restrict__ in,
                                                const float* __restrict__ w,
                                                const float* __restrict__ bias,
                                                const float* __restrict__ g,
                                                const float* __restrict__ bb,
                                                float* __restrict__ out,
                                                int rows, int K, int C) {
    __shared__ float s1[128], s2[128];
    const int j = blockIdx.x;
    const int t = threadIdx.x;
    float v = 0.f;
    if (t < rows) {
        v = bias[j];
        for (int k = 0; k < K; ++k) v += in[t * K + k] * w[k * C + j];
    }
    s1[t] = (t < rows) ? v : 0.f;
    s2[t] = (t < rows) ? v * v : 0.f;
    __syncthreads();
    for (int off = 64; off > 0; off >>= 1) {
        if (t < off) { s1[t] += s1[t + off]; s2[t] += s2[t + off]; }
        __syncthreads();
    }
    const float m = s1[0] / rows;
    const float var = fmaxf(s2[0] / rows - m * m, 0.f);
    const float inv = 1.f / sqrtf(var + EPS);
    if (t < rows) out[t * C + j] = lrelu(g[j] * (v - m) * inv + bb[j]);
}

__global__ void k_linear(const float* __restrict__ in, const float* __restrict__ w,
                         const float* __restrict__ b, float* __restrict__ out,
                         int rows, int K, int D) {
    int total = rows * D;
    for (int idx = blockIdx.x * blockDim.x + threadIdx.x; idx < total; idx += gridDim.x * blockDim.x) {
        int i = idx / D, j = idx - i * D;
        float acc = b[j];
        for (int k = 0; k < K; ++k) acc += in[i * K + k] * w[k * D + j];
        out[idx] = acc;
    }
}

// ---------------- launcher ----------------

extern "C" void kernel_launch(void* const* d_in, const int* in_sizes, int n_in,
                              void* d_out, int out_size, void* d_ws, size_t ws_size,
                              hipStream_t stream) {
    const int*   x_idx  = (const int*)d_in[0];
    const int*   ei     = (const int*)d_in[1];
    const float* eattr  = (const float*)d_in[2];
    const int*   batch  = (const int*)d_in[3];
    const float* demog  = (const float*)d_in[4];
    const float* emb    = (const float*)d_in[5];
    const float* wrel1  = (const float*)d_in[6];
    const float* brel1  = (const float*)d_in[7];
    const float* wroot1 = (const float*)d_in[8];
    const float* wrel2  = (const float*)d_in[9];
    const float* brel2  = (const float*)d_in[10];
    const float* wroot2 = (const float*)d_in[11];
    const float* wrel3  = (const float*)d_in[12];
    const float* brel3  = (const float*)d_in[13];
    const float* wroot3 = (const float*)d_in[14];
    const float* gn1g = (const float*)d_in[15];
    const float* gn1b = (const float*)d_in[16];
    const float* gn1a = (const float*)d_in[17];
    const float* gn2g = (const float*)d_in[18];
    const float* gn2b = (const float*)d_in[19];
    const float* gn2a = (const float*)d_in[20];
    const float* dw   = (const float*)d_in[21];
    const float* db   = (const float*)d_in[22];
    const float* l1w  = (const float*)d_in[23];
    const float* l1b  = (const float*)d_in[24];
    const float* bn1g = (const float*)d_in[25];
    const float* bn1b = (const float*)d_in[26];
    const float* l2w  = (const float*)d_in[27];
    const float* l2b  = (const float*)d_in[28];
    const float* bn2g = (const float*)d_in[29];
    const float* bn2b = (const float*)d_in[30];
    const float* l3w  = (const float*)d_in[31];
    const float* l3b  = (const float*)d_in[32];
    float* out = (float*)d_out;

    float*    W     = (float*)d_ws;
    float*    xf    = W;                                   // fp32 conv out, 12.8M floats
    int2*     ebuf  = (int2*)W;                            // NE int2 (CSR build only; dead before conv1)
    float*    gfacc = W + 12800000;                        // NBATCH*256 fp32 (gf accumulator)
    ushort_t* xcat0 = (ushort_t*)(W + 25600000);           // NN*32 bf16  [agg0|x0]
    ushort_t* xcat1 = (ushort_t*)(W + 27200000);           // NN*128 bf16 [agg1|x1]
    ushort_t* xcat2 = (ushort_t*)(W + 33600000);           // NN*256 bf16 [agg2|x2]
    ushort_t* w1T   = (ushort_t*)(W + 46400000);           // 2048
    ushort_t* w2T   = w1T + 2048;                          // 16384
    ushort_t* w3T   = w2T + 16384;                         // 65536
    int2*     csr_pair = (int2*)(W + 46450000);            // NE int2
    int*      rowstart = (int*)(W + 49650000);             // NN+1
    int*      bstart   = (int*)(W + 49760000);             // NBATCH+1
    int*      bcnt     = (int*)(W + 49761000);             // NBUCK
    int*      bbase    = (int*)(W + 49762000);             // NBUCK+1
    int*      bcur     = (int*)(W + 49763000);             // NBUCK
    float*    h0 = W + 49770000;                           // 100*272
    float*    h1 = h0 + 27200;
    float*    h2 = h1 + 12800;

    const int* src = ei;
    const int* dst = ei + NE;

    auto gsz = [](long long t) {
        long long b = (t + 255) / 256;
        return (int)(b > 524288 ? 524288 : b);
    };
    const int mfma_blk = (NN + 63) / 64;     // 1563 (64 rows/block)
    const int nagg_blk = (NN + 3) / 4;       // 1 node/wave, 4 waves/block

    // ---- bucketed CSR build (by dst) ----
    hipMemsetAsync(bcnt, 0, NBUCK * sizeof(int), stream);
    k_bcount<<<256, 256, 0, stream>>>(dst, bcnt);
    k_bscan<<<1, 512, 0, stream>>>(bcnt, bbase, bcur, rowstart);
    k_bscatter<<<256, 256, 0, stream>>>(dst, src, eattr, bcur, ebuf);
    k_bfinal<<<NBUCK, 256, 0, stream>>>(ebuf, bbase, rowstart, csr_pair);

    k_bounds<<<1, 128, 0, stream>>>(batch, bstart);
    k_wpack<<<(83968 + 255) / 256, 256, 0, stream>>>(wrel1, wroot1, wrel2, wroot2, wrel3, wroot3,
                                                     w1T, w2T, w3T);
    hipMemsetAsync(gfacc, 0, NBATCH * 256 * sizeof(float), stream);

    // x0 (bf16) into xcat0 x-half
    k_gather_b<<<(NN + 255) / 256, 256, 0, stream>>>(x_idx, emb, xcat0);

    // conv1: [agg0|x0](K2=32) @ w1T -> xf (fp32 NN x 64)
    k_aggregate_b<16><<<nagg_blk, 256, 0, stream>>>(xcat0, csr_pair, rowstart);
    k_conv_mfma<32, 64, 0><<<mfma_blk, 256, 0, stream>>>(xcat0, w1T, brel1, xf, batch, bstart, nullptr);
    k_graphnorm<64, 128><<<dim3(NBATCH, 1), 256, 0, stream>>>(xf, xcat1 + 64, bstart, gn1a, gn1g, gn1b);

    // conv2: [agg1|x1](K2=128) @ w2T -> xf (fp32 NN x 128)
    k_aggregate_b<64><<<nagg_blk, 256, 0, stream>>>(xcat1, csr_pair, rowstart);
    k_conv_mfma<128, 128, 0><<<mfma_blk, 256, 0, stream>>>(xcat1, w2T, brel2, xf, batch, bstart, nullptr);
    k_graphnorm<128, 256><<<dim3(NBATCH, 2), 256, 0, stream>>>(xf, xcat2 + 128, bstart, gn2a, gn2g, gn2b);

    // conv3: [agg2|x2](K2=256) @ w3T -> gfacc directly (graph-feature fusion; x3 never materialized)
    k_aggregate_b<128><<<nagg_blk, 256, 0, stream>>>(xcat2, csr_pair, rowstart);
    k_conv_mfma<256, 256, 2><<<mfma_blk, 256, 0, stream>>>(xcat2, w3T, brel3, nullptr, batch, bstart, gfacc);

    // head
    k_gffin<<<(NBATCH * 256 + 255) / 256, 256, 0, stream>>>(gfacc, bstart, h0);
    k_demo<<<(NBATCH * 16 + 255) / 256, 256, 0, stream>>>(demog, dw, db, h0);
    k_lin_bn<<<128, 128, 0, stream>>>(h0, l1w, l1b, bn1g, bn1b, h1, NBATCH, 272, 128);
    k_lin_bn<<<64, 128, 0, stream>>>(h1, l2w, l2b, bn2g, bn2b, h2, NBATCH, 128, 64);
    k_linear<<<gsz(NBATCH * 3), 256, 0, stream>>>(h2, l3w, l3b, out, NBATCH, 64, 3);
}

// Round 15
// 662.898 us; speedup vs baseline: 3.0594x; 1.0081x over previous
//
#include <hip/hip_runtime.h>

// Problem constants (from reference)
#define NN 100000      // nodes
#define NE 1600000     // edges
#define NBATCH 100     // graphs
#define NBUCK 391      // ceil(NN / 256) coarse buckets for CSR build
constexpr float EPS = 1e-5f;

typedef unsigned short ushort_t;
typedef unsigned int uint_t;

using short8 = __attribute__((ext_vector_type(8))) short;   // 8 bf16 (4 VGPRs)
using floatx4 = __attribute__((ext_vector_type(4))) float;  // 4 fp32 acc

__device__ __forceinline__ float lrelu(float x) { return x > 0.f ? x : 0.01f * x; }

__device__ __forceinline__ float b2f(ushort_t u) {
    union { uint_t i; float f; } c; c.i = ((uint_t)u) << 16; return c.f;
}
__device__ __forceinline__ ushort_t f2b(float f) {
    union { float f; uint_t i; } c; c.f = f;
    uint_t u = c.i;
    return (ushort_t)((u + 0x7FFFu + ((u >> 16) & 1u)) >> 16);   // RNE
}
__device__ __forceinline__ void unpack8(const uint4 u, float* f) {
    f[0] = b2f(u.x & 0xffff); f[1] = b2f(u.x >> 16);
    f[2] = b2f(u.y & 0xffff); f[3] = b2f(u.y >> 16);
    f[4] = b2f(u.z & 0xffff); f[5] = b2f(u.z >> 16);
    f[6] = b2f(u.w & 0xffff); f[7] = b2f(u.w >> 16);
}

// ---------------- bucketed CSR build ----------------

__global__ __launch_bounds__(256) void k_bcount(const int* __restrict__ dst,
                                                int* __restrict__ bcnt) {
    __shared__ int h[NBUCK];
    for (int i = threadIdx.x; i < NBUCK; i += 256) h[i] = 0;
    __syncthreads();
    for (int e = blockIdx.x * 256 + threadIdx.x; e < NE; e += gridDim.x * 256)
        atomicAdd(&h[dst[e] >> 8], 1);
    __syncthreads();
    for (int i = threadIdx.x; i < NBUCK; i += 256)
        if (h[i]) atomicAdd(&bcnt[i], h[i]);
}

__global__ __launch_bounds__(512) void k_bscan(const int* __restrict__ bcnt,
                                               int* __restrict__ bbase,
                                               int* __restrict__ bcur,
                                               int* __restrict__ rowstart) {
    __shared__ int s[512];
    const int t = threadIdx.x;
    const int v = (t < NBUCK) ? bcnt[t] : 0;
    s[t] = v;
    __syncthreads();
    for (int off = 1; off < 512; off <<= 1) {
        int o = (t >= off) ? s[t - off] : 0;
        __syncthreads();
        s[t] += o;
        __syncthreads();
    }
    const int excl = s[t] - v;
    if (t < NBUCK) { bbase[t] = excl; bcur[t] = excl; }
    if (t == 0) { bbase[NBUCK] = NE; rowstart[NN] = NE; }
}

__global__ __launch_bounds__(256) void k_bscatter(const int* __restrict__ dst,
                                                  const int* __restrict__ srcv,
                                                  const float* __restrict__ ew,
                                                  int* __restrict__ bcur,
                                                  int2* __restrict__ ebuf) {
    __shared__ int h[NBUCK];
    __shared__ int lcur[NBUCK];
    const int chunk = (NE + gridDim.x - 1) / gridDim.x;
    const int beg = blockIdx.x * chunk;
    const int end = (beg + chunk < NE) ? beg + chunk : NE;
    for (int i = threadIdx.x; i < NBUCK; i += 256) h[i] = 0;
    __syncthreads();
    for (int e = beg + threadIdx.x; e < end; e += 256)
        atomicAdd(&h[dst[e] >> 8], 1);
    __syncthreads();
    for (int i = threadIdx.x; i < NBUCK; i += 256)
        lcur[i] = h[i] ? atomicAdd(&bcur[i], h[i]) : 0;
    __syncthreads();
    for (int e = beg + threadIdx.x; e < end; e += 256) {
        const int d = dst[e];
        const int pos = atomicAdd(&lcur[d >> 8], 1);
        ebuf[pos] = make_int2(srcv[e] | ((d & 255) << 20), __float_as_int(ew[e]));
    }
}

__global__ __launch_bounds__(256) void k_bfinal(const int2* __restrict__ ebuf,
                                                const int* __restrict__ bbase,
                                                int* __restrict__ rowstart,
                                                int2* __restrict__ csr_pair) {
    __shared__ int h[256];
    __shared__ int cur[256];
    const int b = blockIdx.x;
    const int t = threadIdx.x;
    const int base = bbase[b];
    const int cnt = bbase[b + 1] - base;
    h[t] = 0;
    __syncthreads();
    for (int i = t; i < cnt; i += 256)
        atomicAdd(&h[(ebuf[base + i].x >> 20) & 255], 1);
    __syncthreads();
    const int v = h[t];
    cur[t] = v;
    __syncthreads();
    for (int off = 1; off < 256; off <<= 1) {
        int o = (t >= off) ? cur[t - off] : 0;
        __syncthreads();
        cur[t] += o;
        __syncthreads();
    }
    const int excl = cur[t] - v;
    const int n = (b << 8) + t;
    if (n < NN) rowstart[n] = base + excl;
    __syncthreads();
    cur[t] = excl;
    __syncthreads();
    for (int i = t; i < cnt; i += 256) {
        const int2 p = ebuf[base + i];
        const int loc = (p.x >> 20) & 255;
        const int pos = base + atomicAdd(&cur[loc], 1);
        csr_pair[pos] = make_int2(p.x & 0xFFFFF, p.y);
    }
}

__global__ void k_bounds(const int* __restrict__ batch, int* __restrict__ bstart) {
    int b = blockIdx.x * blockDim.x + threadIdx.x;
    if (b > NBATCH) return;
    int lo = 0, hi = NN;
    while (lo < hi) {
        int mid = (lo + hi) >> 1;
        if (batch[mid] < b) lo = mid + 1; else hi = mid;
    }
    bstart[b] = lo;
}

// ---------------- weight pack ----------------------------------------------------------------

__global__ void k_wpack(const float* __restrict__ wr1, const float* __restrict__ wo1,
                        const float* __restrict__ wr2, const float* __restrict__ wo2,
                        const float* __restrict__ wr3, const float* __restrict__ wo3,
                        ushort_t* __restrict__ w1T, ushort_t* __restrict__ w2T,
                        ushort_t* __restrict__ w3T) {
    int idx = blockIdx.x * blockDim.x + threadIdx.x;
    if (idx < 2048) {                                  // conv1: DOUT=64, K2=32
        int n = idx >> 5, k = idx & 31;
        float v = (k < 16) ? wr1[k * 64 + n] : wo1[(k - 16) * 64 + n];
        w1T[idx] = f2b(v);
    } else if (idx < 2048 + 16384) {                   // conv2: DOUT=128, K2=128
        int l = idx - 2048; int n = l >> 7, k = l & 127;
        float v = (k < 64) ? wr2[k * 128 + n] : wo2[(k - 64) * 128 + n];
        w2T[l] = f2b(v);
    } else if (idx < 2048 + 16384 + 65536) {           // conv3: DOUT=256, K2=256
        int l = idx - 18432; int n = l >> 8, k = l & 255;
        float v = (k < 128) ? wr3[k * 256 + n] : wo3[(k - 128) * 256 + n];
        w3T[l] = f2b(v);
    }
}

// ---------------- embedding gather -> bf16 x-half of xcat0 ----------------------------------

__global__ void k_gather_b(const int* __restrict__ xi, const float* __restrict__ emb,
                           ushort_t* __restrict__ xcat0) {
    int n = blockIdx.x * blockDim.x + threadIdx.x;
    if (n >= NN) return;
    const float* e = emb + ((size_t)xi[n] << 4);
    uint_t u[8];
#pragma unroll
    for (int j = 0; j < 8; ++j)
        u[j] = (uint_t)f2b(e[2 * j]) | ((uint_t)f2b(e[2 * j + 1]) << 16);
    uint4* o = (uint4*)(xcat0 + (size_t)n * 32 + 16);
    o[0] = {u[0], u[1], u[2], u[3]};
    o[1] = {u[4], u[5], u[6], u[7]};
}

// ---------------- aggregate (bf16 in/out) ----------------------------------------------------

template <int D>
__global__ void k_aggregate_b(ushort_t* __restrict__ xcat, const int2* __restrict__ csr_pair,
                              const int* __restrict__ rowstart) {
    constexpr int LPN = D / 8;
    constexpr int EP = 64 / LPN;
    const int n = blockIdx.x * 4 + (threadIdx.x >> 6);
    const int lane = threadIdx.x & 63;
    const int sl = lane % LPN;
    const int eg = lane / LPN;
    if (n >= NN) return;
    const int beg = rowstart[n], end = rowstart[n + 1];
    float a0[8] = {}, a1[8] = {};
    int i = beg + eg;
    for (; i + EP < end; i += 2 * EP) {
        const int2 p0 = csr_pair[i];
        const int2 p1 = csr_pair[i + EP];
        const float w0 = __int_as_float(p0.y);
        const float w1 = __int_as_float(p1.y);
        const uint4 u0 = *(const uint4*)(xcat + (size_t)p0.x * (2 * D) + D + sl * 8);
        const uint4 u1 = *(const uint4*)(xcat + (size_t)p1.x * (2 * D) + D + sl * 8);
        float f0[8], f1[8];
        unpack8(u0, f0); unpack8(u1, f1);
#pragma unroll
        for (int j = 0; j < 8; ++j) { a0[j] += f0[j] * w0; a1[j] += f1[j] * w1; }
    }
    if (i < end) {
        const int2 p0 = csr_pair[i];
        const float w0 = __int_as_float(p0.y);
        const uint4 u0 = *(const uint4*)(xcat + (size_t)p0.x * (2 * D) + D + sl * 8);
        float f0[8];
        unpack8(u0, f0);
#pragma unroll
        for (int j = 0; j < 8; ++j) a0[j] += f0[j] * w0;
    }
#pragma unroll
    for (int j = 0; j < 8; ++j) a0[j] += a1[j];
#pragma unroll
    for (int m = LPN; m < 64; m <<= 1)
#pragma unroll
        for (int j = 0; j < 8; ++j) a0[j] += __shfl_xor(a0[j], m);
    if (eg == 0) {
        uint_t u[4];
#pragma unroll
        for (int j = 0; j < 4; ++j)
            u[j] = (uint_t)f2b(a0[2 * j]) | ((uint_t)f2b(a0[2 * j + 1]) << 16);
        *(uint4*)(xcat + (size_t)n * (2 * D) + sl * 8) = {u[0], u[1], u[2], u[3]};
    }
}

// ---------------- conv GEMM via bf16 MFMA ---------------------------------------------------
// MODE 0: fp32 out. MODE 2: graph-feature fusion into gfacc (x3 never materialized).

template <int K2, int DOUT, int MODE>
__global__ __launch_bounds__(256) void k_conv_mfma(
        const ushort_t* __restrict__ xcat, const ushort_t* __restrict__ wcatT,
        const float* __restrict__ brel, float* __restrict__ outp,
        const int* __restrict__ batch, const int* __restrict__ bstart,
        float* __restrict__ gfacc) {
    constexpr int CW = DOUT / 64;          // col tiles per wave (1, 2, 4)
    const int lane = threadIdx.x & 63;
    const int wv = threadIdx.x >> 6;
    const int m = lane & 15;
    const int quad = lane >> 4;
    const int r0 = blockIdx.x * 64;

    floatx4 acc[4][CW] = {};

    const ushort_t* arow[4];
#pragma unroll
    for (int r = 0; r < 4; ++r) {
        int an = r0 + r * 16 + m; if (an >= NN) an = NN - 1;
        arow[r] = xcat + (size_t)an * K2 + quad * 8;
    }
    const ushort_t* brow[CW];
#pragma unroll
    for (int c = 0; c < CW; ++c)
        brow[c] = wcatT + (size_t)((wv * CW + c) * 16 + m) * K2 + quad * 8;

    for (int kk = 0; kk < K2; kk += 32) {
        short8 a[4], b[CW];
#pragma unroll
        for (int r = 0; r < 4; ++r) a[r] = *(const short8*)(arow[r] + kk);
#pragma unroll
        for (int c = 0; c < CW; ++c) b[c] = *(const short8*)(brow[c] + kk);
#pragma unroll
        for (int r = 0; r < 4; ++r)
#pragma unroll
            for (int c = 0; c < CW; ++c)
                acc[r][c] = __builtin_amdgcn_mfma_f32_16x16x32_bf16(a[r], b[c], acc[r][c], 0, 0, 0);
    }

    float bias[CW];
#pragma unroll
    for (int c = 0; c < CW; ++c) bias[c] = brel[(wv * CW + c) * 16 + m];

    if constexpr (MODE == 0) {
#pragma unroll
        for (int c = 0; c < CW; ++c) {
            const int col = (wv * CW + c) * 16 + m;
#pragma unroll
            for (int r = 0; r < 4; ++r)
#pragma unroll
                for (int rr = 0; rr < 4; ++rr) {
                    const int row = r0 + r * 16 + quad * 4 + rr;
                    if (row < NN)
                        outp[(size_t)row * DOUT + col] = acc[r][c][rr] + bias[c];
                }
        }
    } else {
        const int rtop = (r0 + 63 < NN) ? r0 + 63 : NN - 1;
        const int sb0 = batch[r0];
        const int sb1 = batch[rtop];
        for (int sb = sb0; sb <= sb1; ++sb) {
            const int lo = (bstart[sb] > r0) ? bstart[sb] : r0;
            int hi = bstart[sb + 1];
            if (hi > r0 + 64) hi = r0 + 64;
            float s[CW];
#pragma unroll
            for (int c = 0; c < CW; ++c) s[c] = 0.f;
#pragma unroll
            for (int r = 0; r < 4; ++r)
#pragma unroll
                for (int rr = 0; rr < 4; ++rr) {
                    const int row = r0 + r * 16 + quad * 4 + rr;
                    if (row >= lo && row < hi) {
#pragma unroll
                        for (int c = 0; c < CW; ++c) s[c] += acc[r][c][rr] + bias[c];
                    }
                }
#pragma unroll
            for (int c = 0; c < CW; ++c) {
                s[c] += __shfl_xor(s[c], 16);
                s[c] += __shfl_xor(s[c], 32);
            }
            if (quad == 0) {
#pragma unroll
                for (int c = 0; c < CW; ++c)
                    atomicAdd(&gfacc[sb * 256 + (wv * CW + c) * 16 + m], s[c]);
            }
        }
    }
}

// finalize graph features: h0[b*272 + c] = gfacc[b*256+c] / cnt[b]
__global__ void k_gffin(const float* __restrict__ gfacc, const int* __restrict__ bstart,
                        float* __restrict__ h0) {
    int idx = blockIdx.x * blockDim.x + threadIdx.x;
    if (idx >= NBATCH * 256) return;
    int b = idx >> 8, c = idx & 255;
    float cnt = fmaxf((float)(bstart[b + 1] - bstart[b]), 1.f);
    h0[b * 272 + c] = gfacc[idx] / cnt;
}

// ---------------- graph-norm + lrelu: fp32 in -> bf16 out (into xcat x-half) ----------------

template <int D, int OST>
__global__ __launch_bounds__(256) void k_graphnorm(
        const float* __restrict__ xf, ushort_t* __restrict__ xout,
        const int* __restrict__ bstart, const float* __restrict__ a,
        const float* __restrict__ g, const float* __restrict__ bb) {
    __shared__ float4 reds[256];
    __shared__ float4 redq[256];
    __shared__ float smean[64];
    __shared__ float sinv[64];
    const int b = blockIdx.x;
    const int col0 = blockIdx.y * 64;
    const int c4 = (threadIdx.x & 15) * 4;
    const int rg = threadIdx.x >> 4;
    const int beg = bstart[b], end = bstart[b + 1];
    const float cntf = fmaxf((float)(end - beg), 1.f);

    float4 s = {0.f, 0.f, 0.f, 0.f}, q = {0.f, 0.f, 0.f, 0.f};
    for (int r = beg + rg; r < end; r += 16) {
        const float4 v = *(const float4*)&xf[(size_t)r * D + col0 + c4];
        s.x += v.x; s.y += v.y; s.z += v.z; s.w += v.w;
        q.x += v.x * v.x; q.y += v.y * v.y; q.z += v.z * v.z; q.w += v.w * v.w;
    }
    reds[threadIdx.x] = s;
    redq[threadIdx.x] = q;
    __syncthreads();
    if (rg == 0) {
        float4 S = reds[threadIdx.x], Q = redq[threadIdx.x];
        for (int k = 1; k < 16; ++k) {
            const float4 s2 = reds[threadIdx.x + 16 * k];
            const float4 q2 = redq[threadIdx.x + 16 * k];
            S.x += s2.x; S.y += s2.y; S.z += s2.z; S.w += s2.w;
            Q.x += q2.x; Q.y += q2.y; Q.z += q2.z; Q.w += q2.w;
        }
        const float4 al = *(const float4*)&a[col0 + c4];
        const float Sv[4] = {S.x, S.y, S.z, S.w};
        const float Qv[4] = {Q.x, Q.y, Q.z, Q.w};
        const float av[4] = {al.x, al.y, al.z, al.w};
#pragma unroll
        for (int c = 0; c < 4; ++c) {
            const float mm = Sv[c] / cntf;
            const float ex2 = Qv[c] / cntf;
            const float var = fmaxf(ex2 - mm * mm * (2.f * av[c] - av[c] * av[c]), 0.f);
            smean[c4 + c] = mm;
            sinv[c4 + c] = 1.f / sqrtf(var + EPS);
        }
    }
    __syncthreads();
    const float4 mean4 = *(const float4*)&smean[c4];
    const float4 inv4 = *(const float4*)&sinv[c4];
    const float4 al4 = *(const float4*)&a[col0 + c4];
    const float4 g4 = *(const float4*)&g[col0 + c4];
    const float4 bb4 = *(const float4*)&bb[col0 + c4];
    for (int r = beg + rg; r < end; r += 16) {
        const float4 v = *(const float4*)&xf[(size_t)r * D + col0 + c4];
        float y0 = lrelu(g4.x * (v.x - al4.x * mean4.x) * inv4.x + bb4.x);
        float y1 = lrelu(g4.y * (v.y - al4.y * mean4.y) * inv4.y + bb4.y);
        float y2 = lrelu(g4.z * (v.z - al4.z * mean4.z) * inv4.z + bb4.z);
        float y3 = lrelu(g4.w * (v.w - al4.w * mean4.w) * inv4.w + bb4.w);
        uint2 o;
        o.x = (uint_t)f2b(y0) | ((uint_t)f2b(y1) << 16);
        o.y = (uint_t)f2b(y2) | ((uint_t)f2b(y3) << 16);
        *(uint2*)&xout[(size_t)r * OST + col0 + c4] = o;
    }
}

__global__ void k_demo(const float* __restrict__ dg, const float* __restrict__ w,
                       const float* __restrict__ b, float* __restrict__ h0) {
    int idx = blockIdx.x * blockDim.x + threadIdx.x;
    if (idx < NBATCH * 16) {
        int i = idx >> 4, j = idx & 15;
        float acc = b[j];
        for (int k = 0; k < 4; ++k) acc += dg[i * 4 + k] * w[k * 16 + j];
        h0[i * 272 + 256 + j] = acc;
    }
}

// ---------------- head: z = in @ w + bias, block = 16-row tile x C col-threads -------------
// LDS-staged in-tile (coalesced); K-loop: one coalesced w load + 16 broadcast FMAs.

template <int K, int C>
__global__ __launch_bounds__(C) void k_head_lin(const float* __restrict__ in,
                                                const float* __restrict__ w,
                                                const float* __restrict__ bias,
                                                float* __restrict__ z, int rows) {
    __shared__ float s_in[16][K];
    const int j = threadIdx.x;
    const int r0 = blockIdx.x * 16;
    for (int idx = threadIdx.x; idx < 16 * K; idx += C) {
        int r = idx / K, k = idx - r * K;
        s_in[r][k] = (r0 + r < rows) ? in[(size_t)(r0 + r) * K + k] : 0.f;
    }
    __syncthreads();
    float acc[16];
#pragma unroll
    for (int r = 0; r < 16; ++r) acc[r] = 0.f;
    for (int k = 0; k < K; ++k) {
        const float wv = w[k * C + j];
#pragma unroll
        for (int r = 0; r < 16; ++r) acc[r] += s_in[r][k] * wv;
    }
    const float bj = bias[j];
#pragma unroll
    for (int r = 0; r < 16; ++r)
        if (r0 + r < rows) z[(size_t)(r0 + r) * C + j] = acc[r] + bj;
}

// batch-norm + lrelu over rows, in place; one block, C threads, coalesced.
__global__ void k_head_bn(float* __restrict__ z, const float* __restrict__ g,
                          const float* __restrict__ b, int rows, int C) {
    const int j = threadIdx.x;
    if (j >= C) return;
    float s = 0.f, q = 0.f;
    for (int i = 0; i < rows; ++i) { const float v = z[i * C + j]; s += v; q += v * v; }
    const float m = s / rows;
    const float var = fmaxf(q / rows - m * m, 0.f);
    const float inv = 1.f / sqrtf(var + EPS);
    const float gg = g[j], bb = b[j];
    for (int i = 0; i < rows; ++i)
        z[i * C + j] = lrelu(gg * (z[i * C + j] - m) * inv + bb);
}

// final l3: out[100,3] = h2[100,64] @ w + b; one block, LDS-staged (padded stride 65).
__global__ __launch_bounds__(256) void k_head_out(const float* __restrict__ h2,
                                                  const float* __restrict__ w,
                                                  const float* __restrict__ b,
                                                  float* __restrict__ out) {
    __shared__ float s[NBATCH * 65];
    for (int idx = threadIdx.x; idx < NBATCH * 64; idx += 256) {
        int i = idx >> 6, k = idx & 63;
        s[i * 65 + k] = h2[idx];
    }
    __syncthreads();
    const int i = threadIdx.x;
    if (i < NBATCH) {
        float a0 = b[0], a1 = b[1], a2 = b[2];
        for (int k = 0; k < 64; ++k) {
            const float v = s[i * 65 + k];
            a0 += v * w[k * 3 + 0];
            a1 += v * w[k * 3 + 1];
            a2 += v * w[k * 3 + 2];
        }
        out[i * 3 + 0] = a0; out[i * 3 + 1] = a1; out[i * 3 + 2] = a2;
    }
}

// ---------------- launcher ----------------

extern "C" void kernel_launch(void* const* d_in, const int* in_sizes, int n_in,
                              void* d_out, int out_size, void* d_ws, size_t ws_size,
                              hipStream_t stream) {
    const int*   x_idx  = (const int*)d_in[0];
    const int*   ei     = (const int*)d_in[1];
    const float* eattr  = (const float*)d_in[2];
    const int*   batch  = (const int*)d_in[3];
    const float* demog  = (const float*)d_in[4];
    const float* emb    = (const float*)d_in[5];
    const float* wrel1  = (const float*)d_in[6];
    const float* brel1  = (const float*)d_in[7];
    const float* wroot1 = (const float*)d_in[8];
    const float* wrel2  = (const float*)d_in[9];
    const float* brel2  = (const float*)d_in[10];
    const float* wroot2 = (const float*)d_in[11];
    const float* wrel3  = (const float*)d_in[12];
    const float* brel3  = (const float*)d_in[13];
    const float* wroot3 = (const float*)d_in[14];
    const float* gn1g = (const float*)d_in[15];
    const float* gn1b = (const float*)d_in[16];
    const float* gn1a = (const float*)d_in[17];
    const float* gn2g = (const float*)d_in[18];
    const float* gn2b = (const float*)d_in[19];
    const float* gn2a = (const float*)d_in[20];
    const float* dw   = (const float*)d_in[21];
    const float* db   = (const float*)d_in[22];
    const float* l1w  = (const float*)d_in[23];
    const float* l1b  = (const float*)d_in[24];
    const float* bn1g = (const float*)d_in[25];
    const float* bn1b = (const float*)d_in[26];
    const float* l2w  = (const float*)d_in[27];
    const float* l2b  = (const float*)d_in[28];
    const float* bn2g = (const float*)d_in[29];
    const float* bn2b = (const float*)d_in[30];
    const float* l3w  = (const float*)d_in[31];
    const float* l3b  = (const float*)d_in[32];
    float* out = (float*)d_out;

    float*    W     = (float*)d_ws;
    float*    xf    = W;                                   // fp32 conv out, 12.8M floats
    int2*     ebuf  = (int2*)W;                            // NE int2 (CSR build only)
    float*    gfacc = W + 12800000;                        // NBATCH*256 fp32
    ushort_t* xcat0 = (ushort_t*)(W + 25600000);           // NN*32 bf16  [agg0|x0]
    ushort_t* xcat1 = (ushort_t*)(W + 27200000);           // NN*128 bf16 [agg1|x1]
    ushort_t* xcat2 = (ushort_t*)(W + 33600000);           // NN*256 bf16 [agg2|x2]
    ushort_t* w1T   = (ushort_t*)(W + 46400000);           // 2048
    ushort_t* w2T   = w1T + 2048;                          // 16384
    ushort_t* w3T   = w2T + 16384;                         // 65536
    int2*     csr_pair = (int2*)(W + 46450000);            // NE int2
    int*      rowstart = (int*)(W + 49650000);             // NN+1
    int*      bstart   = (int*)(W + 49760000);             // NBATCH+1
    int*      bcnt     = (int*)(W + 49761000);             // NBUCK
    int*      bbase    = (int*)(W + 49762000);             // NBUCK+1
    int*      bcur     = (int*)(W + 49763000);             // NBUCK
    float*    h0 = W + 49770000;                           // 100*272
    float*    h1 = h0 + 27200;
    float*    h2 = h1 + 12800;

    const int* src = ei;
    const int* dst = ei + NE;

    const int mfma_blk = (NN + 63) / 64;     // 1563 (64 rows/block)
    const int nagg_blk = (NN + 3) / 4;       // 1 node/wave, 4 waves/block

    // ---- bucketed CSR build (by dst) ----
    hipMemsetAsync(bcnt, 0, NBUCK * sizeof(int), stream);
    k_bcount<<<256, 256, 0, stream>>>(dst, bcnt);
    k_bscan<<<1, 512, 0, stream>>>(bcnt, bbase, bcur, rowstart);
    k_bscatter<<<256, 256, 0, stream>>>(dst, src, eattr, bcur, ebuf);
    k_bfinal<<<NBUCK, 256, 0, stream>>>(ebuf, bbase, rowstart, csr_pair);

    k_bounds<<<1, 128, 0, stream>>>(batch, bstart);
    k_wpack<<<(83968 + 255) / 256, 256, 0, stream>>>(wrel1, wroot1, wrel2, wroot2, wrel3, wroot3,
                                                     w1T, w2T, w3T);
    hipMemsetAsync(gfacc, 0, NBATCH * 256 * sizeof(float), stream);

    // x0 (bf16) into xcat0 x-half
    k_gather_b<<<(NN + 255) / 256, 256, 0, stream>>>(x_idx, emb, xcat0);

    // conv1: [agg0|x0](K2=32) @ w1T -> xf (fp32 NN x 64)
    k_aggregate_b<16><<<nagg_blk, 256, 0, stream>>>(xcat0, csr_pair, rowstart);
    k_conv_mfma<32, 64, 0><<<mfma_blk, 256, 0, stream>>>(xcat0, w1T, brel1, xf, batch, bstart, nullptr);
    k_graphnorm<64, 128><<<dim3(NBATCH, 1), 256, 0, stream>>>(xf, xcat1 + 64, bstart, gn1a, gn1g, gn1b);

    // conv2: [agg1|x1](K2=128) @ w2T -> xf (fp32 NN x 128)
    k_aggregate_b<64><<<nagg_blk, 256, 0, stream>>>(xcat1, csr_pair, rowstart);
    k_conv_mfma<128, 128, 0><<<mfma_blk, 256, 0, stream>>>(xcat1, w2T, brel2, xf, batch, bstart, nullptr);
    k_graphnorm<128, 256><<<dim3(NBATCH, 2), 256, 0, stream>>>(xf, xcat2 + 128, bstart, gn2a, gn2g, gn2b);

    // conv3: [agg2|x2](K2=256) @ w3T -> gfacc directly (x3 never materialized)
    k_aggregate_b<128><<<nagg_blk, 256, 0, stream>>>(xcat2, csr_pair, rowstart);
    k_conv_mfma<256, 256, 2><<<mfma_blk, 256, 0, stream>>>(xcat2, w3T, brel3, nullptr, batch, bstart, gfacc);

    // head
    k_gffin<<<(NBATCH * 256 + 255) / 256, 256, 0, stream>>>(gfacc, bstart, h0);
    k_demo<<<(NBATCH * 16 + 255) / 256, 256, 0, stream>>>(demog, dw, db, h0);
    k_head_lin<272, 128><<<(NBATCH + 15) / 16, 128, 0, stream>>>(h0, l1w, l1b, h1, NBATCH);
    k_head_bn<<<1, 128, 0, stream>>>(h1, bn1g, bn1b, NBATCH, 128);
    k_head_lin<128, 64><<<(NBATCH + 15) / 16, 64, 0, stream>>>(h1, l2w, l2b, h2, NBATCH);
    k_head_bn<<<1, 64, 0, stream>>>(h2, bn2g, bn2b, NBATCH, 64);
    k_head_out<<<1, 256, 0, stream>>>(h2, l3w, l3b, out);
}

// Round 16
// 650.206 us; speedup vs baseline: 3.1191x; 1.0195x over previous
//
#include <hip/hip_runtime.h>

// Problem constants (from reference)
#define NN 100000      // nodes
#define NE 1600000     // edges
#define NBATCH 100     // graphs
#define NBUCK 391      // ceil(NN / 256) coarse buckets for CSR build
constexpr float EPS = 1e-5f;

typedef unsigned short ushort_t;
typedef unsigned int uint_t;
typedef unsigned char uchar_t;

using short8 = __attribute__((ext_vector_type(8))) short;   // 8 bf16 (4 VGPRs)
using floatx4 = __attribute__((ext_vector_type(4))) float;  // 4 fp32 acc
using floatx2 = __attribute__((ext_vector_type(2))) float;

__device__ __forceinline__ float lrelu(float x) { return x > 0.f ? x : 0.01f * x; }

__device__ __forceinline__ float b2f(ushort_t u) {
    union { uint_t i; float f; } c; c.i = ((uint_t)u) << 16; return c.f;
}
__device__ __forceinline__ ushort_t f2b(float f) {
    union { float f; uint_t i; } c; c.f = f;
    uint_t u = c.i;
    return (ushort_t)((u + 0x7FFFu + ((u >> 16) & 1u)) >> 16);   // RNE
}
__device__ __forceinline__ void unpack8(const uint4 u, float* f) {
    f[0] = b2f(u.x & 0xffff); f[1] = b2f(u.x >> 16);
    f[2] = b2f(u.y & 0xffff); f[3] = b2f(u.y >> 16);
    f[4] = b2f(u.z & 0xffff); f[5] = b2f(u.z >> 16);
    f[6] = b2f(u.w & 0xffff); f[7] = b2f(u.w >> 16);
}
// 8 OCP e4m3 bytes -> 8 fp32 via hw v_cvt_pk_f32_fp8
__device__ __forceinline__ void unpack8_f8(const uint2 u, float* f) {
    floatx2 a = __builtin_amdgcn_cvt_pk_f32_fp8(u.x, false);
    floatx2 b = __builtin_amdgcn_cvt_pk_f32_fp8(u.x, true);
    floatx2 c = __builtin_amdgcn_cvt_pk_f32_fp8(u.y, false);
    floatx2 d = __builtin_amdgcn_cvt_pk_f32_fp8(u.y, true);
    f[0] = a[0]; f[1] = a[1]; f[2] = b[0]; f[3] = b[1];
    f[4] = c[0]; f[5] = c[1]; f[6] = d[0]; f[7] = d[1];
}

// ---------------- bucketed CSR build ----------------

__global__ __launch_bounds__(256) void k_bcount(const int* __restrict__ dst,
                                                int* __restrict__ bcnt) {
    __shared__ int h[NBUCK];
    for (int i = threadIdx.x; i < NBUCK; i += 256) h[i] = 0;
    __syncthreads();
    for (int e = blockIdx.x * 256 + threadIdx.x; e < NE; e += gridDim.x * 256)
        atomicAdd(&h[dst[e] >> 8], 1);
    __syncthreads();
    for (int i = threadIdx.x; i < NBUCK; i += 256)
        if (h[i]) atomicAdd(&bcnt[i], h[i]);
}

__global__ __launch_bounds__(512) void k_bscan(const int* __restrict__ bcnt,
                                               int* __restrict__ bbase,
                                               int* __restrict__ bcur,
                                               int* __restrict__ rowstart) {
    __shared__ int s[512];
    const int t = threadIdx.x;
    const int v = (t < NBUCK) ? bcnt[t] : 0;
    s[t] = v;
    __syncthreads();
    for (int off = 1; off < 512; off <<= 1) {
        int o = (t >= off) ? s[t - off] : 0;
        __syncthreads();
        s[t] += o;
        __syncthreads();
    }
    const int excl = s[t] - v;
    if (t < NBUCK) { bbase[t] = excl; bcur[t] = excl; }
    if (t == 0) { bbase[NBUCK] = NE; rowstart[NN] = NE; }
}

__global__ __launch_bounds__(256) void k_bscatter(const int* __restrict__ dst,
                                                  const int* __restrict__ srcv,
                                                  const float* __restrict__ ew,
                                                  int* __restrict__ bcur,
                                                  int2* __restrict__ ebuf) {
    __shared__ int h[NBUCK];
    __shared__ int lcur[NBUCK];
    const int chunk = (NE + gridDim.x - 1) / gridDim.x;
    const int beg = blockIdx.x * chunk;
    const int end = (beg + chunk < NE) ? beg + chunk : NE;
    for (int i = threadIdx.x; i < NBUCK; i += 256) h[i] = 0;
    __syncthreads();
    for (int e = beg + threadIdx.x; e < end; e += 256)
        atomicAdd(&h[dst[e] >> 8], 1);
    __syncthreads();
    for (int i = threadIdx.x; i < NBUCK; i += 256)
        lcur[i] = h[i] ? atomicAdd(&bcur[i], h[i]) : 0;
    __syncthreads();
    for (int e = beg + threadIdx.x; e < end; e += 256) {
        const int d = dst[e];
        const int pos = atomicAdd(&lcur[d >> 8], 1);
        ebuf[pos] = make_int2(srcv[e] | ((d & 255) << 20), __float_as_int(ew[e]));
    }
}

__global__ __launch_bounds__(256) void k_bfinal(const int2* __restrict__ ebuf,
                                                const int* __restrict__ bbase,
                                                int* __restrict__ rowstart,
                                                int2* __restrict__ csr_pair) {
    __shared__ int h[256];
    __shared__ int cur[256];
    const int b = blockIdx.x;
    const int t = threadIdx.x;
    const int base = bbase[b];
    const int cnt = bbase[b + 1] - base;
    h[t] = 0;
    __syncthreads();
    for (int i = t; i < cnt; i += 256)
        atomicAdd(&h[(ebuf[base + i].x >> 20) & 255], 1);
    __syncthreads();
    const int v = h[t];
    cur[t] = v;
    __syncthreads();
    for (int off = 1; off < 256; off <<= 1) {
        int o = (t >= off) ? cur[t - off] : 0;
        __syncthreads();
        cur[t] += o;
        __syncthreads();
    }
    const int excl = cur[t] - v;
    const int n = (b << 8) + t;
    if (n < NN) rowstart[n] = base + excl;
    __syncthreads();
    cur[t] = excl;
    __syncthreads();
    for (int i = t; i < cnt; i += 256) {
        const int2 p = ebuf[base + i];
        const int loc = (p.x >> 20) & 255;
        const int pos = base + atomicAdd(&cur[loc], 1);
        csr_pair[pos] = make_int2(p.x & 0xFFFFF, p.y);
    }
}

__global__ void k_bounds(const int* __restrict__ batch, int* __restrict__ bstart) {
    int b = blockIdx.x * blockDim.x + threadIdx.x;
    if (b > NBATCH) return;
    int lo = 0, hi = NN;
    while (lo < hi) {
        int mid = (lo + hi) >> 1;
        if (batch[mid] < b) lo = mid + 1; else hi = mid;
    }
    bstart[b] = lo;
}

// ---------------- weight pack ----------------------------------------------------------------

__global__ void k_wpack(const float* __restrict__ wr1, const float* __restrict__ wo1,
                        const float* __restrict__ wr2, const float* __restrict__ wo2,
                        const float* __restrict__ wr3, const float* __restrict__ wo3,
                        ushort_t* __restrict__ w1T, ushort_t* __restrict__ w2T,
                        ushort_t* __restrict__ w3T) {
    int idx = blockIdx.x * blockDim.x + threadIdx.x;
    if (idx < 2048) {
        int n = idx >> 5, k = idx & 31;
        float v = (k < 16) ? wr1[k * 64 + n] : wo1[(k - 16) * 64 + n];
        w1T[idx] = f2b(v);
    } else if (idx < 2048 + 16384) {
        int l = idx - 2048; int n = l >> 7, k = l & 127;
        float v = (k < 64) ? wr2[k * 128 + n] : wo2[(k - 64) * 128 + n];
        w2T[l] = f2b(v);
    } else if (idx < 2048 + 16384 + 65536) {
        int l = idx - 18432; int n = l >> 8, k = l & 255;
        float v = (k < 128) ? wr3[k * 256 + n] : wo3[(k - 128) * 256 + n];
        w3T[l] = f2b(v);
    }
}

// ---------------- embedding gather -> bf16 x-half of xcat0 ----------------------------------

__global__ void k_gather_b(const int* __restrict__ xi, const float* __restrict__ emb,
                           ushort_t* __restrict__ xcat0) {
    int n = blockIdx.x * blockDim.x + threadIdx.x;
    if (n >= NN) return;
    const float* e = emb + ((size_t)xi[n] << 4);
    uint_t u[8];
#pragma unroll
    for (int j = 0; j < 8; ++j)
        u[j] = (uint_t)f2b(e[2 * j]) | ((uint_t)f2b(e[2 * j + 1]) << 16);
    uint4* o = (uint4*)(xcat0 + (size_t)n * 32 + 16);
    o[0] = {u[0], u[1], u[2], u[3]};
    o[1] = {u[4], u[5], u[6], u[7]};
}

// ---------------- aggregate (bf16 in/out) for conv1/conv2 -----------------------------------

template <int D>
__global__ void k_aggregate_b(ushort_t* __restrict__ xcat, const int2* __restrict__ csr_pair,
                              const int* __restrict__ rowstart) {
    constexpr int LPN = D / 8;
    constexpr int EP = 64 / LPN;
    const int n = blockIdx.x * 4 + (threadIdx.x >> 6);
    const int lane = threadIdx.x & 63;
    const int sl = lane % LPN;
    const int eg = lane / LPN;
    if (n >= NN) return;
    const int beg = rowstart[n], end = rowstart[n + 1];
    float a0[8] = {}, a1[8] = {};
    int i = beg + eg;
    for (; i + EP < end; i += 2 * EP) {
        const int2 p0 = csr_pair[i];
        const int2 p1 = csr_pair[i + EP];
        const float w0 = __int_as_float(p0.y);
        const float w1 = __int_as_float(p1.y);
        const uint4 u0 = *(const uint4*)(xcat + (size_t)p0.x * (2 * D) + D + sl * 8);
        const uint4 u1 = *(const uint4*)(xcat + (size_t)p1.x * (2 * D) + D + sl * 8);
        float f0[8], f1[8];
        unpack8(u0, f0); unpack8(u1, f1);
#pragma unroll
        for (int j = 0; j < 8; ++j) { a0[j] += f0[j] * w0; a1[j] += f1[j] * w1; }
    }
    if (i < end) {
        const int2 p0 = csr_pair[i];
        const float w0 = __int_as_float(p0.y);
        const uint4 u0 = *(const uint4*)(xcat + (size_t)p0.x * (2 * D) + D + sl * 8);
        float f0[8];
        unpack8(u0, f0);
#pragma unroll
        for (int j = 0; j < 8; ++j) a0[j] += f0[j] * w0;
    }
#pragma unroll
    for (int j = 0; j < 8; ++j) a0[j] += a1[j];
#pragma unroll
    for (int m = LPN; m < 64; m <<= 1)
#pragma unroll
        for (int j = 0; j < 8; ++j) a0[j] += __shfl_xor(a0[j], m);
    if (eg == 0) {
        uint_t u[4];
#pragma unroll
        for (int j = 0; j < 4; ++j)
            u[j] = (uint_t)f2b(a0[2 * j]) | ((uint_t)f2b(a0[2 * j + 1]) << 16);
        *(uint4*)(xcat + (size_t)n * (2 * D) + sl * 8) = {u[0], u[1], u[2], u[3]};
    }
}

// ---------------- aggregate for conv3: fp8 x2 reads (half bytes), bf16 agg writes ------------

__global__ void k_aggregate_f8(ushort_t* __restrict__ xcat, const uchar_t* __restrict__ x8,
                               const int2* __restrict__ csr_pair, const int* __restrict__ rowstart) {
    constexpr int D = 128;
    constexpr int LPN = 16;
    constexpr int EP = 4;
    const int n = blockIdx.x * 4 + (threadIdx.x >> 6);
    const int lane = threadIdx.x & 63;
    const int sl = lane % LPN;
    const int eg = lane / LPN;
    if (n >= NN) return;
    const int beg = rowstart[n], end = rowstart[n + 1];
    float a0[8] = {}, a1[8] = {};
    int i = beg + eg;
    for (; i + EP < end; i += 2 * EP) {
        const int2 p0 = csr_pair[i];
        const int2 p1 = csr_pair[i + EP];
        const float w0 = __int_as_float(p0.y);
        const float w1 = __int_as_float(p1.y);
        const uint2 u0 = *(const uint2*)(x8 + (size_t)p0.x * D + sl * 8);
        const uint2 u1 = *(const uint2*)(x8 + (size_t)p1.x * D + sl * 8);
        float f0[8], f1[8];
        unpack8_f8(u0, f0); unpack8_f8(u1, f1);
#pragma unroll
        for (int j = 0; j < 8; ++j) { a0[j] += f0[j] * w0; a1[j] += f1[j] * w1; }
    }
    if (i < end) {
        const int2 p0 = csr_pair[i];
        const float w0 = __int_as_float(p0.y);
        const uint2 u0 = *(const uint2*)(x8 + (size_t)p0.x * D + sl * 8);
        float f0[8];
        unpack8_f8(u0, f0);
#pragma unroll
        for (int j = 0; j < 8; ++j) a0[j] += f0[j] * w0;
    }
#pragma unroll
    for (int j = 0; j < 8; ++j) a0[j] += a1[j];
#pragma unroll
    for (int m = LPN; m < 64; m <<= 1)
#pragma unroll
        for (int j = 0; j < 8; ++j) a0[j] += __shfl_xor(a0[j], m);
    if (eg == 0) {
        uint_t u[4];
#pragma unroll
        for (int j = 0; j < 4; ++j)
            u[j] = (uint_t)f2b(a0[2 * j]) | ((uint_t)f2b(a0[2 * j + 1]) << 16);
        *(uint4*)(xcat + (size_t)n * (2 * D) + sl * 8) = {u[0], u[1], u[2], u[3]};
    }
}

// ---------------- conv GEMM via bf16 MFMA ---------------------------------------------------
// MODE 1: fp32 out + per-(batch,col) sum/sumsq stats atomics (feeds 1-pass graphnorm apply).
// MODE 2: graph-feature fusion into gfacc (x3 never materialized).

template <int K2, int DOUT, int MODE>
__global__ __launch_bounds__(256) void k_conv_mfma(
        const ushort_t* __restrict__ xcat, const ushort_t* __restrict__ wcatT,
        const float* __restrict__ brel, float* __restrict__ outp,
        const int* __restrict__ batch, const int* __restrict__ bstart,
        float* __restrict__ sacc, float* __restrict__ qacc) {
    constexpr int CW = DOUT / 64;
    const int lane = threadIdx.x & 63;
    const int wv = threadIdx.x >> 6;
    const int m = lane & 15;
    const int quad = lane >> 4;
    const int r0 = blockIdx.x * 64;

    floatx4 acc[4][CW] = {};

    const ushort_t* arow[4];
#pragma unroll
    for (int r = 0; r < 4; ++r) {
        int an = r0 + r * 16 + m; if (an >= NN) an = NN - 1;
        arow[r] = xcat + (size_t)an * K2 + quad * 8;
    }
    const ushort_t* brow[CW];
#pragma unroll
    for (int c = 0; c < CW; ++c)
        brow[c] = wcatT + (size_t)((wv * CW + c) * 16 + m) * K2 + quad * 8;

    for (int kk = 0; kk < K2; kk += 32) {
        short8 a[4], b[CW];
#pragma unroll
        for (int r = 0; r < 4; ++r) a[r] = *(const short8*)(arow[r] + kk);
#pragma unroll
        for (int c = 0; c < CW; ++c) b[c] = *(const short8*)(brow[c] + kk);
#pragma unroll
        for (int r = 0; r < 4; ++r)
#pragma unroll
            for (int c = 0; c < CW; ++c)
                acc[r][c] = __builtin_amdgcn_mfma_f32_16x16x32_bf16(a[r], b[c], acc[r][c], 0, 0, 0);
    }

    float bias[CW];
#pragma unroll
    for (int c = 0; c < CW; ++c) bias[c] = brel[(wv * CW + c) * 16 + m];

    if constexpr (MODE == 1) {
#pragma unroll
        for (int c = 0; c < CW; ++c) {
            const int col = (wv * CW + c) * 16 + m;
#pragma unroll
            for (int r = 0; r < 4; ++r)
#pragma unroll
                for (int rr = 0; rr < 4; ++rr) {
                    const int row = r0 + r * 16 + quad * 4 + rr;
                    if (row < NN)
                        outp[(size_t)row * DOUT + col] = acc[r][c][rr] + bias[c];
                }
        }
        // per-(batch,col) sum / sumsq for graphnorm
        const int rtop = (r0 + 63 < NN) ? r0 + 63 : NN - 1;
        const int sb0 = batch[r0];
        const int sb1 = batch[rtop];
        for (int sb = sb0; sb <= sb1; ++sb) {
            const int lo = (bstart[sb] > r0) ? bstart[sb] : r0;
            int hi = bstart[sb + 1];
            if (hi > r0 + 64) hi = r0 + 64;
            float s[CW], q[CW];
#pragma unroll
            for (int c = 0; c < CW; ++c) { s[c] = 0.f; q[c] = 0.f; }
#pragma unroll
            for (int r = 0; r < 4; ++r)
#pragma unroll
                for (int rr = 0; rr < 4; ++rr) {
                    const int row = r0 + r * 16 + quad * 4 + rr;
                    if (row >= lo && row < hi) {
#pragma unroll
                        for (int c = 0; c < CW; ++c) {
                            const float v = acc[r][c][rr] + bias[c];
                            s[c] += v; q[c] += v * v;
                        }
                    }
                }
#pragma unroll
            for (int c = 0; c < CW; ++c) {
                s[c] += __shfl_xor(s[c], 16); s[c] += __shfl_xor(s[c], 32);
                q[c] += __shfl_xor(q[c], 16); q[c] += __shfl_xor(q[c], 32);
            }
            if (quad == 0) {
#pragma unroll
                for (int c = 0; c < CW; ++c) {
                    const int col = (wv * CW + c) * 16 + m;
                    atomicAdd(&sacc[sb * DOUT + col], s[c]);
                    atomicAdd(&qacc[sb * DOUT + col], q[c]);
                }
            }
        }
    } else {
        const int rtop = (r0 + 63 < NN) ? r0 + 63 : NN - 1;
        const int sb0 = batch[r0];
        const int sb1 = batch[rtop];
        for (int sb = sb0; sb <= sb1; ++sb) {
            const int lo = (bstart[sb] > r0) ? bstart[sb] : r0;
            int hi = bstart[sb + 1];
            if (hi > r0 + 64) hi = r0 + 64;
            float s[CW];
#pragma unroll
            for (int c = 0; c < CW; ++c) s[c] = 0.f;
#pragma unroll
            for (int r = 0; r < 4; ++r)
#pragma unroll
                for (int rr = 0; rr < 4; ++rr) {
                    const int row = r0 + r * 16 + quad * 4 + rr;
                    if (row >= lo && row < hi) {
#pragma unroll
                        for (int c = 0; c < CW; ++c) s[c] += acc[r][c][rr] + bias[c];
                    }
                }
#pragma unroll
            for (int c = 0; c < CW; ++c) {
                s[c] += __shfl_xor(s[c], 16);
                s[c] += __shfl_xor(s[c], 32);
            }
            if (quad == 0) {
#pragma unroll
                for (int c = 0; c < CW; ++c)
                    atomicAdd(&sacc[sb * 256 + (wv * CW + c) * 16 + m], s[c]);
            }
        }
    }
}

// finalize graph features: h0[b*272 + c] = gfacc[b*256+c] / cnt[b]
__global__ void k_gffin(const float* __restrict__ gfacc, const int* __restrict__ bstart,
                        float* __restrict__ h0) {
    int idx = blockIdx.x * blockDim.x + threadIdx.x;
    if (idx >= NBATCH * 256) return;
    int b = idx >> 8, c = idx & 255;
    float cnt = fmaxf((float)(bstart[b + 1] - bstart[b]), 1.f);
    h0[b * 272 + c] = gfacc[idx] / cnt;
}

// ---------------- graph-norm apply (1 pass): stats from sacc/qacc; bf16 out (+optional fp8) --

template <int D, int OST, bool F8>
__global__ __launch_bounds__(256) void k_gnapply(
        const float* __restrict__ xf, ushort_t* __restrict__ xout, uchar_t* __restrict__ x8out,
        const int* __restrict__ bstart, const float* __restrict__ sacc,
        const float* __restrict__ qacc, const float* __restrict__ a,
        const float* __restrict__ g, const float* __restrict__ bb) {
    const int b = blockIdx.x;
    const int col0 = blockIdx.y * 64;
    const int c4 = (threadIdx.x & 15) * 4;
    const int rg = threadIdx.x >> 4;
    const int beg = bstart[b], end = bstart[b + 1];
    const float cntf = fmaxf((float)(end - beg), 1.f);

    const float4 S = *(const float4*)&sacc[b * D + col0 + c4];
    const float4 Q = *(const float4*)&qacc[b * D + col0 + c4];
    const float4 al4 = *(const float4*)&a[col0 + c4];
    const float4 g4 = *(const float4*)&g[col0 + c4];
    const float4 bb4 = *(const float4*)&bb[col0 + c4];
    float mean[4], inv[4];
    const float Sv[4] = {S.x, S.y, S.z, S.w};
    const float Qv[4] = {Q.x, Q.y, Q.z, Q.w};
    const float av[4] = {al4.x, al4.y, al4.z, al4.w};
#pragma unroll
    for (int c = 0; c < 4; ++c) {
        const float mm = Sv[c] / cntf;
        const float ex2 = Qv[c] / cntf;
        const float var = fmaxf(ex2 - mm * mm * (2.f * av[c] - av[c] * av[c]), 0.f);
        mean[c] = mm;
        inv[c] = 1.f / sqrtf(var + EPS);
    }
    for (int r = beg + rg; r < end; r += 16) {
        const float4 v = *(const float4*)&xf[(size_t)r * D + col0 + c4];
        const float y0 = lrelu(g4.x * (v.x - av[0] * mean[0]) * inv[0] + bb4.x);
        const float y1 = lrelu(g4.y * (v.y - av[1] * mean[1]) * inv[1] + bb4.y);
        const float y2 = lrelu(g4.z * (v.z - av[2] * mean[2]) * inv[2] + bb4.z);
        const float y3 = lrelu(g4.w * (v.w - av[3] * mean[3]) * inv[3] + bb4.w);
        uint2 o;
        o.x = (uint_t)f2b(y0) | ((uint_t)f2b(y1) << 16);
        o.y = (uint_t)f2b(y2) | ((uint_t)f2b(y3) << 16);
        *(uint2*)&xout[(size_t)r * OST + col0 + c4] = o;
        if constexpr (F8) {
            uint_t p = __builtin_amdgcn_cvt_pk_fp8_f32(y0, y1, 0, false);
            p = __builtin_amdgcn_cvt_pk_fp8_f32(y2, y3, p, true);
            *(uint_t*)&x8out[(size_t)r * D + col0 + c4] = p;
        }
    }
}

__global__ void k_demo(const float* __restrict__ dg, const float* __restrict__ w,
                       const float* __restrict__ b, float* __restrict__ h0) {
    int idx = blockIdx.x * blockDim.x + threadIdx.x;
    if (idx < NBATCH * 16) {
        int i = idx >> 4, j = idx & 15;
        float acc = b[j];
        for (int k = 0; k < 4; ++k) acc += dg[i * 4 + k] * w[k * 16 + j];
        h0[i * 272 + 256 + j] = acc;
    }
}

// ---------------- head ----------------------------------------------------------------------

template <int K, int C>
__global__ __launch_bounds__(C) void k_head_lin(const float* __restrict__ in,
                                                const float* __restrict__ w,
                                                const float* __restrict__ bias,
                                                float* __restrict__ z, int rows) {
    __shared__ float s_in[16][K];
    const int j = threadIdx.x;
    const int r0 = blockIdx.x * 16;
    for (int idx = threadIdx.x; idx < 16 * K; idx += C) {
        int r = idx / K, k = idx - r * K;
        s_in[r][k] = (r0 + r < rows) ? in[(size_t)(r0 + r) * K + k] : 0.f;
    }
    __syncthreads();
    float acc[16];
#pragma unroll
    for (int r = 0; r < 16; ++r) acc[r] = 0.f;
    for (int k = 0; k < K; ++k) {
        const float wv = w[k * C + j];
#pragma unroll
        for (int r = 0; r < 16; ++r) acc[r] += s_in[r][k] * wv;
    }
    const float bj = bias[j];
#pragma unroll
    for (int r = 0; r < 16; ++r)
        if (r0 + r < rows) z[(size_t)(r0 + r) * C + j] = acc[r] + bj;
}

__global__ void k_head_bn(float* __restrict__ z, const float* __restrict__ g,
                          const float* __restrict__ b, int rows, int C) {
    const int j = threadIdx.x;
    if (j >= C) return;
    float s = 0.f, q = 0.f;
    for (int i = 0; i < rows; ++i) { const float v = z[i * C + j]; s += v; q += v * v; }
    const float m = s / rows;
    const float var = fmaxf(q / rows - m * m, 0.f);
    const float inv = 1.f / sqrtf(var + EPS);
    const float gg = g[j], bb = b[j];
    for (int i = 0; i < rows; ++i)
        z[i * C + j] = lrelu(gg * (z[i * C + j] - m) * inv + bb);
}

__global__ __launch_bounds__(256) void k_head_out(const float* __restrict__ h2,
                                                  const float* __restrict__ w,
                                                  const float* __restrict__ b,
                                                  float* __restrict__ out) {
    __shared__ float s[NBATCH * 65];
    for (int idx = threadIdx.x; idx < NBATCH * 64; idx += 256) {
        int i = idx >> 6, k = idx & 63;
        s[i * 65 + k] = h2[idx];
    }
    __syncthreads();
    const int i = threadIdx.x;
    if (i < NBATCH) {
        float a0 = b[0], a1 = b[1], a2 = b[2];
        for (int k = 0; k < 64; ++k) {
            const float v = s[i * 65 + k];
            a0 += v * w[k * 3 + 0];
            a1 += v * w[k * 3 + 1];
            a2 += v * w[k * 3 + 2];
        }
        out[i * 3 + 0] = a0; out[i * 3 + 1] = a1; out[i * 3 + 2] = a2;
    }
}

// ---------------- launcher ----------------

extern "C" void kernel_launch(void* const* d_in, const int* in_sizes, int n_in,
                              void* d_out, int out_size, void* d_ws, size_t ws_size,
                              hipStream_t stream) {
    const int*   x_idx  = (const int*)d_in[0];
    const int*   ei     = (const int*)d_in[1];
    const float* eattr  = (const float*)d_in[2];
    const int*   batch  = (const int*)d_in[3];
    const float* demog  = (const float*)d_in[4];
    const float* emb    = (const float*)d_in[5];
    const float* wrel1  = (const float*)d_in[6];
    const float* brel1  = (const float*)d_in[7];
    const float* wroot1 = (const float*)d_in[8];
    const float* wrel2  = (const float*)d_in[9];
    const float* brel2  = (const float*)d_in[10];
    const float* wroot2 = (const float*)d_in[11];
    const float* wrel3  = (const float*)d_in[12];
    const float* brel3  = (const float*)d_in[13];
    const float* wroot3 = (const float*)d_in[14];
    const float* gn1g = (const float*)d_in[15];
    const float* gn1b = (const float*)d_in[16];
    const float* gn1a = (const float*)d_in[17];
    const float* gn2g = (const float*)d_in[18];
    const float* gn2b = (const float*)d_in[19];
    const float* gn2a = (const float*)d_in[20];
    const float* dw   = (const float*)d_in[21];
    const float* db   = (const float*)d_in[22];
    const float* l1w  = (const float*)d_in[23];
    const float* l1b  = (const float*)d_in[24];
    const float* bn1g = (const float*)d_in[25];
    const float* bn1b = (const float*)d_in[26];
    const float* l2w  = (const float*)d_in[27];
    const float* l2b  = (const float*)d_in[28];
    const float* bn2g = (const float*)d_in[29];
    const float* bn2b = (const float*)d_in[30];
    const float* l3w  = (const float*)d_in[31];
    const float* l3b  = (const float*)d_in[32];
    float* out = (float*)d_out;

    float*    W     = (float*)d_ws;
    float*    xf    = W;                                   // fp32 conv out, 12.8M floats
    int2*     ebuf  = (int2*)W;                            // NE int2 (CSR build only)
    float*    gfacc = W + 12800000;                        // NBATCH*256 fp32
    ushort_t* xcat0 = (ushort_t*)(W + 25600000);           // NN*32 bf16  [agg0|x0]
    ushort_t* xcat1 = (ushort_t*)(W + 27200000);           // NN*128 bf16 [agg1|x1]
    ushort_t* xcat2 = (ushort_t*)(W + 33600000);           // NN*256 bf16 [agg2|x2]
    ushort_t* w1T   = (ushort_t*)(W + 46400000);           // 2048
    ushort_t* w2T   = w1T + 2048;                          // 16384
    ushort_t* w3T   = w2T + 16384;                         // 65536
    int2*     csr_pair = (int2*)(W + 46450000);            // NE int2
    int*      rowstart = (int*)(W + 49650000);             // NN+1
    int*      bstart   = (int*)(W + 49760000);             // NBATCH+1
    int*      bcnt     = (int*)(W + 49761000);             // NBUCK
    int*      bbase    = (int*)(W + 49762000);             // NBUCK+1
    int*      bcur     = (int*)(W + 49763000);             // NBUCK
    float*    h0 = W + 49770000;                           // 100*272
    float*    h1 = h0 + 27200;
    float*    h2 = h1 + 12800;
    float*    sacc1 = W + 49817000;                        // 100*64
    float*    qacc1 = sacc1 + 6400;
    float*    sacc2 = W + 49830000;                        // 100*128
    float*    qacc2 = sacc2 + 12800;
    uchar_t*  x8    = (uchar_t*)(W + 49860000);            // NN*128 fp8 e4m3 (x2 copy)

    const int* src = ei;
    const int* dst = ei + NE;

    const int mfma_blk = (NN + 63) / 64;     // 1563 (64 rows/block)
    const int nagg_blk = (NN + 3) / 4;       // 1 node/wave, 4 waves/block

    // ---- bucketed CSR build (by dst) ----
    hipMemsetAsync(bcnt, 0, NBUCK * sizeof(int), stream);
    k_bcount<<<256, 256, 0, stream>>>(dst, bcnt);
    k_bscan<<<1, 512, 0, stream>>>(bcnt, bbase, bcur, rowstart);
    k_bscatter<<<256, 256, 0, stream>>>(dst, src, eattr, bcur, ebuf);
    k_bfinal<<<NBUCK, 256, 0, stream>>>(ebuf, bbase, rowstart, csr_pair);

    k_bounds<<<1, 128, 0, stream>>>(batch, bstart);
    k_wpack<<<(83968 + 255) / 256, 256, 0, stream>>>(wrel1, wroot1, wrel2, wroot2, wrel3, wroot3,
                                                     w1T, w2T, w3T);
    hipMemsetAsync(gfacc, 0, NBATCH * 256 * sizeof(float), stream);
    hipMemsetAsync(sacc1, 0, (6400 * 2) * sizeof(float), stream);
    hipMemsetAsync(sacc2, 0, (12800 * 2) * sizeof(float), stream);

    // x0 (bf16) into xcat0 x-half
    k_gather_b<<<(NN + 255) / 256, 256, 0, stream>>>(x_idx, emb, xcat0);

    // conv1: [agg0|x0](K2=32) @ w1T -> xf (fp32 NN x 64) + graphnorm stats
    k_aggregate_b<16><<<nagg_blk, 256, 0, stream>>>(xcat0, csr_pair, rowstart);
    k_conv_mfma<32, 64, 1><<<mfma_blk, 256, 0, stream>>>(xcat0, w1T, brel1, xf, batch, bstart, sacc1, qacc1);
    k_gnapply<64, 128, false><<<dim3(NBATCH, 1), 256, 0, stream>>>(xf, xcat1 + 64, nullptr,
                                                                   bstart, sacc1, qacc1, gn1a, gn1g, gn1b);

    // conv2: [agg1|x1](K2=128) @ w2T -> xf (fp32 NN x 128) + stats; apply writes bf16 + fp8 copy
    k_aggregate_b<64><<<nagg_blk, 256, 0, stream>>>(xcat1, csr_pair, rowstart);
    k_conv_mfma<128, 128, 1><<<mfma_blk, 256, 0, stream>>>(xcat1, w2T, brel2, xf, batch, bstart, sacc2, qacc2);
    k_gnapply<128, 256, true><<<dim3(NBATCH, 2), 256, 0, stream>>>(xf, xcat2 + 128, x8,
                                                                   bstart, sacc2, qacc2, gn2a, gn2g, gn2b);

    // conv3: [agg2|x2](K2=256) @ w3T -> gfacc directly (x3 never materialized)
    k_aggregate_f8<<<nagg_blk, 256, 0, stream>>>(xcat2, x8, csr_pair, rowstart);
    k_conv_mfma<256, 256, 2><<<mfma_blk, 256, 0, stream>>>(xcat2, w3T, brel3, nullptr, batch, bstart, gfacc, nullptr);

    // head
    k_gffin<<<(NBATCH * 256 + 255) / 256, 256, 0, stream>>>(gfacc, bstart, h0);
    k_demo<<<(NBATCH * 16 + 255) / 256, 256, 0, stream>>>(demog, dw, db, h0);
    k_head_lin<272, 128><<<(NBATCH + 15) / 16, 128, 0, stream>>>(h0, l1w, l1b, h1, NBATCH);
    k_head_bn<<<1, 128, 0, stream>>>(h1, bn1g, bn1b, NBATCH, 128);
    k_head_lin<128, 64><<<(NBATCH + 15) / 16, 64, 0, stream>>>(h1, l2w, l2b, h2, NBATCH);
    k_head_bn<<<1, 64, 0, stream>>>(h2, bn2g, bn2b, NBATCH, 64);
    k_head_out<<<1, 256, 0, stream>>>(h2, l3w, l3b, out);
}

// Round 17
// 624.484 us; speedup vs baseline: 3.2476x; 1.0412x over previous
//
#include <hip/hip_runtime.h>

// Problem constants (from reference)
#define NN 100000      // nodes
#define NE 1600000     // edges
#define NBATCH 100     // graphs
#define NBUCK 391      // ceil(NN / 256) coarse buckets for CSR build
constexpr float EPS = 1e-5f;

typedef unsigned short ushort_t;
typedef unsigned int uint_t;
typedef unsigned char uchar_t;

using short8 = __attribute__((ext_vector_type(8))) short;   // 8 bf16 (4 VGPRs)
using floatx4 = __attribute__((ext_vector_type(4))) float;  // 4 fp32 acc
using floatx2 = __attribute__((ext_vector_type(2))) float;

__device__ __forceinline__ float lrelu(float x) { return x > 0.f ? x : 0.01f * x; }

__device__ __forceinline__ float b2f(ushort_t u) {
    union { uint_t i; float f; } c; c.i = ((uint_t)u) << 16; return c.f;
}
__device__ __forceinline__ ushort_t f2b(float f) {
    union { float f; uint_t i; } c; c.f = f;
    uint_t u = c.i;
    return (ushort_t)((u + 0x7FFFu + ((u >> 16) & 1u)) >> 16);   // RNE
}
__device__ __forceinline__ void unpack8(const uint4 u, float* f) {
    f[0] = b2f(u.x & 0xffff); f[1] = b2f(u.x >> 16);
    f[2] = b2f(u.y & 0xffff); f[3] = b2f(u.y >> 16);
    f[4] = b2f(u.z & 0xffff); f[5] = b2f(u.z >> 16);
    f[6] = b2f(u.w & 0xffff); f[7] = b2f(u.w >> 16);
}
__device__ __forceinline__ void unpack8_f8(const uint2 u, float* f) {
    floatx2 a = __builtin_amdgcn_cvt_pk_f32_fp8(u.x, false);
    floatx2 b = __builtin_amdgcn_cvt_pk_f32_fp8(u.x, true);
    floatx2 c = __builtin_amdgcn_cvt_pk_f32_fp8(u.y, false);
    floatx2 d = __builtin_amdgcn_cvt_pk_f32_fp8(u.y, true);
    f[0] = a[0]; f[1] = a[1]; f[2] = b[0]; f[3] = b[1];
    f[4] = c[0]; f[5] = c[1]; f[6] = d[0]; f[7] = d[1];
}

// ---------------- bucketed CSR build ----------------

__global__ __launch_bounds__(256) void k_bcount(const int* __restrict__ dst,
                                                int* __restrict__ bcnt) {
    __shared__ int h[NBUCK];
    for (int i = threadIdx.x; i < NBUCK; i += 256) h[i] = 0;
    __syncthreads();
    for (int e = blockIdx.x * 256 + threadIdx.x; e < NE; e += gridDim.x * 256)
        atomicAdd(&h[dst[e] >> 8], 1);
    __syncthreads();
    for (int i = threadIdx.x; i < NBUCK; i += 256)
        if (h[i]) atomicAdd(&bcnt[i], h[i]);
}

__global__ __launch_bounds__(512) void k_bscan(const int* __restrict__ bcnt,
                                               int* __restrict__ bbase,
                                               int* __restrict__ bcur,
                                               int* __restrict__ rowstart) {
    __shared__ int s[512];
    const int t = threadIdx.x;
    const int v = (t < NBUCK) ? bcnt[t] : 0;
    s[t] = v;
    __syncthreads();
    for (int off = 1; off < 512; off <<= 1) {
        int o = (t >= off) ? s[t - off] : 0;
        __syncthreads();
        s[t] += o;
        __syncthreads();
    }
    const int excl = s[t] - v;
    if (t < NBUCK) { bbase[t] = excl; bcur[t] = excl; }
    if (t == 0) { bbase[NBUCK] = NE; rowstart[NN] = NE; }
}

__global__ __launch_bounds__(256) void k_bscatter(const int* __restrict__ dst,
                                                  const int* __restrict__ srcv,
                                                  const float* __restrict__ ew,
                                                  int* __restrict__ bcur,
                                                  int2* __restrict__ ebuf) {
    __shared__ int h[NBUCK];
    __shared__ int lcur[NBUCK];
    const int chunk = (NE + gridDim.x - 1) / gridDim.x;
    const int beg = blockIdx.x * chunk;
    const int end = (beg + chunk < NE) ? beg + chunk : NE;
    for (int i = threadIdx.x; i < NBUCK; i += 256) h[i] = 0;
    __syncthreads();
    for (int e = beg + threadIdx.x; e < end; e += 256)
        atomicAdd(&h[dst[e] >> 8], 1);
    __syncthreads();
    for (int i = threadIdx.x; i < NBUCK; i += 256)
        lcur[i] = h[i] ? atomicAdd(&bcur[i], h[i]) : 0;
    __syncthreads();
    for (int e = beg + threadIdx.x; e < end; e += 256) {
        const int d = dst[e];
        const int pos = atomicAdd(&lcur[d >> 8], 1);
        ebuf[pos] = make_int2(srcv[e] | ((d & 255) << 20), __float_as_int(ew[e]));
    }
}

__global__ __launch_bounds__(256) void k_bfinal(const int2* __restrict__ ebuf,
                                                const int* __restrict__ bbase,
                                                int* __restrict__ rowstart,
                                                int2* __restrict__ csr_pair) {
    __shared__ int h[256];
    __shared__ int cur[256];
    const int b = blockIdx.x;
    const int t = threadIdx.x;
    const int base = bbase[b];
    const int cnt = bbase[b + 1] - base;
    h[t] = 0;
    __syncthreads();
    for (int i = t; i < cnt; i += 256)
        atomicAdd(&h[(ebuf[base + i].x >> 20) & 255], 1);
    __syncthreads();
    const int v = h[t];
    cur[t] = v;
    __syncthreads();
    for (int off = 1; off < 256; off <<= 1) {
        int o = (t >= off) ? cur[t - off] : 0;
        __syncthreads();
        cur[t] += o;
        __syncthreads();
    }
    const int excl = cur[t] - v;
    const int n = (b << 8) + t;
    if (n < NN) rowstart[n] = base + excl;
    __syncthreads();
    cur[t] = excl;
    __syncthreads();
    for (int i = t; i < cnt; i += 256) {
        const int2 p = ebuf[base + i];
        const int loc = (p.x >> 20) & 255;
        const int pos = base + atomicAdd(&cur[loc], 1);
        csr_pair[pos] = make_int2(p.x & 0xFFFFF, p.y);
    }
}

__global__ void k_bounds(const int* __restrict__ batch, int* __restrict__ bstart) {
    int b = blockIdx.x * blockDim.x + threadIdx.x;
    if (b > NBATCH) return;
    int lo = 0, hi = NN;
    while (lo < hi) {
        int mid = (lo + hi) >> 1;
        if (batch[mid] < b) lo = mid + 1; else hi = mid;
    }
    bstart[b] = lo;
}

// ---------------- weight pack: fragment-major (per-wave-load 64x16B contiguous) --------------
// fragment (ct, kb): element for lane=(m + 16*quad), j in [0,8):
//   wf[((ct*(K2/32)+kb)*64 + lane)*8 + j] = W[k = kb*32 + quad*8 + j][col = ct*16 + m]

template <int K, int K2, int DOUT>
__global__ void k_wpackf(const float* __restrict__ wrel, const float* __restrict__ wroot,
                         ushort_t* __restrict__ wf) {
    int idx = blockIdx.x * 256 + threadIdx.x;
    if (idx >= DOUT * K2) return;
    const int col = idx / K2, k = idx - col * K2;
    const float v = (k < K) ? wrel[k * DOUT + col] : wroot[(k - K) * DOUT + col];
    const int ct = col >> 4, m = col & 15;
    const int kb = k >> 5, q = (k >> 3) & 3, j = k & 7;
    const int lane = m + (q << 4);
    wf[(((size_t)(ct * (K2 / 32) + kb) * 64 + lane) << 3) + j] = f2b(v);
}

// ---------------- embedding gather -> bf16 x-half of xcat0 ----------------------------------

__global__ void k_gather_b(const int* __restrict__ xi, const float* __restrict__ emb,
                           ushort_t* __restrict__ xcat0) {
    int n = blockIdx.x * blockDim.x + threadIdx.x;
    if (n >= NN) return;
    const float* e = emb + ((size_t)xi[n] << 4);
    uint_t u[8];
#pragma unroll
    for (int j = 0; j < 8; ++j)
        u[j] = (uint_t)f2b(e[2 * j]) | ((uint_t)f2b(e[2 * j + 1]) << 16);
    uint4* o = (uint4*)(xcat0 + (size_t)n * 32 + 16);
    o[0] = {u[0], u[1], u[2], u[3]};
    o[1] = {u[4], u[5], u[6], u[7]};
}

// ---------------- aggregate (bf16 in/out) for conv1/conv2 -----------------------------------

template <int D>
__global__ void k_aggregate_b(ushort_t* __restrict__ xcat, const int2* __restrict__ csr_pair,
                              const int* __restrict__ rowstart) {
    constexpr int LPN = D / 8;
    constexpr int EP = 64 / LPN;
    const int n = blockIdx.x * 4 + (threadIdx.x >> 6);
    const int lane = threadIdx.x & 63;
    const int sl = lane % LPN;
    const int eg = lane / LPN;
    if (n >= NN) return;
    const int beg = rowstart[n], end = rowstart[n + 1];
    float a0[8] = {}, a1[8] = {};
    int i = beg + eg;
    for (; i + EP < end; i += 2 * EP) {
        const int2 p0 = csr_pair[i];
        const int2 p1 = csr_pair[i + EP];
        const float w0 = __int_as_float(p0.y);
        const float w1 = __int_as_float(p1.y);
        const uint4 u0 = *(const uint4*)(xcat + (size_t)p0.x * (2 * D) + D + sl * 8);
        const uint4 u1 = *(const uint4*)(xcat + (size_t)p1.x * (2 * D) + D + sl * 8);
        float f0[8], f1[8];
        unpack8(u0, f0); unpack8(u1, f1);
#pragma unroll
        for (int j = 0; j < 8; ++j) { a0[j] += f0[j] * w0; a1[j] += f1[j] * w1; }
    }
    if (i < end) {
        const int2 p0 = csr_pair[i];
        const float w0 = __int_as_float(p0.y);
        const uint4 u0 = *(const uint4*)(xcat + (size_t)p0.x * (2 * D) + D + sl * 8);
        float f0[8];
        unpack8(u0, f0);
#pragma unroll
        for (int j = 0; j < 8; ++j) a0[j] += f0[j] * w0;
    }
#pragma unroll
    for (int j = 0; j < 8; ++j) a0[j] += a1[j];
#pragma unroll
    for (int m = LPN; m < 64; m <<= 1)
#pragma unroll
        for (int j = 0; j < 8; ++j) a0[j] += __shfl_xor(a0[j], m);
    if (eg == 0) {
        uint_t u[4];
#pragma unroll
        for (int j = 0; j < 4; ++j)
            u[j] = (uint_t)f2b(a0[2 * j]) | ((uint_t)f2b(a0[2 * j + 1]) << 16);
        *(uint4*)(xcat + (size_t)n * (2 * D) + sl * 8) = {u[0], u[1], u[2], u[3]};
    }
}

// ---------------- aggregate for conv3: fp8 x2 reads, bf16 agg writes ------------------------

__global__ void k_aggregate_f8(ushort_t* __restrict__ xcat, const uchar_t* __restrict__ x8,
                               const int2* __restrict__ csr_pair, const int* __restrict__ rowstart) {
    constexpr int D = 128;
    constexpr int LPN = 16;
    constexpr int EP = 4;
    const int n = blockIdx.x * 4 + (threadIdx.x >> 6);
    const int lane = threadIdx.x & 63;
    const int sl = lane % LPN;
    const int eg = lane / LPN;
    if (n >= NN) return;
    const int beg = rowstart[n], end = rowstart[n + 1];
    float a0[8] = {}, a1[8] = {};
    int i = beg + eg;
    for (; i + EP < end; i += 2 * EP) {
        const int2 p0 = csr_pair[i];
        const int2 p1 = csr_pair[i + EP];
        const float w0 = __int_as_float(p0.y);
        const float w1 = __int_as_float(p1.y);
        const uint2 u0 = *(const uint2*)(x8 + (size_t)p0.x * D + sl * 8);
        const uint2 u1 = *(const uint2*)(x8 + (size_t)p1.x * D + sl * 8);
        float f0[8], f1[8];
        unpack8_f8(u0, f0); unpack8_f8(u1, f1);
#pragma unroll
        for (int j = 0; j < 8; ++j) { a0[j] += f0[j] * w0; a1[j] += f1[j] * w1; }
    }
    if (i < end) {
        const int2 p0 = csr_pair[i];
        const float w0 = __int_as_float(p0.y);
        const uint2 u0 = *(const uint2*)(x8 + (size_t)p0.x * D + sl * 8);
        float f0[8];
        unpack8_f8(u0, f0);
#pragma unroll
        for (int j = 0; j < 8; ++j) a0[j] += f0[j] * w0;
    }
#pragma unroll
    for (int j = 0; j < 8; ++j) a0[j] += a1[j];
#pragma unroll
    for (int m = LPN; m < 64; m <<= 1)
#pragma unroll
        for (int j = 0; j < 8; ++j) a0[j] += __shfl_xor(a0[j], m);
    if (eg == 0) {
        uint_t u[4];
#pragma unroll
        for (int j = 0; j < 4; ++j)
            u[j] = (uint_t)f2b(a0[2 * j]) | ((uint_t)f2b(a0[2 * j + 1]) << 16);
        *(uint4*)(xcat + (size_t)n * (2 * D) + sl * 8) = {u[0], u[1], u[2], u[3]};
    }
}

// ---------------- conv GEMM via bf16 MFMA (fragment-major B) --------------------------------
// MODE 1: fp32 out + per-(batch,col) sum/sumsq stats. MODE 2: gf fusion (split-K via blockIdx.y;
// bias applied only by split 0).

template <int K2, int DOUT, int MODE, int NSPLIT>
__global__ __launch_bounds__(256) void k_conv_mfma(
        const ushort_t* __restrict__ xcat, const ushort_t* __restrict__ wfrag,
        const float* __restrict__ brel, float* __restrict__ outp,
        const int* __restrict__ batch, const int* __restrict__ bstart,
        float* __restrict__ sacc, float* __restrict__ qacc) {
    constexpr int CW = DOUT / 64;
    constexpr int KBTOT = K2 / 32;
    constexpr int KSTEPS = KBTOT / NSPLIT;
    const int lane = threadIdx.x & 63;
    const int wv = threadIdx.x >> 6;
    const int m = lane & 15;
    const int quad = lane >> 4;
    const int r0 = blockIdx.x * 64;
    const int kb0 = blockIdx.y * KSTEPS;

    floatx4 acc[4][CW] = {};

    const ushort_t* arow[4];
#pragma unroll
    for (int r = 0; r < 4; ++r) {
        int an = r0 + r * 16 + m; if (an >= NN) an = NN - 1;
        arow[r] = xcat + (size_t)an * K2 + quad * 8 + kb0 * 32;
    }
    const ushort_t* bfr[CW];
#pragma unroll
    for (int c = 0; c < CW; ++c)
        bfr[c] = wfrag + (((size_t)((wv * CW + c) * KBTOT + kb0) * 64 + lane) << 3);

#pragma unroll
    for (int s = 0; s < KSTEPS; ++s) {
        short8 a[4], b[CW];
#pragma unroll
        for (int r = 0; r < 4; ++r) a[r] = *(const short8*)(arow[r] + s * 32);
#pragma unroll
        for (int c = 0; c < CW; ++c) b[c] = *(const short8*)(bfr[c] + (size_t)s * 512);
#pragma unroll
        for (int r = 0; r < 4; ++r)
#pragma unroll
            for (int c = 0; c < CW; ++c)
                acc[r][c] = __builtin_amdgcn_mfma_f32_16x16x32_bf16(a[r], b[c], acc[r][c], 0, 0, 0);
    }

    float bias[CW];
#pragma unroll
    for (int c = 0; c < CW; ++c)
        bias[c] = (NSPLIT == 1 || blockIdx.y == 0) ? brel[(wv * CW + c) * 16 + m] : 0.f;

    if constexpr (MODE == 1) {
#pragma unroll
        for (int c = 0; c < CW; ++c) {
            const int col = (wv * CW + c) * 16 + m;
#pragma unroll
            for (int r = 0; r < 4; ++r)
#pragma unroll
                for (int rr = 0; rr < 4; ++rr) {
                    const int row = r0 + r * 16 + quad * 4 + rr;
                    if (row < NN)
                        outp[(size_t)row * DOUT + col] = acc[r][c][rr] + bias[c];
                }
        }
        const int rtop = (r0 + 63 < NN) ? r0 + 63 : NN - 1;
        const int sb0 = batch[r0];
        const int sb1 = batch[rtop];
        for (int sb = sb0; sb <= sb1; ++sb) {
            const int lo = (bstart[sb] > r0) ? bstart[sb] : r0;
            int hi = bstart[sb + 1];
            if (hi > r0 + 64) hi = r0 + 64;
            float s[CW], q[CW];
#pragma unroll
            for (int c = 0; c < CW; ++c) { s[c] = 0.f; q[c] = 0.f; }
#pragma unroll
            for (int r = 0; r < 4; ++r)
#pragma unroll
                for (int rr = 0; rr < 4; ++rr) {
                    const int row = r0 + r * 16 + quad * 4 + rr;
                    if (row >= lo && row < hi) {
#pragma unroll
                        for (int c = 0; c < CW; ++c) {
                            const float v = acc[r][c][rr] + bias[c];
                            s[c] += v; q[c] += v * v;
                        }
                    }
                }
#pragma unroll
            for (int c = 0; c < CW; ++c) {
                s[c] += __shfl_xor(s[c], 16); s[c] += __shfl_xor(s[c], 32);
                q[c] += __shfl_xor(q[c], 16); q[c] += __shfl_xor(q[c], 32);
            }
            if (quad == 0) {
#pragma unroll
                for (int c = 0; c < CW; ++c) {
                    const int col = (wv * CW + c) * 16 + m;
                    atomicAdd(&sacc[sb * DOUT + col], s[c]);
                    atomicAdd(&qacc[sb * DOUT + col], q[c]);
                }
            }
        }
    } else {
        const int rtop = (r0 + 63 < NN) ? r0 + 63 : NN - 1;
        const int sb0 = batch[r0];
        const int sb1 = batch[rtop];
        for (int sb = sb0; sb <= sb1; ++sb) {
            const int lo = (bstart[sb] > r0) ? bstart[sb] : r0;
            int hi = bstart[sb + 1];
            if (hi > r0 + 64) hi = r0 + 64;
            float s[CW];
#pragma unroll
            for (int c = 0; c < CW; ++c) s[c] = 0.f;
#pragma unroll
            for (int r = 0; r < 4; ++r)
#pragma unroll
                for (int rr = 0; rr < 4; ++rr) {
                    const int row = r0 + r * 16 + quad * 4 + rr;
                    if (row >= lo && row < hi) {
#pragma unroll
                        for (int c = 0; c < CW; ++c) s[c] += acc[r][c][rr] + bias[c];
                    }
                }
#pragma unroll
            for (int c = 0; c < CW; ++c) {
                s[c] += __shfl_xor(s[c], 16);
                s[c] += __shfl_xor(s[c], 32);
            }
            if (quad == 0) {
#pragma unroll
                for (int c = 0; c < CW; ++c)
                    atomicAdd(&sacc[sb * 256 + (wv * CW + c) * 16 + m], s[c]);
            }
        }
    }
}

// finalize graph features
__global__ void k_gffin(const float* __restrict__ gfacc, const int* __restrict__ bstart,
                        float* __restrict__ h0) {
    int idx = blockIdx.x * blockDim.x + threadIdx.x;
    if (idx >= NBATCH * 256) return;
    int b = idx >> 8, c = idx & 255;
    float cnt = fmaxf((float)(bstart[b + 1] - bstart[b]), 1.f);
    h0[b * 272 + c] = gfacc[idx] / cnt;
}

// ---------------- graph-norm apply (1 pass) --------------------------------------------------

template <int D, int OST, bool F8>
__global__ __launch_bounds__(256) void k_gnapply(
        const float* __restrict__ xf, ushort_t* __restrict__ xout, uchar_t* __restrict__ x8out,
        const int* __restrict__ bstart, const float* __restrict__ sacc,
        const float* __restrict__ qacc, const float* __restrict__ a,
        const float* __restrict__ g, const float* __restrict__ bb) {
    const int b = blockIdx.x;
    const int col0 = blockIdx.y * 64;
    const int c4 = (threadIdx.x & 15) * 4;
    const int rg = threadIdx.x >> 4;
    const int beg = bstart[b], end = bstart[b + 1];
    const float cntf = fmaxf((float)(end - beg), 1.f);

    const float4 S = *(const float4*)&sacc[b * D + col0 + c4];
    const float4 Q = *(const float4*)&qacc[b * D + col0 + c4];
    const float4 al4 = *(const float4*)&a[col0 + c4];
    const float4 g4 = *(const float4*)&g[col0 + c4];
    const float4 bb4 = *(const float4*)&bb[col0 + c4];
    float mean[4], inv[4];
    const float Sv[4] = {S.x, S.y, S.z, S.w};
    const float Qv[4] = {Q.x, Q.y, Q.z, Q.w};
    const float av[4] = {al4.x, al4.y, al4.z, al4.w};
#pragma unroll
    for (int c = 0; c < 4; ++c) {
        const float mm = Sv[c] / cntf;
        const float ex2 = Qv[c] / cntf;
        const float var = fmaxf(ex2 - mm * mm * (2.f * av[c] - av[c] * av[c]), 0.f);
        mean[c] = mm;
        inv[c] = 1.f / sqrtf(var + EPS);
    }
    for (int r = beg + rg; r < end; r += 16) {
        const float4 v = *(const float4*)&xf[(size_t)r * D + col0 + c4];
        const float y0 = lrelu(g4.x * (v.x - av[0] * mean[0]) * inv[0] + bb4.x);
        const float y1 = lrelu(g4.y * (v.y - av[1] * mean[1]) * inv[1] + bb4.y);
        const float y2 = lrelu(g4.z * (v.z - av[2] * mean[2]) * inv[2] + bb4.z);
        const float y3 = lrelu(g4.w * (v.w - av[3] * mean[3]) * inv[3] + bb4.w);
        uint2 o;
        o.x = (uint_t)f2b(y0) | ((uint_t)f2b(y1) << 16);
        o.y = (uint_t)f2b(y2) | ((uint_t)f2b(y3) << 16);
        *(uint2*)&xout[(size_t)r * OST + col0 + c4] = o;
        if constexpr (F8) {
            uint_t p = __builtin_amdgcn_cvt_pk_fp8_f32(y0, y1, 0, false);
            p = __builtin_amdgcn_cvt_pk_fp8_f32(y2, y3, p, true);
            *(uint_t*)&x8out[(size_t)r * D + col0 + c4] = p;
        }
    }
}

__global__ void k_demo(const float* __restrict__ dg, const float* __restrict__ w,
                       const float* __restrict__ b, float* __restrict__ h0) {
    int idx = blockIdx.x * blockDim.x + threadIdx.x;
    if (idx < NBATCH * 16) {
        int i = idx >> 4, j = idx & 15;
        float acc = b[j];
        for (int k = 0; k < 4; ++k) acc += dg[i * 4 + k] * w[k * 16 + j];
        h0[i * 272 + 256 + j] = acc;
    }
}

// ---------------- head ----------------------------------------------------------------------

template <int K, int C>
__global__ __launch_bounds__(C) void k_head_lin(const float* __restrict__ in,
                                                const float* __restrict__ w,
                                                const float* __restrict__ bias,
                                                float* __restrict__ z, int rows) {
    __shared__ float s_in[16][K];
    const int j = threadIdx.x;
    const int r0 = blockIdx.x * 16;
    for (int idx = threadIdx.x; idx < 16 * K; idx += C) {
        int r = idx / K, k = idx - r * K;
        s_in[r][k] = (r0 + r < rows) ? in[(size_t)(r0 + r) * K + k] : 0.f;
    }
    __syncthreads();
    float acc[16];
#pragma unroll
    for (int r = 0; r < 16; ++r) acc[r] = 0.f;
    for (int k = 0; k < K; ++k) {
        const float wv = w[k * C + j];
#pragma unroll
        for (int r = 0; r < 16; ++r) acc[r] += s_in[r][k] * wv;
    }
    const float bj = bias[j];
#pragma unroll
    for (int r = 0; r < 16; ++r)
        if (r0 + r < rows) z[(size_t)(r0 + r) * C + j] = acc[r] + bj;
}

__global__ void k_head_bn(float* __restrict__ z, const float* __restrict__ g,
                          const float* __restrict__ b, int rows, int C) {
    const int j = threadIdx.x;
    if (j >= C) return;
    float s = 0.f, q = 0.f;
    for (int i = 0; i < rows; ++i) { const float v = z[i * C + j]; s += v; q += v * v; }
    const float m = s / rows;
    const float var = fmaxf(q / rows - m * m, 0.f);
    const float inv = 1.f / sqrtf(var + EPS);
    const float gg = g[j], bb = b[j];
    for (int i = 0; i < rows; ++i)
        z[i * C + j] = lrelu(gg * (z[i * C + j] - m) * inv + bb);
}

__global__ __launch_bounds__(256) void k_head_out(const float* __restrict__ h2,
                                                  const float* __restrict__ w,
                                                  const float* __restrict__ b,
                                                  float* __restrict__ out) {
    __shared__ float s[NBATCH * 65];
    for (int idx = threadIdx.x; idx < NBATCH * 64; idx += 256) {
        int i = idx >> 6, k = idx & 63;
        s[i * 65 + k] = h2[idx];
    }
    __syncthreads();
    const int i = threadIdx.x;
    if (i < NBATCH) {
        float a0 = b[0], a1 = b[1], a2 = b[2];
        for (int k = 0; k < 64; ++k) {
            const float v = s[i * 65 + k];
            a0 += v * w[k * 3 + 0];
            a1 += v * w[k * 3 + 1];
            a2 += v * w[k * 3 + 2];
        }
        out[i * 3 + 0] = a0; out[i * 3 + 1] = a1; out[i * 3 + 2] = a2;
    }
}

// ---------------- launcher ----------------

extern "C" void kernel_launch(void* const* d_in, const int* in_sizes, int n_in,
                              void* d_out, int out_size, void* d_ws, size_t ws_size,
                              hipStream_t stream) {
    const int*   x_idx  = (const int*)d_in[0];
    const int*   ei     = (const int*)d_in[1];
    const float* eattr  = (const float*)d_in[2];
    const int*   batch  = (const int*)d_in[3];
    const float* demog  = (const float*)d_in[4];
    const float* emb    = (const float*)d_in[5];
    const float* wrel1  = (const float*)d_in[6];
    const float* brel1  = (const float*)d_in[7];
    const float* wroot1 = (const float*)d_in[8];
    const float* wrel2  = (const float*)d_in[9];
    const float* brel2  = (const float*)d_in[10];
    const float* wroot2 = (const float*)d_in[11];
    const float* wrel3  = (const float*)d_in[12];
    const float* brel3  = (const float*)d_in[13];
    const float* wroot3 = (const float*)d_in[14];
    const float* gn1g = (const float*)d_in[15];
    const float* gn1b = (const float*)d_in[16];
    const float* gn1a = (const float*)d_in[17];
    const float* gn2g = (const float*)d_in[18];
    const float* gn2b = (const float*)d_in[19];
    const float* gn2a = (const float*)d_in[20];
    const float* dw   = (const float*)d_in[21];
    const float* db   = (const float*)d_in[22];
    const float* l1w  = (const float*)d_in[23];
    const float* l1b  = (const float*)d_in[24];
    const float* bn1g = (const float*)d_in[25];
    const float* bn1b = (const float*)d_in[26];
    const float* l2w  = (const float*)d_in[27];
    const float* l2b  = (const float*)d_in[28];
    const float* bn2g = (const float*)d_in[29];
    const float* bn2b = (const float*)d_in[30];
    const float* l3w  = (const float*)d_in[31];
    const float* l3b  = (const float*)d_in[32];
    float* out = (float*)d_out;

    float*    W     = (float*)d_ws;
    float*    xf    = W;                                   // fp32 conv out, 12.8M floats
    int2*     ebuf  = (int2*)W;                            // NE int2 (CSR build only)
    float*    gfacc = W + 12800000;                        // NBATCH*256 fp32
    ushort_t* xcat0 = (ushort_t*)(W + 25600000);           // NN*32 bf16  [agg0|x0]
    ushort_t* xcat1 = (ushort_t*)(W + 27200000);           // NN*128 bf16 [agg1|x1]
    ushort_t* xcat2 = (ushort_t*)(W + 33600000);           // NN*256 bf16 [agg2|x2]
    ushort_t* w1T   = (ushort_t*)(W + 46400000);           // 2048
    ushort_t* w2T   = w1T + 2048;                          // 16384
    ushort_t* w3T   = w2T + 16384;                         // 65536
    int2*     csr_pair = (int2*)(W + 46450000);            // NE int2
    int*      rowstart = (int*)(W + 49650000);             // NN+1
    int*      bstart   = (int*)(W + 49760000);             // NBATCH+1
    int*      bcnt     = (int*)(W + 49761000);             // NBUCK
    int*      bbase    = (int*)(W + 49762000);             // NBUCK+1
    int*      bcur     = (int*)(W + 49763000);             // NBUCK
    float*    h0 = W + 49770000;                           // 100*272
    float*    h1 = h0 + 27200;
    float*    h2 = h1 + 12800;
    float*    sacc1 = W + 49817000;                        // 100*64
    float*    qacc1 = sacc1 + 6400;
    float*    sacc2 = W + 49830000;                        // 100*128
    float*    qacc2 = sacc2 + 12800;
    uchar_t*  x8    = (uchar_t*)(W + 49860000);            // NN*128 fp8 e4m3 (x2 copy)

    const int* src = ei;
    const int* dst = ei + NE;

    const int mfma_blk = (NN + 63) / 64;     // 1563 (64 rows/block)
    const int nagg_blk = (NN + 3) / 4;       // 1 node/wave, 4 waves/block

    // ---- bucketed CSR build (by dst) ----
    hipMemsetAsync(bcnt, 0, NBUCK * sizeof(int), stream);
    k_bcount<<<256, 256, 0, stream>>>(dst, bcnt);
    k_bscan<<<1, 512, 0, stream>>>(bcnt, bbase, bcur, rowstart);
    k_bscatter<<<256, 256, 0, stream>>>(dst, src, eattr, bcur, ebuf);
    k_bfinal<<<NBUCK, 256, 0, stream>>>(ebuf, bbase, rowstart, csr_pair);

    k_bounds<<<1, 128, 0, stream>>>(batch, bstart);
    k_wpackf<16, 32, 64><<<(2048 + 255) / 256, 256, 0, stream>>>(wrel1, wroot1, w1T);
    k_wpackf<64, 128, 128><<<(16384 + 255) / 256, 256, 0, stream>>>(wrel2, wroot2, w2T);
    k_wpackf<128, 256, 256><<<(65536 + 255) / 256, 256, 0, stream>>>(wrel3, wroot3, w3T);
    hipMemsetAsync(gfacc, 0, NBATCH * 256 * sizeof(float), stream);
    hipMemsetAsync(sacc1, 0, (6400 * 2) * sizeof(float), stream);
    hipMemsetAsync(sacc2, 0, (12800 * 2) * sizeof(float), stream);

    // x0 (bf16) into xcat0 x-half
    k_gather_b<<<(NN + 255) / 256, 256, 0, stream>>>(x_idx, emb, xcat0);

    // conv1: [agg0|x0](K2=32) @ w1T -> xf (fp32 NN x 64) + graphnorm stats
    k_aggregate_b<16><<<nagg_blk, 256, 0, stream>>>(xcat0, csr_pair, rowstart);
    k_conv_mfma<32, 64, 1, 1><<<mfma_blk, 256, 0, stream>>>(xcat0, w1T, brel1, xf, batch, bstart, sacc1, qacc1);
    k_gnapply<64, 128, false><<<dim3(NBATCH, 1), 256, 0, stream>>>(xf, xcat1 + 64, nullptr,
                                                                   bstart, sacc1, qacc1, gn1a, gn1g, gn1b);

    // conv2: [agg1|x1](K2=128) @ w2T -> xf (fp32 NN x 128) + stats; apply writes bf16 + fp8
    k_aggregate_b<64><<<nagg_blk, 256, 0, stream>>>(xcat1, csr_pair, rowstart);
    k_conv_mfma<128, 128, 1, 1><<<mfma_blk, 256, 0, stream>>>(xcat1, w2T, brel2, xf, batch, bstart, sacc2, qacc2);
    k_gnapply<128, 256, true><<<dim3(NBATCH, 2), 256, 0, stream>>>(xf, xcat2 + 128, x8,
                                                                   bstart, sacc2, qacc2, gn2a, gn2g, gn2b);

    // conv3: [agg2|x2](K2=256) @ w3T -> gfacc (split-K=2, x3 never materialized)
    k_aggregate_f8<<<nagg_blk, 256, 0, stream>>>(xcat2, x8, csr_pair, rowstart);
    k_conv_mfma<256, 256, 2, 2><<<dim3(mfma_blk, 2), 256, 0, stream>>>(xcat2, w3T, brel3, nullptr, batch, bstart, gfacc, nullptr);

    // head
    k_gffin<<<(NBATCH * 256 + 255) / 256, 256, 0, stream>>>(gfacc, bstart, h0);
    k_demo<<<(NBATCH * 16 + 255) / 256, 256, 0, stream>>>(demog, dw, db, h0);
    k_head_lin<272, 128><<<(NBATCH + 15) / 16, 128, 0, stream>>>(h0, l1w, l1b, h1, NBATCH);
    k_head_bn<<<1, 128, 0, stream>>>(h1, bn1g, bn1b, NBATCH, 128);
    k_head_lin<128, 64><<<(NBATCH + 15) / 16, 64, 0, stream>>>(h1, l2w, l2b, h2, NBATCH);
    k_head_bn<<<1, 64, 0, stream>>>(h2, bn2g, bn2b, NBATCH, 64);
    k_head_out<<<1, 256, 0, stream>>>(h2, l3w, l3b, out);
}